// Round 3
// baseline (1808.224 us; speedup 1.0000x reference)
//
#include <hip/hip_runtime.h>
#include <math.h>

#define PI_F 3.14159265358979323846f

typedef __attribute__((ext_vector_type(8))) _Float16 half8;
typedef __attribute__((ext_vector_type(4))) float f32x4;

// ---------------------------------------------------------------------------
// conv1: fp32 VALU direct conv (CIN=3), output NHWC fp16 (pre-BN) + stats.
// grid (8,1,256), 256 thr. Each thread: 2 rows x 32 couts at one x.
// ---------------------------------------------------------------------------
__global__ __launch_bounds__(256) void conv1_kernel(
    const float* __restrict__ in, const float* __restrict__ wgt,
    const float* __restrict__ bias, _Float16* __restrict__ out,
    float* __restrict__ partials)
{
    __shared__ __align__(16) float s_in[3][10][66];
    __shared__ __align__(16) float s_w[3][9][32];
    __shared__ float s_red[64];

    const int t = threadIdx.x;
    const int x = t & 63;
    const int q = t >> 6;           // row-pair 0..3
    const int tile = blockIdx.x;
    const int n = blockIdx.z;
    const int y0 = tile * 8;

    // stage input 3x10x66
    for (int idx = t; idx < 3 * 10 * 66; idx += 256) {
        int xl = idx % 66;
        int r1 = idx / 66;
        int yl = r1 % 10;
        int ci = r1 / 10;
        int gy = y0 + yl - 1, gx = xl - 1;
        float v = 0.f;
        if (gy >= 0 && gy < 64 && gx >= 0 && gx < 64)
            v = in[((size_t)(n * 3 + ci) * 64 + gy) * 64 + gx];
        s_in[ci][yl][xl] = v;
    }
    // stage weights 3x9x32
    for (int idx = t; idx < 3 * 9 * 32; idx += 256) {
        int co = idx & 31;
        int r2 = idx >> 5;
        int tap = r2 % 9;
        int ci = r2 / 9;
        s_w[ci][tap][co] = wgt[(size_t)(co * 3 + ci) * 9 + tap];
    }
    if (t < 64) s_red[t] = 0.f;
    __syncthreads();

    float4 acc0[8], acc1[8];
    #pragma unroll
    for (int i = 0; i < 8; ++i) {
        acc0[i] = make_float4(0.f, 0.f, 0.f, 0.f);
        acc1[i] = make_float4(0.f, 0.f, 0.f, 0.f);
    }
    #pragma unroll
    for (int ci = 0; ci < 3; ++ci) {
        #pragma unroll
        for (int ky = 0; ky < 3; ++ky) {
            #pragma unroll
            for (int kx = 0; kx < 3; ++kx) {
                float iv0 = s_in[ci][2 * q + ky][x + kx];
                float iv1 = s_in[ci][2 * q + 1 + ky][x + kx];
                #pragma unroll
                for (int c4 = 0; c4 < 8; ++c4) {
                    float4 wv = *(const float4*)&s_w[ci][ky * 3 + kx][c4 * 4];
                    acc0[c4].x += wv.x * iv0; acc0[c4].y += wv.y * iv0;
                    acc0[c4].z += wv.z * iv0; acc0[c4].w += wv.w * iv0;
                    acc1[c4].x += wv.x * iv1; acc1[c4].y += wv.y * iv1;
                    acc1[c4].z += wv.z * iv1; acc1[c4].w += wv.w * iv1;
                }
            }
        }
    }

    const int gy0 = y0 + 2 * q;
    size_t base0 = (((size_t)n * 64 + gy0) * 64 + x) * 32;
    #pragma unroll
    for (int c8 = 0; c8 < 4; ++c8) {
        half8 h0, h1;
        #pragma unroll
        for (int j = 0; j < 8; ++j) {
            int c = c8 * 8 + j;
            int c4 = c >> 2, cc = c & 3;
            float bv = bias[c];
            float v0 = ((const float*)&acc0[c4])[cc] + bv;
            float v1 = ((const float*)&acc1[c4])[cc] + bv;
            h0[j] = (_Float16)v0; h1[j] = (_Float16)v1;
            float s = v0 + v1, s2 = v0 * v0 + v1 * v1;
            #pragma unroll
            for (int off = 32; off > 0; off >>= 1) {
                s += __shfl_xor(s, off);
                s2 += __shfl_xor(s2, off);
            }
            if ((t & 63) == 0) {
                atomicAdd(&s_red[c], s);
                atomicAdd(&s_red[32 + c], s2);
            }
        }
        *(half8*)&out[base0 + c8 * 8] = h0;
        *(half8*)&out[base0 + 2048 + c8 * 8] = h1;   // next row: +64*32
    }
    __syncthreads();
    if (t < 64)
        partials[((size_t)n * 8 + tile) * 64 + t] = s_red[t];
}

// ---------------------------------------------------------------------------
// Weight transform: [COUT][CIN][3][3] fp32 -> [COUT][9*CIN] fp16, k=(tap,ci)
// ---------------------------------------------------------------------------
__global__ __launch_bounds__(256) void wt_transform_kernel(
    const float* __restrict__ w2, const float* __restrict__ w3,
    const float* __restrict__ w4, _Float16* __restrict__ t2,
    _Float16* __restrict__ t3, _Float16* __restrict__ t4)
{
    int idx = blockIdx.x * 256 + threadIdx.x;
    if (idx < 9216) {               // conv2: 32x(9*32)
        int co = idx / 288, rem = idx % 288, tap = rem / 32, ci = rem % 32;
        t2[idx] = (_Float16)w2[(size_t)(co * 32 + ci) * 9 + tap];
    } else if (idx < 27648) {       // conv3: 64x(9*32)
        int e = idx - 9216;
        int co = e / 288, rem = e % 288, tap = rem / 32, ci = rem % 32;
        t3[e] = (_Float16)w3[(size_t)(co * 32 + ci) * 9 + tap];
    } else if (idx < 64512) {       // conv4: 64x(9*64)
        int e = idx - 27648;
        int co = e / 576, rem = e % 576, tap = rem / 64, ci = rem % 64;
        t4[e] = (_Float16)w4[(size_t)(co * 64 + ci) * 9 + tap];
    }
}

// ---------------------------------------------------------------------------
// Implicit-GEMM 3x3 conv via MFMA f16. NHWC fp16 in/out (H=W).
// Block: 128 spatial x 32 cout, 4 waves (32 spatial x 32 cout each).
// Optional BN(scale,shift)+ReLU applied to input during LDS staging.
// Emits per-block per-cout sum/sumsq (of conv+bias output) for BN stats.
// ---------------------------------------------------------------------------
template<int W, int CIN, int COUT>
__global__ __launch_bounds__(256) void conv_mfma_kernel(
    const _Float16* __restrict__ in, const _Float16* __restrict__ wt,
    const float* __restrict__ bias, const float* __restrict__ ss_in,
    _Float16* __restrict__ out, float* __restrict__ partials)
{
    constexpr int H = W;
    constexpr int ROWS = 128 / W;
    constexpr int CS = CIN + 8;     // padded channel stride (halves)
    constexpr int K = 9 * CIN;
    constexpr int KS = K + 8;       // padded weight row stride (halves)
    constexpr int TR = ROWS + 2;
    constexpr int TC = W + 2;
    __shared__ __align__(16) _Float16 s_in[TR * TC * CS];
    __shared__ __align__(16) _Float16 s_w[32 * KS];
    __shared__ float s_red[64];

    const int t = threadIdx.x;
    const int row0 = blockIdx.x * ROWS;
    const int cout0 = blockIdx.y * 32;
    const int n = blockIdx.z;

    // ---- stage weights: [32 couts][K] -> [co][KS] ----
    for (int idx = t; idx < 32 * (K / 8); idx += 256) {
        int k8 = idx % (K / 8);
        int co = idx / (K / 8);
        *(half8*)&s_w[co * KS + k8 * 8] =
            *(const half8*)&wt[(size_t)(cout0 + co) * K + k8 * 8];
    }
    // ---- stage input tile (zero-padded halo, optional bn+relu) ----
    for (int idx = t; idx < TR * TC * (CIN / 8); idx += 256) {
        int c8 = idx % (CIN / 8);
        int colr = idx / (CIN / 8);
        int col = colr % TC;
        int r = colr / TC;
        int gy = row0 + r - 1, gx = col - 1;
        half8 v;
        #pragma unroll
        for (int j = 0; j < 8; ++j) v[j] = (_Float16)0.f;
        if (gy >= 0 && gy < H && gx >= 0 && gx < W) {
            v = *(const half8*)&in[(((size_t)n * H + gy) * W + gx) * CIN + c8 * 8];
            if (ss_in) {
                #pragma unroll
                for (int j = 0; j < 8; ++j) {
                    int c = c8 * 8 + j;
                    float f = (float)v[j] * ss_in[c] + ss_in[CIN + c];
                    v[j] = (_Float16)fmaxf(0.f, f);
                }
            }
        }
        *(half8*)&s_in[(r * TC + col) * CS + c8 * 8] = v;
    }
    if (t < 64) s_red[t] = 0.f;
    __syncthreads();

    const int w = t >> 6, l = t & 63;
    const int lm = l & 15, lg = l >> 4;
    int rA[2], xA[2];
    #pragma unroll
    for (int f = 0; f < 2; ++f) {
        int m = w * 32 + f * 16 + lm;
        rA[f] = m / W;
        xA[f] = m % W;
    }
    f32x4 zero4 = {0.f, 0.f, 0.f, 0.f};
    f32x4 acc[2][2];
    acc[0][0] = zero4; acc[0][1] = zero4; acc[1][0] = zero4; acc[1][1] = zero4;

    #pragma unroll
    for (int ks = 0; ks < K; ks += 32) {
        const int tap = ks / CIN;
        const int ci0 = ks % CIN;
        const int dy = tap / 3, dx = tap % 3;
        half8 b0 = *(const half8*)&s_w[lm * KS + ks + lg * 8];
        half8 b1 = *(const half8*)&s_w[(lm + 16) * KS + ks + lg * 8];
        #pragma unroll
        for (int f = 0; f < 2; ++f) {
            half8 a = *(const half8*)&s_in[((rA[f] + dy) * TC + xA[f] + dx) * CS + ci0 + lg * 8];
            acc[f][0] = __builtin_amdgcn_mfma_f32_16x16x32_f16(a, b0, acc[f][0], 0, 0, 0);
            acc[f][1] = __builtin_amdgcn_mfma_f32_16x16x32_f16(a, b1, acc[f][1], 0, 0, 0);
        }
    }

    // ---- bias + NHWC fp16 store + stats ----
    float bv0 = bias[cout0 + lm];
    float bv1 = bias[cout0 + 16 + lm];
    float s0 = 0.f, s20 = 0.f, s1 = 0.f, s21 = 0.f;
    #pragma unroll
    for (int f = 0; f < 2; ++f) {
        #pragma unroll
        for (int r = 0; r < 4; ++r) {
            int m = w * 32 + f * 16 + lg * 4 + r;
            int y = row0 + m / W, xo = m % W;
            size_t base = (((size_t)n * H + y) * W + xo) * COUT + cout0;
            float v0 = acc[f][0][r] + bv0;
            float v1 = acc[f][1][r] + bv1;
            out[base + lm] = (_Float16)v0;
            out[base + 16 + lm] = (_Float16)v1;
            s0 += v0; s20 += v0 * v0;
            s1 += v1; s21 += v1 * v1;
        }
    }
    s0 += __shfl_xor(s0, 16);  s0 += __shfl_xor(s0, 32);
    s1 += __shfl_xor(s1, 16);  s1 += __shfl_xor(s1, 32);
    s20 += __shfl_xor(s20, 16); s20 += __shfl_xor(s20, 32);
    s21 += __shfl_xor(s21, 16); s21 += __shfl_xor(s21, 32);
    if (l < 16) {
        atomicAdd(&s_red[lm], s0);
        atomicAdd(&s_red[16 + lm], s1);
        atomicAdd(&s_red[32 + lm], s20);
        atomicAdd(&s_red[48 + lm], s21);
    }
    __syncthreads();
    if (t < 64) {
        size_t bid = ((size_t)n * gridDim.y + blockIdx.y) * gridDim.x + blockIdx.x;
        partials[bid * 64 + t] = s_red[t];
    }
}

// ---------------------------------------------------------------------------
// Reduce per-block partials -> BN scale/shift per channel.
// ---------------------------------------------------------------------------
__global__ __launch_bounds__(256) void bn_finalize_kernel(
    const float* __restrict__ partials, int nx, int ng, float inv_count,
    const float* __restrict__ gamma, const float* __restrict__ beta,
    float* __restrict__ ss, int COUT)
{
    int T = 256 / COUT;
    int c = threadIdx.x / T;
    int s = threadIdx.x % T;
    int g = c >> 5, i = c & 31;
    float sum = 0.f, sq = 0.f;
    int total = 256 * nx;
    for (int k = s; k < total; k += T) {
        int n = k / nx, xt = k - n * nx;
        size_t bid = ((size_t)(n * ng + g) * nx + xt) * 64;
        sum += partials[bid + i];
        sq  += partials[bid + 32 + i];
    }
    __shared__ float rs[256], rq[256];
    rs[threadIdx.x] = sum; rq[threadIdx.x] = sq;
    __syncthreads();
    if (s == 0) {
        for (int k2 = 1; k2 < T; ++k2) { sum += rs[threadIdx.x + k2]; sq += rq[threadIdx.x + k2]; }
        float mean = sum * inv_count;
        float var = sq * inv_count - mean * mean;
        float scale = gamma[c] * rsqrtf(var + 1e-5f);
        ss[c] = scale;
        ss[COUT + c] = beta[c] - mean * scale;
    }
}

// ---------------------------------------------------------------------------
// NHWC BN+ReLU + 2x2/2 maxpool, fp16 -> fp16.
// ---------------------------------------------------------------------------
template<int C>
__global__ __launch_bounds__(256) void pool_nhwc_kernel(
    const _Float16* __restrict__ in, const float* __restrict__ ss,
    _Float16* __restrict__ out, int HO, int total)
{
    int idx = blockIdx.x * 256 + threadIdx.x;
    if (idx >= total) return;
    int c8 = idx % (C / 8);
    int p = idx / (C / 8);
    int x = p % HO;
    int p2 = p / HO;
    int y = p2 % HO;
    int n = p2 / HO;
    int WI = 2 * HO;
    size_t b00 = (((size_t)n * WI + 2 * y) * WI + 2 * x) * C + c8 * 8;
    half8 v00 = *(const half8*)&in[b00];
    half8 v01 = *(const half8*)&in[b00 + C];
    half8 v10 = *(const half8*)&in[b00 + (size_t)WI * C];
    half8 v11 = *(const half8*)&in[b00 + (size_t)WI * C + C];
    half8 o;
    #pragma unroll
    for (int j = 0; j < 8; ++j) {
        int c = c8 * 8 + j;
        float sc = ss[c], sh = ss[C + c];
        float m = fmaxf(fmaxf((float)v00[j] * sc + sh, (float)v01[j] * sc + sh),
                        fmaxf((float)v10[j] * sc + sh, (float)v11[j] * sc + sh));
        o[j] = (_Float16)fmaxf(0.f, m);
    }
    *(half8*)&out[(((size_t)n * HO + y) * HO + x) * C + c8 * 8] = o;
}

// ---------------------------------------------------------------------------
// fc1 GEMM, K-split. A: NHWC fp16 pool2 (256,16,16,64), logical k=c*256+y*16+x
// ---------------------------------------------------------------------------
__global__ __launch_bounds__(256) void fc1_partial_kernel(
    const _Float16* __restrict__ A, const float* __restrict__ Bw, float* __restrict__ hp)
{
    __shared__ float As[64][33];
    __shared__ float Bs[32][33];
    const int t = threadIdx.x;
    const int n0 = blockIdx.x * 64;
    const int j0 = blockIdx.y * 32;
    const int k0 = blockIdx.z * 1024;
    const int j = t & 31;
    const int i0 = (t >> 5) * 8;
    float acc[8] = {0.f, 0.f, 0.f, 0.f, 0.f, 0.f, 0.f, 0.f};
    for (int ks = 0; ks < 1024; ks += 32) {
        __syncthreads();
        #pragma unroll
        for (int r = 0; r < 8; ++r) {
            int e = t + 256 * r;
            int row = e >> 5, kk = e & 31;
            int k = k0 + ks + kk;
            int c = k >> 8, yx = k & 255, y = yx >> 4, xx = yx & 15;
            As[row][kk] = (float)A[(((size_t)(n0 + row) * 16 + y) * 16 + xx) * 64 + c];
        }
        #pragma unroll
        for (int r = 0; r < 4; ++r) {
            int e = t + 256 * r;
            int row = e >> 5, kk = e & 31;
            Bs[row][kk] = Bw[(size_t)(j0 + row) * 16384 + k0 + ks + kk];
        }
        __syncthreads();
        #pragma unroll
        for (int kk = 0; kk < 32; ++kk) {
            float bv = Bs[j][kk];
            #pragma unroll
            for (int i = 0; i < 8; ++i) acc[i] += As[i0 + i][kk] * bv;
        }
    }
    #pragma unroll
    for (int i = 0; i < 8; ++i)
        hp[((size_t)blockIdx.z * 256 + n0 + i0 + i) * 128 + j0 + j] = acc[i];
}

__global__ __launch_bounds__(256) void fc1_reduce_kernel(
    const float* __restrict__ hp, const float* __restrict__ bias, float* __restrict__ h1)
{
    int gid = blockIdx.x * 256 + threadIdx.x;   // 32768
    int n = gid >> 7, j = gid & 127;
    float s = bias[j];
    #pragma unroll
    for (int kc = 0; kc < 16; ++kc) s += hp[((size_t)kc * 256 + n) * 128 + j];
    h1[gid] = fmaxf(0.f, s);
}

// ---------------------------------------------------------------------------
// fc2: (256,128) x (10,128)^T + b -> xq (256,10). One wave per batch element.
// ---------------------------------------------------------------------------
__global__ __launch_bounds__(64) void fc2_kernel(
    const float* __restrict__ h1, const float* __restrict__ w,
    const float* __restrict__ b, float* __restrict__ xq)
{
    int n = blockIdx.x, l = threadIdx.x;
    float a0 = h1[n * 128 + l], a1 = h1[n * 128 + 64 + l];
    float p[10];
    #pragma unroll
    for (int j = 0; j < 10; ++j)
        p[j] = w[j * 128 + l] * a0 + w[j * 128 + 64 + l] * a1;
    #pragma unroll
    for (int j = 0; j < 10; ++j) {
        #pragma unroll
        for (int off = 32; off > 0; off >>= 1) p[j] += __shfl_xor(p[j], off);
    }
    if (l == 0) {
        #pragma unroll
        for (int j = 0; j < 10; ++j) xq[n * 10 + j] = p[j] + b[j];
    }
}

// ---------------------------------------------------------------------------
// 10-qubit state-vector sim (1024 amplitudes in LDS) + Z expectations + head.
// ---------------------------------------------------------------------------
__global__ __launch_bounds__(256) void quantum_head_kernel(
    const float* __restrict__ xq, const float* __restrict__ qw,
    const float* __restrict__ head_w, const float* __restrict__ head_b,
    float* __restrict__ outp)
{
    __shared__ float sr[1024], si[1024];
    const int n = blockIdx.x, t = threadIdx.x;
    for (int i = t; i < 1024; i += 256) { sr[i] = 0.f; si[i] = 0.f; }
    __syncthreads();
    if (t == 0) sr[0] = 1.f;
    __syncthreads();

    for (int w = 0; w < 10; ++w) {
        float th = 0.5f * PI_F * xq[n * 10 + w];
        float c = cosf(th), s = sinf(th);
        int k = 9 - w, kb = 1 << k;
        #pragma unroll
        for (int pp = 0; pp < 2; ++pp) {
            int p = t + 256 * pp;
            int i0 = ((p >> k) << (k + 1)) | (p & (kb - 1));
            int i1 = i0 | kb;
            float ar = sr[i0], br = sr[i1], ai = si[i0], bi = si[i1];
            sr[i0] = c * ar - s * br;  si[i0] = c * ai - s * bi;
            sr[i1] = s * ar + c * br;  si[i1] = s * ai + c * bi;
        }
        __syncthreads();
    }

    for (int l = 0; l < 6; ++l) {
        for (int w = 0; w < 10; ++w) {
            const float* qp = qw + (l * 10 + w) * 3;
            float phi = qp[0], th = qp[1], om = qp[2];
            float c = cosf(0.5f * th), s = sinf(0.5f * th);
            float apo = 0.5f * (phi + om), amo = 0.5f * (phi - om);
            float cpo = cosf(apo), spo = sinf(apo);
            float cmo = cosf(amo), smo = sinf(amo);
            float m00r = cpo * c,  m00i = -spo * c;
            float m01r = -cmo * s, m01i = -smo * s;
            float m10r = cmo * s,  m10i = -smo * s;
            float m11r = cpo * c,  m11i = spo * c;
            int k = 9 - w, kb = 1 << k;
            #pragma unroll
            for (int pp = 0; pp < 2; ++pp) {
                int p = t + 256 * pp;
                int i0 = ((p >> k) << (k + 1)) | (p & (kb - 1));
                int i1 = i0 | kb;
                float ar = sr[i0], ai = si[i0], br = sr[i1], bi = si[i1];
                sr[i0] = m00r * ar - m00i * ai + m01r * br - m01i * bi;
                si[i0] = m00r * ai + m00i * ar + m01r * bi + m01i * br;
                sr[i1] = m10r * ar - m10i * ai + m11r * br - m11i * bi;
                si[i1] = m10r * ai + m10i * ar + m11r * bi + m11i * br;
            }
            __syncthreads();
        }
        int r = l % 9 + 1;
        float tr[4], ti[4];
        #pragma unroll
        for (int si_ = 0; si_ < 4; ++si_) {
            int i = t + 256 * si_;
            int jdx = i;
            #pragma unroll
            for (int w = 9; w >= 0; --w) {
                int tt = (w + r) % 10;
                int pc = 9 - w, pt = 9 - tt;
                jdx ^= ((jdx >> pc) & 1) << pt;
            }
            tr[si_] = sr[jdx]; ti[si_] = si[jdx];
        }
        __syncthreads();
        #pragma unroll
        for (int si_ = 0; si_ < 4; ++si_) {
            int i = t + 256 * si_;
            sr[i] = tr[si_]; si[i] = ti[si_];
        }
        __syncthreads();
    }

    float pk[10];
    #pragma unroll
    for (int w = 0; w < 10; ++w) pk[w] = 0.f;
    #pragma unroll
    for (int si_ = 0; si_ < 4; ++si_) {
        int i = t + 256 * si_;
        float pr = sr[i] * sr[i] + si[i] * si[i];
        #pragma unroll
        for (int w = 0; w < 10; ++w)
            pk[w] += ((i >> (9 - w)) & 1) ? -pr : pr;
    }
    __syncthreads();
    #pragma unroll
    for (int w = 0; w < 10; ++w) {
        #pragma unroll
        for (int off = 32; off > 0; off >>= 1) pk[w] += __shfl_xor(pk[w], off);
    }
    int wave = t >> 6, lane = t & 63;
    if (lane == 0) {
        #pragma unroll
        for (int w = 0; w < 10; ++w) sr[wave * 10 + w] = pk[w];
    }
    __syncthreads();
    if (t < 10) si[t] = sr[t] + sr[10 + t] + sr[20 + t] + sr[30 + t];
    __syncthreads();
    if (t < 10) {
        float o = head_b[t];
        #pragma unroll
        for (int kk = 0; kk < 10; ++kk) o += si[kk] * head_w[t * 10 + kk];
        outp[n * 10 + t] = o;
    }
}

// ---------------------------------------------------------------------------
// Workspace (≈139 MB): two 33.55M-half NHWC regions (ping-pong) + fp32 tail.
// H0: c1out -> pool1 -> c4out ; H1: c2out -> c3out -> pool2
// ---------------------------------------------------------------------------
extern "C" void kernel_launch(void* const* d_in, const int* in_sizes, int n_in,
                              void* d_out, int out_size, void* d_ws, size_t ws_size,
                              hipStream_t stream)
{
    const float* x   = (const float*)d_in[0];
    const float* c1w = (const float*)d_in[1];  const float* c1b = (const float*)d_in[2];
    const float* g1  = (const float*)d_in[3];  const float* b1  = (const float*)d_in[4];
    const float* c2w = (const float*)d_in[5];  const float* c2b = (const float*)d_in[6];
    const float* g2  = (const float*)d_in[7];  const float* b2  = (const float*)d_in[8];
    const float* c3w = (const float*)d_in[9];  const float* c3b = (const float*)d_in[10];
    const float* g3  = (const float*)d_in[11]; const float* b3  = (const float*)d_in[12];
    const float* c4w = (const float*)d_in[13]; const float* c4b = (const float*)d_in[14];
    const float* g4  = (const float*)d_in[15]; const float* b4  = (const float*)d_in[16];
    const float* f1w = (const float*)d_in[17]; const float* f1b = (const float*)d_in[18];
    const float* f2w = (const float*)d_in[19]; const float* f2b = (const float*)d_in[20];
    const float* qw  = (const float*)d_in[21];
    const float* hw  = (const float*)d_in[22]; const float* hb  = (const float*)d_in[23];

    float* ws = (float*)d_ws;
    _Float16* H0 = (_Float16*)ws;              // 33,554,432 halves
    _Float16* H1 = H0 + 33554432;              // 33,554,432 halves
    float* part = ws + 33554432;               // 524,288
    float* ss1  = part + 524288;               // 64
    float* ss2  = ss1 + 64;                    // 64
    float* ss3  = ss2 + 64;                    // 128
    float* ss4  = ss3 + 128;                   // 128
    float* hp   = ss4 + 128;                   // 524,288
    float* h1   = hp + 524288;                 // 32,768
    float* xqv  = h1 + 32768;                  // 2,560
    _Float16* wt2 = (_Float16*)(xqv + 2560);   // 9,216 halves
    _Float16* wt3 = wt2 + 9216;                // 18,432 halves
    _Float16* wt4 = wt3 + 18432;               // 36,864 halves

    // weight transforms (independent)
    wt_transform_kernel<<<252, 256, 0, stream>>>(c2w, c3w, c4w, wt2, wt3, wt4);

    // conv1: x -> H0 (256,64,64,32) NHWC fp16 + stats
    conv1_kernel<<<dim3(8, 1, 256), 256, 0, stream>>>(x, c1w, c1b, H0, part);
    bn_finalize_kernel<<<1, 256, 0, stream>>>(part, 8, 1, 1.f / 1048576.f, g1, b1, ss1, 32);

    // conv2 (MFMA): bn1+relu(H0) -> H1 (256,64,64,32)
    conv_mfma_kernel<64, 32, 32><<<dim3(32, 1, 256), 256, 0, stream>>>(
        H0, wt2, c2b, ss1, H1, part);
    bn_finalize_kernel<<<1, 256, 0, stream>>>(part, 32, 1, 1.f / 1048576.f, g2, b2, ss2, 32);

    // pool1: bn2+relu(H1) pooled -> H0 (256,32,32,32)
    pool_nhwc_kernel<32><<<4096, 256, 0, stream>>>(H1, ss2, H0, 32, 1048576);

    // conv3 (MFMA): H0 (activated) -> H1 (256,32,32,64)
    conv_mfma_kernel<32, 32, 64><<<dim3(8, 2, 256), 256, 0, stream>>>(
        H0, wt3, c3b, nullptr, H1, part);
    bn_finalize_kernel<<<1, 256, 0, stream>>>(part, 8, 2, 1.f / 262144.f, g3, b3, ss3, 64);

    // conv4 (MFMA): bn3+relu(H1) -> H0 (256,32,32,64)
    conv_mfma_kernel<32, 64, 64><<<dim3(8, 2, 256), 256, 0, stream>>>(
        H1, wt4, c4b, ss3, H0, part);
    bn_finalize_kernel<<<1, 256, 0, stream>>>(part, 8, 2, 1.f / 262144.f, g4, b4, ss4, 64);

    // pool2: bn4+relu(H0) pooled -> H1 (256,16,16,64)
    pool_nhwc_kernel<64><<<2048, 256, 0, stream>>>(H0, ss4, H1, 16, 524288);

    // fc1 (K-split, NHWC-permuted A) + reduce -> h1 (256,128)
    fc1_partial_kernel<<<dim3(4, 4, 16), 256, 0, stream>>>(H1, f1w, hp);
    fc1_reduce_kernel<<<128, 256, 0, stream>>>(hp, f1b, h1);

    // fc2 -> xq (256,10)
    fc2_kernel<<<256, 64, 0, stream>>>(h1, f2w, f2b, xqv);

    // quantum circuit + head -> out (256,10)
    quantum_head_kernel<<<256, 256, 0, stream>>>(xqv, qw, hw, hb, (float*)d_out);
}

// Round 4
// 445.871 us; speedup vs baseline: 4.0555x; 4.0555x over previous
//
#include <hip/hip_runtime.h>
#include <math.h>

#define PI_F 3.14159265358979323846f

typedef __attribute__((ext_vector_type(8))) _Float16 half8;
typedef __attribute__((ext_vector_type(4))) float f32x4;

// ---------------------------------------------------------------------------
// conv1: fp32 VALU direct conv (CIN=3) -> NHWC fp16 (pre-BN), no stats.
// Block: 4 rows x 64 cols of one image. One thread = one pixel, 32 couts in
// registers. Epilogue: pack to LDS, cooperative linear half8 store.
// grid (16, 1, 256).
// ---------------------------------------------------------------------------
__global__ __launch_bounds__(256) void conv1_kernel(
    const float* __restrict__ in, const float* __restrict__ wgt,
    const float* __restrict__ bias, _Float16* __restrict__ out)
{
    __shared__ __align__(16) float s_in[3][6][66];
    __shared__ __align__(16) float s_w[27][32];    // [ci*9+tap][co]
    __shared__ __align__(16) half8 s_out[256][5];  // [pixel][c8], +1 pad

    const int t = threadIdx.x;
    const int x = t & 63;
    const int y = t >> 6;                 // 0..3
    const int y0 = blockIdx.x * 4;
    const int n = blockIdx.z;

    // stage input rows y0-1 .. y0+4 (6 rows) x 66 cols x 3 ch
    for (int idx = t; idx < 3 * 6 * 66; idx += 256) {
        int xl = idx % 66;
        int r1 = idx / 66;
        int yl = r1 % 6;
        int ci = r1 / 6;
        int gy = y0 + yl - 1, gx = xl - 1;
        float v = 0.f;
        if (gy >= 0 && gy < 64 && gx >= 0 && gx < 64)
            v = in[((size_t)(n * 3 + ci) * 64 + gy) * 64 + gx];
        s_in[ci][yl][xl] = v;
    }
    // stage weights [co][ci][3][3] -> s_w[ci*9+tap][co]
    for (int idx = t; idx < 27 * 32; idx += 256) {
        int co = idx & 31;
        int r = idx >> 5;                 // ci*9+tap
        s_w[r][co] = wgt[co * 27 + r];
    }
    __syncthreads();

    float acc[32];
    #pragma unroll
    for (int c = 0; c < 32; ++c) acc[c] = bias[c];

    #pragma unroll
    for (int ci = 0; ci < 3; ++ci) {
        #pragma unroll
        for (int dy = 0; dy < 3; ++dy) {
            #pragma unroll
            for (int dx = 0; dx < 3; ++dx) {
                float iv = s_in[ci][y + dy][x + dx];
                #pragma unroll
                for (int c4 = 0; c4 < 8; ++c4) {
                    float4 wv = *(const float4*)&s_w[ci * 9 + dy * 3 + dx][c4 * 4];
                    acc[c4 * 4 + 0] += wv.x * iv;
                    acc[c4 * 4 + 1] += wv.y * iv;
                    acc[c4 * 4 + 2] += wv.z * iv;
                    acc[c4 * 4 + 3] += wv.w * iv;
                }
            }
        }
    }

    #pragma unroll
    for (int c8 = 0; c8 < 4; ++c8) {
        half8 h;
        #pragma unroll
        for (int j = 0; j < 8; ++j) h[j] = (_Float16)acc[c8 * 8 + j];
        s_out[t][c8] = h;
    }
    __syncthreads();

    // cooperative linear store: 1024 half8s, consecutive lanes -> consecutive 16B
    size_t base = ((size_t)n * 64 + y0) * 2048;   // halves; 64*32 per row
    #pragma unroll
    for (int r = 0; r < 4; ++r) {
        int e = r * 256 + t;
        *(half8*)&out[base + (size_t)e * 8] = s_out[e >> 2][e & 3];
    }
}

// ---------------------------------------------------------------------------
// Per-channel sum/sumsq over NHWC fp16 tensor with C=32. grid (nx, 1, 256).
// Each block: 512 pixels (16384 halves). partials[bid*64 + {c | 32+c}].
// ---------------------------------------------------------------------------
__global__ __launch_bounds__(256) void stats_nhwc32_kernel(
    const _Float16* __restrict__ in, float* __restrict__ partials, int nx)
{
    __shared__ float s_red[64];
    const int t = threadIdx.x;
    const int xt = blockIdx.x;
    const int n = blockIdx.z;
    const int c8 = t & 3;

    float sum[8], sq[8];
    #pragma unroll
    for (int j = 0; j < 8; ++j) { sum[j] = 0.f; sq[j] = 0.f; }

    size_t base = (size_t)n * 131072 + (size_t)xt * 16384;
    #pragma unroll
    for (int r = 0; r < 8; ++r) {
        int e = r * 256 + t;
        half8 v = *(const half8*)&in[base + (size_t)e * 8];
        #pragma unroll
        for (int j = 0; j < 8; ++j) {
            float f = (float)v[j];
            sum[j] += f; sq[j] += f * f;
        }
    }
    // reduce across lanes sharing (t&3): xor 4,8,16,32
    #pragma unroll
    for (int off = 4; off <= 32; off <<= 1) {
        #pragma unroll
        for (int j = 0; j < 8; ++j) {
            sum[j] += __shfl_xor(sum[j], off);
            sq[j]  += __shfl_xor(sq[j], off);
        }
    }
    if (t < 64) s_red[t] = 0.f;
    __syncthreads();
    if ((t & 63) < 4) {
        #pragma unroll
        for (int j = 0; j < 8; ++j) {
            atomicAdd(&s_red[c8 * 8 + j], sum[j]);
            atomicAdd(&s_red[32 + c8 * 8 + j], sq[j]);
        }
    }
    __syncthreads();
    if (t < 64)
        partials[((size_t)n * nx + xt) * 64 + t] = s_red[t];
}

// ---------------------------------------------------------------------------
// Weight transform: [COUT][CIN][3][3] fp32 -> [COUT][9*CIN] fp16, k=(tap,ci)
// ---------------------------------------------------------------------------
__global__ __launch_bounds__(256) void wt_transform_kernel(
    const float* __restrict__ w2, const float* __restrict__ w3,
    const float* __restrict__ w4, _Float16* __restrict__ t2,
    _Float16* __restrict__ t3, _Float16* __restrict__ t4)
{
    int idx = blockIdx.x * 256 + threadIdx.x;
    if (idx < 9216) {               // conv2: 32x(9*32)
        int co = idx / 288, rem = idx % 288, tap = rem / 32, ci = rem % 32;
        t2[idx] = (_Float16)w2[(size_t)(co * 32 + ci) * 9 + tap];
    } else if (idx < 27648) {       // conv3: 64x(9*32)
        int e = idx - 9216;
        int co = e / 288, rem = e % 288, tap = rem / 32, ci = rem % 32;
        t3[e] = (_Float16)w3[(size_t)(co * 32 + ci) * 9 + tap];
    } else if (idx < 64512) {       // conv4: 64x(9*64)
        int e = idx - 27648;
        int co = e / 576, rem = e % 576, tap = rem / 64, ci = rem % 64;
        t4[e] = (_Float16)w4[(size_t)(co * 64 + ci) * 9 + tap];
    }
}

// ---------------------------------------------------------------------------
// Implicit-GEMM 3x3 conv via MFMA f16. NHWC fp16 in/out (H=W).
// Block: 128 spatial x 32 cout, 4 waves. Optional BN+ReLU on input staging.
// Emits per-block per-cout sum/sumsq for BN stats.
// ---------------------------------------------------------------------------
template<int W, int CIN, int COUT>
__global__ __launch_bounds__(256) void conv_mfma_kernel(
    const _Float16* __restrict__ in, const _Float16* __restrict__ wt,
    const float* __restrict__ bias, const float* __restrict__ ss_in,
    _Float16* __restrict__ out, float* __restrict__ partials)
{
    constexpr int H = W;
    constexpr int ROWS = 128 / W;
    constexpr int CS = CIN + 8;
    constexpr int K = 9 * CIN;
    constexpr int KS = K + 8;
    constexpr int TR = ROWS + 2;
    constexpr int TC = W + 2;
    __shared__ __align__(16) _Float16 s_in[TR * TC * CS];
    __shared__ __align__(16) _Float16 s_w[32 * KS];
    __shared__ float s_red[64];

    const int t = threadIdx.x;
    const int row0 = blockIdx.x * ROWS;
    const int cout0 = blockIdx.y * 32;
    const int n = blockIdx.z;

    for (int idx = t; idx < 32 * (K / 8); idx += 256) {
        int k8 = idx % (K / 8);
        int co = idx / (K / 8);
        *(half8*)&s_w[co * KS + k8 * 8] =
            *(const half8*)&wt[(size_t)(cout0 + co) * K + k8 * 8];
    }
    for (int idx = t; idx < TR * TC * (CIN / 8); idx += 256) {
        int c8 = idx % (CIN / 8);
        int colr = idx / (CIN / 8);
        int col = colr % TC;
        int r = colr / TC;
        int gy = row0 + r - 1, gx = col - 1;
        half8 v;
        #pragma unroll
        for (int j = 0; j < 8; ++j) v[j] = (_Float16)0.f;
        if (gy >= 0 && gy < H && gx >= 0 && gx < W) {
            v = *(const half8*)&in[(((size_t)n * H + gy) * W + gx) * CIN + c8 * 8];
            if (ss_in) {
                #pragma unroll
                for (int j = 0; j < 8; ++j) {
                    int c = c8 * 8 + j;
                    float f = (float)v[j] * ss_in[c] + ss_in[CIN + c];
                    v[j] = (_Float16)fmaxf(0.f, f);
                }
            }
        }
        *(half8*)&s_in[(r * TC + col) * CS + c8 * 8] = v;
    }
    if (t < 64) s_red[t] = 0.f;
    __syncthreads();

    const int w = t >> 6, l = t & 63;
    const int lm = l & 15, lg = l >> 4;
    int rA[2], xA[2];
    #pragma unroll
    for (int f = 0; f < 2; ++f) {
        int m = w * 32 + f * 16 + lm;
        rA[f] = m / W;
        xA[f] = m % W;
    }
    f32x4 zero4 = {0.f, 0.f, 0.f, 0.f};
    f32x4 acc[2][2];
    acc[0][0] = zero4; acc[0][1] = zero4; acc[1][0] = zero4; acc[1][1] = zero4;

    #pragma unroll
    for (int ks = 0; ks < K; ks += 32) {
        const int tap = ks / CIN;
        const int ci0 = ks % CIN;
        const int dy = tap / 3, dx = tap % 3;
        half8 b0 = *(const half8*)&s_w[lm * KS + ks + lg * 8];
        half8 b1 = *(const half8*)&s_w[(lm + 16) * KS + ks + lg * 8];
        #pragma unroll
        for (int f = 0; f < 2; ++f) {
            half8 a = *(const half8*)&s_in[((rA[f] + dy) * TC + xA[f] + dx) * CS + ci0 + lg * 8];
            acc[f][0] = __builtin_amdgcn_mfma_f32_16x16x32_f16(a, b0, acc[f][0], 0, 0, 0);
            acc[f][1] = __builtin_amdgcn_mfma_f32_16x16x32_f16(a, b1, acc[f][1], 0, 0, 0);
        }
    }

    float bv0 = bias[cout0 + lm];
    float bv1 = bias[cout0 + 16 + lm];
    float s0 = 0.f, s20 = 0.f, s1 = 0.f, s21 = 0.f;
    #pragma unroll
    for (int f = 0; f < 2; ++f) {
        #pragma unroll
        for (int r = 0; r < 4; ++r) {
            int m = w * 32 + f * 16 + lg * 4 + r;
            int yy = row0 + m / W, xo = m % W;
            size_t base = (((size_t)n * H + yy) * W + xo) * COUT + cout0;
            float v0 = acc[f][0][r] + bv0;
            float v1 = acc[f][1][r] + bv1;
            out[base + lm] = (_Float16)v0;
            out[base + 16 + lm] = (_Float16)v1;
            s0 += v0; s20 += v0 * v0;
            s1 += v1; s21 += v1 * v1;
        }
    }
    s0 += __shfl_xor(s0, 16);  s0 += __shfl_xor(s0, 32);
    s1 += __shfl_xor(s1, 16);  s1 += __shfl_xor(s1, 32);
    s20 += __shfl_xor(s20, 16); s20 += __shfl_xor(s20, 32);
    s21 += __shfl_xor(s21, 16); s21 += __shfl_xor(s21, 32);
    if (l < 16) {
        atomicAdd(&s_red[lm], s0);
        atomicAdd(&s_red[16 + lm], s1);
        atomicAdd(&s_red[32 + lm], s20);
        atomicAdd(&s_red[48 + lm], s21);
    }
    __syncthreads();
    if (t < 64) {
        size_t bid = ((size_t)n * gridDim.y + blockIdx.y) * gridDim.x + blockIdx.x;
        partials[bid * 64 + t] = s_red[t];
    }
}

// ---------------------------------------------------------------------------
// Reduce per-block partials -> BN scale/shift. grid = COUT blocks.
// partials bid = (n*ng + g)*nx + xt; 64 floats = 32 sums + 32 sumsq (per group)
// ---------------------------------------------------------------------------
__global__ __launch_bounds__(256) void bn_finalize_kernel(
    const float* __restrict__ partials, int nx, int ng, float inv_count,
    const float* __restrict__ gamma, const float* __restrict__ beta,
    float* __restrict__ ss, int COUT)
{
    const int c = blockIdx.x;
    const int g = c >> 5, i = c & 31;
    const int t = threadIdx.x;
    float sum = 0.f, sq = 0.f;
    int total = 256 * nx;
    for (int e = t; e < total; e += 256) {
        int n = e / nx, xt = e - n * nx;
        size_t bid = ((size_t)(n * ng + g) * nx + xt) * 64;
        sum += partials[bid + i];
        sq  += partials[bid + 32 + i];
    }
    #pragma unroll
    for (int off = 32; off > 0; off >>= 1) {
        sum += __shfl_xor(sum, off);
        sq  += __shfl_xor(sq, off);
    }
    __shared__ float rs[4], rq[4];
    if ((t & 63) == 0) { rs[t >> 6] = sum; rq[t >> 6] = sq; }
    __syncthreads();
    if (t == 0) {
        sum = rs[0] + rs[1] + rs[2] + rs[3];
        sq  = rq[0] + rq[1] + rq[2] + rq[3];
        float mean = sum * inv_count;
        float var = sq * inv_count - mean * mean;
        float scale = gamma[c] * rsqrtf(var + 1e-5f);
        ss[c] = scale;
        ss[COUT + c] = beta[c] - mean * scale;
    }
}

// ---------------------------------------------------------------------------
// NHWC BN+ReLU + 2x2/2 maxpool, fp16 -> fp16.
// ---------------------------------------------------------------------------
template<int C>
__global__ __launch_bounds__(256) void pool_nhwc_kernel(
    const _Float16* __restrict__ in, const float* __restrict__ ss,
    _Float16* __restrict__ out, int HO, int total)
{
    int idx = blockIdx.x * 256 + threadIdx.x;
    if (idx >= total) return;
    int c8 = idx % (C / 8);
    int p = idx / (C / 8);
    int x = p % HO;
    int p2 = p / HO;
    int y = p2 % HO;
    int n = p2 / HO;
    int WI = 2 * HO;
    size_t b00 = (((size_t)n * WI + 2 * y) * WI + 2 * x) * C + c8 * 8;
    half8 v00 = *(const half8*)&in[b00];
    half8 v01 = *(const half8*)&in[b00 + C];
    half8 v10 = *(const half8*)&in[b00 + (size_t)WI * C];
    half8 v11 = *(const half8*)&in[b00 + (size_t)WI * C + C];
    half8 o;
    #pragma unroll
    for (int j = 0; j < 8; ++j) {
        int c = c8 * 8 + j;
        float sc = ss[c], sh = ss[C + c];
        float m = fmaxf(fmaxf((float)v00[j] * sc + sh, (float)v01[j] * sc + sh),
                        fmaxf((float)v10[j] * sc + sh, (float)v11[j] * sc + sh));
        o[j] = (_Float16)fmaxf(0.f, m);
    }
    *(half8*)&out[(((size_t)n * HO + y) * HO + x) * C + c8 * 8] = o;
}

// ---------------------------------------------------------------------------
// fc1 GEMM, K-split. A: NHWC fp16 pool2 (256,16,16,64), logical k=c*256+y*16+x
// ---------------------------------------------------------------------------
__global__ __launch_bounds__(256) void fc1_partial_kernel(
    const _Float16* __restrict__ A, const float* __restrict__ Bw, float* __restrict__ hp)
{
    __shared__ float As[64][33];
    __shared__ float Bs[32][33];
    const int t = threadIdx.x;
    const int n0 = blockIdx.x * 64;
    const int j0 = blockIdx.y * 32;
    const int k0 = blockIdx.z * 1024;
    const int j = t & 31;
    const int i0 = (t >> 5) * 8;
    float acc[8] = {0.f, 0.f, 0.f, 0.f, 0.f, 0.f, 0.f, 0.f};
    for (int ks = 0; ks < 1024; ks += 32) {
        __syncthreads();
        #pragma unroll
        for (int r = 0; r < 8; ++r) {
            int e = t + 256 * r;
            int row = e >> 5, kk = e & 31;
            int k = k0 + ks + kk;
            int c = k >> 8, yx = k & 255, y = yx >> 4, xx = yx & 15;
            As[row][kk] = (float)A[(((size_t)(n0 + row) * 16 + y) * 16 + xx) * 64 + c];
        }
        #pragma unroll
        for (int r = 0; r < 4; ++r) {
            int e = t + 256 * r;
            int row = e >> 5, kk = e & 31;
            Bs[row][kk] = Bw[(size_t)(j0 + row) * 16384 + k0 + ks + kk];
        }
        __syncthreads();
        #pragma unroll
        for (int kk = 0; kk < 32; ++kk) {
            float bv = Bs[j][kk];
            #pragma unroll
            for (int i = 0; i < 8; ++i) acc[i] += As[i0 + i][kk] * bv;
        }
    }
    #pragma unroll
    for (int i = 0; i < 8; ++i)
        hp[((size_t)blockIdx.z * 256 + n0 + i0 + i) * 128 + j0 + j] = acc[i];
}

__global__ __launch_bounds__(256) void fc1_reduce_kernel(
    const float* __restrict__ hp, const float* __restrict__ bias, float* __restrict__ h1)
{
    int gid = blockIdx.x * 256 + threadIdx.x;   // 32768
    int n = gid >> 7, j = gid & 127;
    float s = bias[j];
    #pragma unroll
    for (int kc = 0; kc < 16; ++kc) s += hp[((size_t)kc * 256 + n) * 128 + j];
    h1[gid] = fmaxf(0.f, s);
}

// ---------------------------------------------------------------------------
// fc2: (256,128) x (10,128)^T + b -> xq (256,10). One wave per batch element.
// ---------------------------------------------------------------------------
__global__ __launch_bounds__(64) void fc2_kernel(
    const float* __restrict__ h1, const float* __restrict__ w,
    const float* __restrict__ b, float* __restrict__ xq)
{
    int n = blockIdx.x, l = threadIdx.x;
    float a0 = h1[n * 128 + l], a1 = h1[n * 128 + 64 + l];
    float p[10];
    #pragma unroll
    for (int j = 0; j < 10; ++j)
        p[j] = w[j * 128 + l] * a0 + w[j * 128 + 64 + l] * a1;
    #pragma unroll
    for (int j = 0; j < 10; ++j) {
        #pragma unroll
        for (int off = 32; off > 0; off >>= 1) p[j] += __shfl_xor(p[j], off);
    }
    if (l == 0) {
        #pragma unroll
        for (int j = 0; j < 10; ++j) xq[n * 10 + j] = p[j] + b[j];
    }
}

// ---------------------------------------------------------------------------
// 10-qubit state-vector sim (1024 amplitudes in LDS) + Z expectations + head.
// ---------------------------------------------------------------------------
__global__ __launch_bounds__(256) void quantum_head_kernel(
    const float* __restrict__ xq, const float* __restrict__ qw,
    const float* __restrict__ head_w, const float* __restrict__ head_b,
    float* __restrict__ outp)
{
    __shared__ float sr[1024], si[1024];
    const int n = blockIdx.x, t = threadIdx.x;
    for (int i = t; i < 1024; i += 256) { sr[i] = 0.f; si[i] = 0.f; }
    __syncthreads();
    if (t == 0) sr[0] = 1.f;
    __syncthreads();

    for (int w = 0; w < 10; ++w) {
        float th = 0.5f * PI_F * xq[n * 10 + w];
        float c = cosf(th), s = sinf(th);
        int k = 9 - w, kb = 1 << k;
        #pragma unroll
        for (int pp = 0; pp < 2; ++pp) {
            int p = t + 256 * pp;
            int i0 = ((p >> k) << (k + 1)) | (p & (kb - 1));
            int i1 = i0 | kb;
            float ar = sr[i0], br = sr[i1], ai = si[i0], bi = si[i1];
            sr[i0] = c * ar - s * br;  si[i0] = c * ai - s * bi;
            sr[i1] = s * ar + c * br;  si[i1] = s * ai + c * bi;
        }
        __syncthreads();
    }

    for (int l = 0; l < 6; ++l) {
        for (int w = 0; w < 10; ++w) {
            const float* qp = qw + (l * 10 + w) * 3;
            float phi = qp[0], th = qp[1], om = qp[2];
            float c = cosf(0.5f * th), s = sinf(0.5f * th);
            float apo = 0.5f * (phi + om), amo = 0.5f * (phi - om);
            float cpo = cosf(apo), spo = sinf(apo);
            float cmo = cosf(amo), smo = sinf(amo);
            float m00r = cpo * c,  m00i = -spo * c;
            float m01r = -cmo * s, m01i = -smo * s;
            float m10r = cmo * s,  m10i = -smo * s;
            float m11r = cpo * c,  m11i = spo * c;
            int k = 9 - w, kb = 1 << k;
            #pragma unroll
            for (int pp = 0; pp < 2; ++pp) {
                int p = t + 256 * pp;
                int i0 = ((p >> k) << (k + 1)) | (p & (kb - 1));
                int i1 = i0 | kb;
                float ar = sr[i0], ai = si[i0], br = sr[i1], bi = si[i1];
                sr[i0] = m00r * ar - m00i * ai + m01r * br - m01i * bi;
                si[i0] = m00r * ai + m00i * ar + m01r * bi + m01i * br;
                sr[i1] = m10r * ar - m10i * ai + m11r * br - m11i * bi;
                si[i1] = m10r * ai + m10i * ar + m11r * bi + m11i * br;
            }
            __syncthreads();
        }
        int r = l % 9 + 1;
        float tr[4], ti[4];
        #pragma unroll
        for (int si_ = 0; si_ < 4; ++si_) {
            int i = t + 256 * si_;
            int jdx = i;
            #pragma unroll
            for (int w = 9; w >= 0; --w) {
                int tt = (w + r) % 10;
                int pc = 9 - w, pt = 9 - tt;
                jdx ^= ((jdx >> pc) & 1) << pt;
            }
            tr[si_] = sr[jdx]; ti[si_] = si[jdx];
        }
        __syncthreads();
        #pragma unroll
        for (int si_ = 0; si_ < 4; ++si_) {
            int i = t + 256 * si_;
            sr[i] = tr[si_]; si[i] = ti[si_];
        }
        __syncthreads();
    }

    float pk[10];
    #pragma unroll
    for (int w = 0; w < 10; ++w) pk[w] = 0.f;
    #pragma unroll
    for (int si_ = 0; si_ < 4; ++si_) {
        int i = t + 256 * si_;
        float pr = sr[i] * sr[i] + si[i] * si[i];
        #pragma unroll
        for (int w = 0; w < 10; ++w)
            pk[w] += ((i >> (9 - w)) & 1) ? -pr : pr;
    }
    __syncthreads();
    #pragma unroll
    for (int w = 0; w < 10; ++w) {
        #pragma unroll
        for (int off = 32; off > 0; off >>= 1) pk[w] += __shfl_xor(pk[w], off);
    }
    int wave = t >> 6, lane = t & 63;
    if (lane == 0) {
        #pragma unroll
        for (int w = 0; w < 10; ++w) sr[wave * 10 + w] = pk[w];
    }
    __syncthreads();
    if (t < 10) si[t] = sr[t] + sr[10 + t] + sr[20 + t] + sr[30 + t];
    __syncthreads();
    if (t < 10) {
        float o = head_b[t];
        #pragma unroll
        for (int kk = 0; kk < 10; ++kk) o += si[kk] * head_w[t * 10 + kk];
        outp[n * 10 + t] = o;
    }
}

// ---------------------------------------------------------------------------
// Workspace (≈139 MB): two 33.55M-half NHWC regions (ping-pong) + fp32 tail.
// H0: c1out -> pool1 -> c4out ; H1: c2out -> c3out -> pool2
// ---------------------------------------------------------------------------
extern "C" void kernel_launch(void* const* d_in, const int* in_sizes, int n_in,
                              void* d_out, int out_size, void* d_ws, size_t ws_size,
                              hipStream_t stream)
{
    const float* x   = (const float*)d_in[0];
    const float* c1w = (const float*)d_in[1];  const float* c1b = (const float*)d_in[2];
    const float* g1  = (const float*)d_in[3];  const float* b1  = (const float*)d_in[4];
    const float* c2w = (const float*)d_in[5];  const float* c2b = (const float*)d_in[6];
    const float* g2  = (const float*)d_in[7];  const float* b2  = (const float*)d_in[8];
    const float* c3w = (const float*)d_in[9];  const float* c3b = (const float*)d_in[10];
    const float* g3  = (const float*)d_in[11]; const float* b3  = (const float*)d_in[12];
    const float* c4w = (const float*)d_in[13]; const float* c4b = (const float*)d_in[14];
    const float* g4  = (const float*)d_in[15]; const float* b4  = (const float*)d_in[16];
    const float* f1w = (const float*)d_in[17]; const float* f1b = (const float*)d_in[18];
    const float* f2w = (const float*)d_in[19]; const float* f2b = (const float*)d_in[20];
    const float* qw  = (const float*)d_in[21];
    const float* hw  = (const float*)d_in[22]; const float* hb  = (const float*)d_in[23];

    float* ws = (float*)d_ws;
    _Float16* H0 = (_Float16*)ws;              // 33,554,432 halves
    _Float16* H1 = H0 + 33554432;              // 33,554,432 halves
    float* part = ws + 33554432;               // 524,288
    float* ss1  = part + 524288;               // 64
    float* ss2  = ss1 + 64;                    // 64
    float* ss3  = ss2 + 64;                    // 128
    float* ss4  = ss3 + 128;                   // 128
    float* hp   = ss4 + 128;                   // 524,288
    float* h1   = hp + 524288;                 // 32,768
    float* xqv  = h1 + 32768;                  // 2,560
    _Float16* wt2 = (_Float16*)(xqv + 2560);   // 9,216 halves
    _Float16* wt3 = wt2 + 9216;                // 18,432 halves
    _Float16* wt4 = wt3 + 18432;               // 36,864 halves

    // weight transforms (independent)
    wt_transform_kernel<<<252, 256, 0, stream>>>(c2w, c3w, c4w, wt2, wt3, wt4);

    // conv1: x -> H0 (256,64,64,32) NHWC fp16
    conv1_kernel<<<dim3(16, 1, 256), 256, 0, stream>>>(x, c1w, c1b, H0);
    // BN1 stats from H0
    stats_nhwc32_kernel<<<dim3(8, 1, 256), 256, 0, stream>>>(H0, part, 8);
    bn_finalize_kernel<<<32, 256, 0, stream>>>(part, 8, 1, 1.f / 1048576.f, g1, b1, ss1, 32);

    // conv2 (MFMA): bn1+relu(H0) -> H1 (256,64,64,32)
    conv_mfma_kernel<64, 32, 32><<<dim3(32, 1, 256), 256, 0, stream>>>(
        H0, wt2, c2b, ss1, H1, part);
    bn_finalize_kernel<<<32, 256, 0, stream>>>(part, 32, 1, 1.f / 1048576.f, g2, b2, ss2, 32);

    // pool1: bn2+relu(H1) pooled -> H0 (256,32,32,32)
    pool_nhwc_kernel<32><<<4096, 256, 0, stream>>>(H1, ss2, H0, 32, 1048576);

    // conv3 (MFMA): H0 (activated) -> H1 (256,32,32,64)
    conv_mfma_kernel<32, 32, 64><<<dim3(8, 2, 256), 256, 0, stream>>>(
        H0, wt3, c3b, nullptr, H1, part);
    bn_finalize_kernel<<<64, 256, 0, stream>>>(part, 8, 2, 1.f / 262144.f, g3, b3, ss3, 64);

    // conv4 (MFMA): bn3+relu(H1) -> H0 (256,32,32,64)
    conv_mfma_kernel<32, 64, 64><<<dim3(8, 2, 256), 256, 0, stream>>>(
        H1, wt4, c4b, ss3, H0, part);
    bn_finalize_kernel<<<64, 256, 0, stream>>>(part, 8, 2, 1.f / 262144.f, g4, b4, ss4, 64);

    // pool2: bn4+relu(H0) pooled -> H1 (256,16,16,64)
    pool_nhwc_kernel<64><<<2048, 256, 0, stream>>>(H0, ss4, H1, 16, 524288);

    // fc1 (K-split, NHWC-permuted A) + reduce -> h1 (256,128)
    fc1_partial_kernel<<<dim3(4, 4, 16), 256, 0, stream>>>(H1, f1w, hp);
    fc1_reduce_kernel<<<128, 256, 0, stream>>>(hp, f1b, h1);

    // fc2 -> xq (256,10)
    fc2_kernel<<<256, 64, 0, stream>>>(h1, f2w, f2b, xqv);

    // quantum circuit + head -> out (256,10)
    quantum_head_kernel<<<256, 256, 0, stream>>>(xqv, qw, hw, hb, (float*)d_out);
}

// Round 5
// 345.535 us; speedup vs baseline: 5.2331x; 1.2904x over previous
//
#include <hip/hip_runtime.h>
#include <math.h>

#define PI_F 3.14159265358979323846f

typedef __attribute__((ext_vector_type(8))) _Float16 half8;
typedef __attribute__((ext_vector_type(4))) float f32x4;

// ---------------------------------------------------------------------------
// conv1: fp32 VALU direct conv (CIN=3) -> NHWC fp16 (pre-BN), no stats.
// ---------------------------------------------------------------------------
__global__ __launch_bounds__(256) void conv1_kernel(
    const float* __restrict__ in, const float* __restrict__ wgt,
    const float* __restrict__ bias, _Float16* __restrict__ out)
{
    __shared__ __align__(16) float s_in[3][6][66];
    __shared__ __align__(16) float s_w[27][32];    // [ci*9+tap][co]
    __shared__ __align__(16) half8 s_out[256][5];  // [pixel][c8], +1 pad

    const int t = threadIdx.x;
    const int x = t & 63;
    const int y = t >> 6;                 // 0..3
    const int y0 = blockIdx.x * 4;
    const int n = blockIdx.z;

    for (int idx = t; idx < 3 * 6 * 66; idx += 256) {
        int xl = idx % 66;
        int r1 = idx / 66;
        int yl = r1 % 6;
        int ci = r1 / 6;
        int gy = y0 + yl - 1, gx = xl - 1;
        float v = 0.f;
        if (gy >= 0 && gy < 64 && gx >= 0 && gx < 64)
            v = in[((size_t)(n * 3 + ci) * 64 + gy) * 64 + gx];
        s_in[ci][yl][xl] = v;
    }
    for (int idx = t; idx < 27 * 32; idx += 256) {
        int co = idx & 31;
        int r = idx >> 5;
        s_w[r][co] = wgt[co * 27 + r];
    }
    __syncthreads();

    float acc[32];
    #pragma unroll
    for (int c = 0; c < 32; ++c) acc[c] = bias[c];

    #pragma unroll
    for (int ci = 0; ci < 3; ++ci) {
        #pragma unroll
        for (int dy = 0; dy < 3; ++dy) {
            #pragma unroll
            for (int dx = 0; dx < 3; ++dx) {
                float iv = s_in[ci][y + dy][x + dx];
                #pragma unroll
                for (int c4 = 0; c4 < 8; ++c4) {
                    float4 wv = *(const float4*)&s_w[ci * 9 + dy * 3 + dx][c4 * 4];
                    acc[c4 * 4 + 0] += wv.x * iv;
                    acc[c4 * 4 + 1] += wv.y * iv;
                    acc[c4 * 4 + 2] += wv.z * iv;
                    acc[c4 * 4 + 3] += wv.w * iv;
                }
            }
        }
    }

    #pragma unroll
    for (int c8 = 0; c8 < 4; ++c8) {
        half8 h;
        #pragma unroll
        for (int j = 0; j < 8; ++j) h[j] = (_Float16)acc[c8 * 8 + j];
        s_out[t][c8] = h;
    }
    __syncthreads();

    size_t base = ((size_t)n * 64 + y0) * 2048;
    #pragma unroll
    for (int r = 0; r < 4; ++r) {
        int e = r * 256 + t;
        *(half8*)&out[base + (size_t)e * 8] = s_out[e >> 2][e & 3];
    }
}

// ---------------------------------------------------------------------------
// Per-channel sum/sumsq over NHWC fp16 tensor with C=32. grid (nx, 1, 256).
// ---------------------------------------------------------------------------
__global__ __launch_bounds__(256) void stats_nhwc32_kernel(
    const _Float16* __restrict__ in, float* __restrict__ partials, int nx)
{
    __shared__ float s_red[64];
    const int t = threadIdx.x;
    const int xt = blockIdx.x;
    const int n = blockIdx.z;
    const int c8 = t & 3;

    float sum[8], sq[8];
    #pragma unroll
    for (int j = 0; j < 8; ++j) { sum[j] = 0.f; sq[j] = 0.f; }

    size_t base = (size_t)n * 131072 + (size_t)xt * 16384;
    #pragma unroll
    for (int r = 0; r < 8; ++r) {
        int e = r * 256 + t;
        half8 v = *(const half8*)&in[base + (size_t)e * 8];
        #pragma unroll
        for (int j = 0; j < 8; ++j) {
            float f = (float)v[j];
            sum[j] += f; sq[j] += f * f;
        }
    }
    #pragma unroll
    for (int off = 4; off <= 32; off <<= 1) {
        #pragma unroll
        for (int j = 0; j < 8; ++j) {
            sum[j] += __shfl_xor(sum[j], off);
            sq[j]  += __shfl_xor(sq[j], off);
        }
    }
    if (t < 64) s_red[t] = 0.f;
    __syncthreads();
    if ((t & 63) < 4) {
        #pragma unroll
        for (int j = 0; j < 8; ++j) {
            atomicAdd(&s_red[c8 * 8 + j], sum[j]);
            atomicAdd(&s_red[32 + c8 * 8 + j], sq[j]);
        }
    }
    __syncthreads();
    if (t < 64)
        partials[((size_t)n * nx + xt) * 64 + t] = s_red[t];
}

// ---------------------------------------------------------------------------
// Weight transform: [COUT][CIN][3][3] fp32 -> [COUT][9*CIN] fp16, k=(tap,ci)
// ---------------------------------------------------------------------------
__global__ __launch_bounds__(256) void wt_transform_kernel(
    const float* __restrict__ w2, const float* __restrict__ w3,
    const float* __restrict__ w4, _Float16* __restrict__ t2,
    _Float16* __restrict__ t3, _Float16* __restrict__ t4)
{
    int idx = blockIdx.x * 256 + threadIdx.x;
    if (idx < 9216) {
        int co = idx / 288, rem = idx % 288, tap = rem / 32, ci = rem % 32;
        t2[idx] = (_Float16)w2[(size_t)(co * 32 + ci) * 9 + tap];
    } else if (idx < 27648) {
        int e = idx - 9216;
        int co = e / 288, rem = e % 288, tap = rem / 32, ci = rem % 32;
        t3[e] = (_Float16)w3[(size_t)(co * 32 + ci) * 9 + tap];
    } else if (idx < 64512) {
        int e = idx - 27648;
        int co = e / 576, rem = e % 576, tap = rem / 64, ci = rem % 64;
        t4[e] = (_Float16)w4[(size_t)(co * 64 + ci) * 9 + tap];
    }
}

// ---------------------------------------------------------------------------
// fc1 weight transform: f1w [128][16384] fp32 NCHW-k -> w1t [128][16384] fp16
// NHWC-k: w1t[j][yx*64+c] = f1w[j][c*256+yx]. grid (4 yx-tiles, 128 j).
// ---------------------------------------------------------------------------
__global__ __launch_bounds__(256) void fc1w_transform_kernel(
    const float* __restrict__ w, _Float16* __restrict__ wt)
{
    __shared__ float lds[64][65];
    const int t = threadIdx.x;
    const int yx0 = blockIdx.x * 64;
    const int j = blockIdx.y;
    #pragma unroll
    for (int i = 0; i < 16; ++i) {
        int idx = t + 256 * i;
        int c = idx >> 6, yxl = idx & 63;
        lds[c][yxl] = w[(size_t)j * 16384 + c * 256 + yx0 + yxl];
    }
    __syncthreads();
    #pragma unroll
    for (int i = 0; i < 2; ++i) {
        int idx = t + 256 * i;
        int yxl = idx >> 3, c8 = idx & 7;
        half8 h;
        #pragma unroll
        for (int jj = 0; jj < 8; ++jj)
            h[jj] = (_Float16)lds[c8 * 8 + jj][yxl];
        *(half8*)&wt[(size_t)j * 16384 + (size_t)(yx0 + yxl) * 64 + c8 * 8] = h;
    }
}

// ---------------------------------------------------------------------------
// Implicit-GEMM 3x3 conv via MFMA f16. NHWC fp16 in/out (H=W).
// ---------------------------------------------------------------------------
template<int W, int CIN, int COUT>
__global__ __launch_bounds__(256) void conv_mfma_kernel(
    const _Float16* __restrict__ in, const _Float16* __restrict__ wt,
    const float* __restrict__ bias, const float* __restrict__ ss_in,
    _Float16* __restrict__ out, float* __restrict__ partials)
{
    constexpr int H = W;
    constexpr int ROWS = 128 / W;
    constexpr int CS = CIN + 8;
    constexpr int K = 9 * CIN;
    constexpr int KS = K + 8;
    constexpr int TR = ROWS + 2;
    constexpr int TC = W + 2;
    __shared__ __align__(16) _Float16 s_in[TR * TC * CS];
    __shared__ __align__(16) _Float16 s_w[32 * KS];
    __shared__ float s_red[64];

    const int t = threadIdx.x;
    const int row0 = blockIdx.x * ROWS;
    const int cout0 = blockIdx.y * 32;
    const int n = blockIdx.z;

    for (int idx = t; idx < 32 * (K / 8); idx += 256) {
        int k8 = idx % (K / 8);
        int co = idx / (K / 8);
        *(half8*)&s_w[co * KS + k8 * 8] =
            *(const half8*)&wt[(size_t)(cout0 + co) * K + k8 * 8];
    }
    for (int idx = t; idx < TR * TC * (CIN / 8); idx += 256) {
        int c8 = idx % (CIN / 8);
        int colr = idx / (CIN / 8);
        int col = colr % TC;
        int r = colr / TC;
        int gy = row0 + r - 1, gx = col - 1;
        half8 v;
        #pragma unroll
        for (int j = 0; j < 8; ++j) v[j] = (_Float16)0.f;
        if (gy >= 0 && gy < H && gx >= 0 && gx < W) {
            v = *(const half8*)&in[(((size_t)n * H + gy) * W + gx) * CIN + c8 * 8];
            if (ss_in) {
                #pragma unroll
                for (int j = 0; j < 8; ++j) {
                    int c = c8 * 8 + j;
                    float f = (float)v[j] * ss_in[c] + ss_in[CIN + c];
                    v[j] = (_Float16)fmaxf(0.f, f);
                }
            }
        }
        *(half8*)&s_in[(r * TC + col) * CS + c8 * 8] = v;
    }
    if (t < 64) s_red[t] = 0.f;
    __syncthreads();

    const int w = t >> 6, l = t & 63;
    const int lm = l & 15, lg = l >> 4;
    int rA[2], xA[2];
    #pragma unroll
    for (int f = 0; f < 2; ++f) {
        int m = w * 32 + f * 16 + lm;
        rA[f] = m / W;
        xA[f] = m % W;
    }
    f32x4 zero4 = {0.f, 0.f, 0.f, 0.f};
    f32x4 acc[2][2];
    acc[0][0] = zero4; acc[0][1] = zero4; acc[1][0] = zero4; acc[1][1] = zero4;

    #pragma unroll
    for (int ks = 0; ks < K; ks += 32) {
        const int tap = ks / CIN;
        const int ci0 = ks % CIN;
        const int dy = tap / 3, dx = tap % 3;
        half8 b0 = *(const half8*)&s_w[lm * KS + ks + lg * 8];
        half8 b1 = *(const half8*)&s_w[(lm + 16) * KS + ks + lg * 8];
        #pragma unroll
        for (int f = 0; f < 2; ++f) {
            half8 a = *(const half8*)&s_in[((rA[f] + dy) * TC + xA[f] + dx) * CS + ci0 + lg * 8];
            acc[f][0] = __builtin_amdgcn_mfma_f32_16x16x32_f16(a, b0, acc[f][0], 0, 0, 0);
            acc[f][1] = __builtin_amdgcn_mfma_f32_16x16x32_f16(a, b1, acc[f][1], 0, 0, 0);
        }
    }

    float bv0 = bias[cout0 + lm];
    float bv1 = bias[cout0 + 16 + lm];
    float s0 = 0.f, s20 = 0.f, s1 = 0.f, s21 = 0.f;
    #pragma unroll
    for (int f = 0; f < 2; ++f) {
        #pragma unroll
        for (int r = 0; r < 4; ++r) {
            int m = w * 32 + f * 16 + lg * 4 + r;
            int yy = row0 + m / W, xo = m % W;
            size_t base = (((size_t)n * H + yy) * W + xo) * COUT + cout0;
            float v0 = acc[f][0][r] + bv0;
            float v1 = acc[f][1][r] + bv1;
            out[base + lm] = (_Float16)v0;
            out[base + 16 + lm] = (_Float16)v1;
            s0 += v0; s20 += v0 * v0;
            s1 += v1; s21 += v1 * v1;
        }
    }
    s0 += __shfl_xor(s0, 16);  s0 += __shfl_xor(s0, 32);
    s1 += __shfl_xor(s1, 16);  s1 += __shfl_xor(s1, 32);
    s20 += __shfl_xor(s20, 16); s20 += __shfl_xor(s20, 32);
    s21 += __shfl_xor(s21, 16); s21 += __shfl_xor(s21, 32);
    if (l < 16) {
        atomicAdd(&s_red[lm], s0);
        atomicAdd(&s_red[16 + lm], s1);
        atomicAdd(&s_red[32 + lm], s20);
        atomicAdd(&s_red[48 + lm], s21);
    }
    __syncthreads();
    if (t < 64) {
        size_t bid = ((size_t)n * gridDim.y + blockIdx.y) * gridDim.x + blockIdx.x;
        partials[bid * 64 + t] = s_red[t];
    }
}

// ---------------------------------------------------------------------------
// Reduce per-block partials -> BN scale/shift. grid = COUT blocks.
// ---------------------------------------------------------------------------
__global__ __launch_bounds__(256) void bn_finalize_kernel(
    const float* __restrict__ partials, int nx, int ng, float inv_count,
    const float* __restrict__ gamma, const float* __restrict__ beta,
    float* __restrict__ ss, int COUT)
{
    const int c = blockIdx.x;
    const int g = c >> 5, i = c & 31;
    const int t = threadIdx.x;
    float sum = 0.f, sq = 0.f;
    int total = 256 * nx;
    for (int e = t; e < total; e += 256) {
        int n = e / nx, xt = e - n * nx;
        size_t bid = ((size_t)(n * ng + g) * nx + xt) * 64;
        sum += partials[bid + i];
        sq  += partials[bid + 32 + i];
    }
    #pragma unroll
    for (int off = 32; off > 0; off >>= 1) {
        sum += __shfl_xor(sum, off);
        sq  += __shfl_xor(sq, off);
    }
    __shared__ float rs[4], rq[4];
    if ((t & 63) == 0) { rs[t >> 6] = sum; rq[t >> 6] = sq; }
    __syncthreads();
    if (t == 0) {
        sum = rs[0] + rs[1] + rs[2] + rs[3];
        sq  = rq[0] + rq[1] + rq[2] + rq[3];
        float mean = sum * inv_count;
        float var = sq * inv_count - mean * mean;
        float scale = gamma[c] * rsqrtf(var + 1e-5f);
        ss[c] = scale;
        ss[COUT + c] = beta[c] - mean * scale;
    }
}

// ---------------------------------------------------------------------------
// NHWC BN+ReLU + 2x2/2 maxpool, fp16 -> fp16.
// ---------------------------------------------------------------------------
template<int C>
__global__ __launch_bounds__(256) void pool_nhwc_kernel(
    const _Float16* __restrict__ in, const float* __restrict__ ss,
    _Float16* __restrict__ out, int HO, int total)
{
    int idx = blockIdx.x * 256 + threadIdx.x;
    if (idx >= total) return;
    int c8 = idx % (C / 8);
    int p = idx / (C / 8);
    int x = p % HO;
    int p2 = p / HO;
    int y = p2 % HO;
    int n = p2 / HO;
    int WI = 2 * HO;
    size_t b00 = (((size_t)n * WI + 2 * y) * WI + 2 * x) * C + c8 * 8;
    half8 v00 = *(const half8*)&in[b00];
    half8 v01 = *(const half8*)&in[b00 + C];
    half8 v10 = *(const half8*)&in[b00 + (size_t)WI * C];
    half8 v11 = *(const half8*)&in[b00 + (size_t)WI * C + C];
    half8 o;
    #pragma unroll
    for (int j = 0; j < 8; ++j) {
        int c = c8 * 8 + j;
        float sc = ss[c], sh = ss[C + c];
        float m = fmaxf(fmaxf((float)v00[j] * sc + sh, (float)v01[j] * sc + sh),
                        fmaxf((float)v10[j] * sc + sh, (float)v11[j] * sc + sh));
        o[j] = (_Float16)fmaxf(0.f, m);
    }
    *(half8*)&out[(((size_t)n * HO + y) * HO + x) * C + c8 * 8] = o;
}

// ---------------------------------------------------------------------------
// fc1 MFMA GEMM (K-split): A (256,16384) fp16 NHWC-k x w1t (128,16384) fp16
// grid (4 m-tiles, 32 k-chunks of 512). Block: 4 waves, each 16 rows x 128 j.
// Partials hp[kc][n][j] fp32.
// ---------------------------------------------------------------------------
__global__ __launch_bounds__(256) void fc1_mfma_kernel(
    const _Float16* __restrict__ A, const _Float16* __restrict__ Bw,
    float* __restrict__ hp)
{
    __shared__ __align__(16) _Float16 As[64][72];
    __shared__ __align__(16) _Float16 Bs[128][72];
    const int t = threadIdx.x;
    const int mt = blockIdx.x;
    const int kc = blockIdx.y;
    const int w = t >> 6, l = t & 63;
    const int lm = l & 15, lg = l >> 4;

    f32x4 zero4 = {0.f, 0.f, 0.f, 0.f};
    f32x4 acc[8];
    #pragma unroll
    for (int nb = 0; nb < 8; ++nb) acc[nb] = zero4;

    const size_t a_base = (size_t)(mt * 64) * 16384 + (size_t)kc * 512;
    const size_t b_base = (size_t)kc * 512;

    for (int p = 0; p < 8; ++p) {
        __syncthreads();
        #pragma unroll
        for (int i = 0; i < 2; ++i) {
            int idx = t + 256 * i;
            int r = idx >> 3, c8 = idx & 7;
            *(half8*)&As[r][c8 * 8] =
                *(const half8*)&A[a_base + (size_t)r * 16384 + p * 64 + c8 * 8];
        }
        #pragma unroll
        for (int i = 0; i < 4; ++i) {
            int idx = t + 256 * i;
            int r = idx >> 3, c8 = idx & 7;
            *(half8*)&Bs[r][c8 * 8] =
                *(const half8*)&Bw[b_base + (size_t)r * 16384 + p * 64 + c8 * 8];
        }
        __syncthreads();
        #pragma unroll
        for (int ks = 0; ks < 64; ks += 32) {
            half8 a = *(const half8*)&As[w * 16 + lm][ks + lg * 8];
            #pragma unroll
            for (int nb = 0; nb < 8; ++nb) {
                half8 b = *(const half8*)&Bs[nb * 16 + lm][ks + lg * 8];
                acc[nb] = __builtin_amdgcn_mfma_f32_16x16x32_f16(a, b, acc[nb], 0, 0, 0);
            }
        }
    }
    #pragma unroll
    for (int nb = 0; nb < 8; ++nb) {
        #pragma unroll
        for (int r = 0; r < 4; ++r) {
            int row = mt * 64 + w * 16 + lg * 4 + r;
            hp[((size_t)kc * 256 + row) * 128 + nb * 16 + lm] = acc[nb][r];
        }
    }
}

__global__ __launch_bounds__(256) void fc1_reduce_kernel(
    const float* __restrict__ hp, const float* __restrict__ bias, float* __restrict__ h1)
{
    int gid = blockIdx.x * 256 + threadIdx.x;   // 32768
    int n = gid >> 7, j = gid & 127;
    float s = bias[j];
    #pragma unroll
    for (int kc = 0; kc < 32; ++kc) s += hp[((size_t)kc * 256 + n) * 128 + j];
    h1[gid] = fmaxf(0.f, s);
}

// ---------------------------------------------------------------------------
// fc2: (256,128) x (10,128)^T + b -> xq (256,10). One wave per batch element.
// ---------------------------------------------------------------------------
__global__ __launch_bounds__(64) void fc2_kernel(
    const float* __restrict__ h1, const float* __restrict__ w,
    const float* __restrict__ b, float* __restrict__ xq)
{
    int n = blockIdx.x, l = threadIdx.x;
    float a0 = h1[n * 128 + l], a1 = h1[n * 128 + 64 + l];
    float p[10];
    #pragma unroll
    for (int j = 0; j < 10; ++j)
        p[j] = w[j * 128 + l] * a0 + w[j * 128 + 64 + l] * a1;
    #pragma unroll
    for (int j = 0; j < 10; ++j) {
        #pragma unroll
        for (int off = 32; off > 0; off >>= 1) p[j] += __shfl_xor(p[j], off);
    }
    if (l == 0) {
        #pragma unroll
        for (int j = 0; j < 10; ++j) xq[n * 10 + j] = p[j] + b[j];
    }
}

// ---------------------------------------------------------------------------
// 10-qubit state-vector sim (1024 amplitudes in LDS) + Z expectations + head.
// ---------------------------------------------------------------------------
__global__ __launch_bounds__(256) void quantum_head_kernel(
    const float* __restrict__ xq, const float* __restrict__ qw,
    const float* __restrict__ head_w, const float* __restrict__ head_b,
    float* __restrict__ outp)
{
    __shared__ float sr[1024], si[1024];
    const int n = blockIdx.x, t = threadIdx.x;
    for (int i = t; i < 1024; i += 256) { sr[i] = 0.f; si[i] = 0.f; }
    __syncthreads();
    if (t == 0) sr[0] = 1.f;
    __syncthreads();

    for (int w = 0; w < 10; ++w) {
        float th = 0.5f * PI_F * xq[n * 10 + w];
        float c = cosf(th), s = sinf(th);
        int k = 9 - w, kb = 1 << k;
        #pragma unroll
        for (int pp = 0; pp < 2; ++pp) {
            int p = t + 256 * pp;
            int i0 = ((p >> k) << (k + 1)) | (p & (kb - 1));
            int i1 = i0 | kb;
            float ar = sr[i0], br = sr[i1], ai = si[i0], bi = si[i1];
            sr[i0] = c * ar - s * br;  si[i0] = c * ai - s * bi;
            sr[i1] = s * ar + c * br;  si[i1] = s * ai + c * bi;
        }
        __syncthreads();
    }

    for (int l = 0; l < 6; ++l) {
        for (int w = 0; w < 10; ++w) {
            const float* qp = qw + (l * 10 + w) * 3;
            float phi = qp[0], th = qp[1], om = qp[2];
            float c = cosf(0.5f * th), s = sinf(0.5f * th);
            float apo = 0.5f * (phi + om), amo = 0.5f * (phi - om);
            float cpo = cosf(apo), spo = sinf(apo);
            float cmo = cosf(amo), smo = sinf(amo);
            float m00r = cpo * c,  m00i = -spo * c;
            float m01r = -cmo * s, m01i = -smo * s;
            float m10r = cmo * s,  m10i = -smo * s;
            float m11r = cpo * c,  m11i = spo * c;
            int k = 9 - w, kb = 1 << k;
            #pragma unroll
            for (int pp = 0; pp < 2; ++pp) {
                int p = t + 256 * pp;
                int i0 = ((p >> k) << (k + 1)) | (p & (kb - 1));
                int i1 = i0 | kb;
                float ar = sr[i0], ai = si[i0], br = sr[i1], bi = si[i1];
                sr[i0] = m00r * ar - m00i * ai + m01r * br - m01i * bi;
                si[i0] = m00r * ai + m00i * ar + m01r * bi + m01i * br;
                sr[i1] = m10r * ar - m10i * ai + m11r * br - m11i * bi;
                si[i1] = m10r * ai + m10i * ar + m11r * bi + m11i * br;
            }
            __syncthreads();
        }
        int r = l % 9 + 1;
        float tr[4], ti[4];
        #pragma unroll
        for (int si_ = 0; si_ < 4; ++si_) {
            int i = t + 256 * si_;
            int jdx = i;
            #pragma unroll
            for (int w = 9; w >= 0; --w) {
                int tt = (w + r) % 10;
                int pc = 9 - w, pt = 9 - tt;
                jdx ^= ((jdx >> pc) & 1) << pt;
            }
            tr[si_] = sr[jdx]; ti[si_] = si[jdx];
        }
        __syncthreads();
        #pragma unroll
        for (int si_ = 0; si_ < 4; ++si_) {
            int i = t + 256 * si_;
            sr[i] = tr[si_]; si[i] = ti[si_];
        }
        __syncthreads();
    }

    float pk[10];
    #pragma unroll
    for (int w = 0; w < 10; ++w) pk[w] = 0.f;
    #pragma unroll
    for (int si_ = 0; si_ < 4; ++si_) {
        int i = t + 256 * si_;
        float pr = sr[i] * sr[i] + si[i] * si[i];
        #pragma unroll
        for (int w = 0; w < 10; ++w)
            pk[w] += ((i >> (9 - w)) & 1) ? -pr : pr;
    }
    __syncthreads();
    #pragma unroll
    for (int w = 0; w < 10; ++w) {
        #pragma unroll
        for (int off = 32; off > 0; off >>= 1) pk[w] += __shfl_xor(pk[w], off);
    }
    int wave = t >> 6, lane = t & 63;
    if (lane == 0) {
        #pragma unroll
        for (int w = 0; w < 10; ++w) sr[wave * 10 + w] = pk[w];
    }
    __syncthreads();
    if (t < 10) si[t] = sr[t] + sr[10 + t] + sr[20 + t] + sr[30 + t];
    __syncthreads();
    if (t < 10) {
        float o = head_b[t];
        #pragma unroll
        for (int kk = 0; kk < 10; ++kk) o += si[kk] * head_w[t * 10 + kk];
        outp[n * 10 + t] = o;
    }
}

// ---------------------------------------------------------------------------
// Workspace (≈145 MB)
// ---------------------------------------------------------------------------
extern "C" void kernel_launch(void* const* d_in, const int* in_sizes, int n_in,
                              void* d_out, int out_size, void* d_ws, size_t ws_size,
                              hipStream_t stream)
{
    const float* x   = (const float*)d_in[0];
    const float* c1w = (const float*)d_in[1];  const float* c1b = (const float*)d_in[2];
    const float* g1  = (const float*)d_in[3];  const float* b1  = (const float*)d_in[4];
    const float* c2w = (const float*)d_in[5];  const float* c2b = (const float*)d_in[6];
    const float* g2  = (const float*)d_in[7];  const float* b2  = (const float*)d_in[8];
    const float* c3w = (const float*)d_in[9];  const float* c3b = (const float*)d_in[10];
    const float* g3  = (const float*)d_in[11]; const float* b3  = (const float*)d_in[12];
    const float* c4w = (const float*)d_in[13]; const float* c4b = (const float*)d_in[14];
    const float* g4  = (const float*)d_in[15]; const float* b4  = (const float*)d_in[16];
    const float* f1w = (const float*)d_in[17]; const float* f1b = (const float*)d_in[18];
    const float* f2w = (const float*)d_in[19]; const float* f2b = (const float*)d_in[20];
    const float* qw  = (const float*)d_in[21];
    const float* hw  = (const float*)d_in[22]; const float* hb  = (const float*)d_in[23];

    float* ws = (float*)d_ws;
    _Float16* H0 = (_Float16*)ws;              // 33,554,432 halves
    _Float16* H1 = H0 + 33554432;              // 33,554,432 halves
    float* part = ws + 33554432;               // 524,288
    float* ss1  = part + 524288;               // 64
    float* ss2  = ss1 + 64;                    // 64
    float* ss3  = ss2 + 64;                    // 128
    float* ss4  = ss3 + 128;                   // 128
    float* hp   = ss4 + 128;                   // 1,048,576 (32*256*128)
    float* h1   = hp + 1048576;                // 32,768
    float* xqv  = h1 + 32768;                  // 2,560
    _Float16* wt2 = (_Float16*)(xqv + 2560);   // 9,216 halves
    _Float16* wt3 = wt2 + 9216;                // 18,432 halves
    _Float16* wt4 = wt3 + 18432;               // 36,864 halves
    _Float16* w1t = wt4 + 36864;               // 2,097,152 halves

    // one-time weight transforms (independent)
    wt_transform_kernel<<<252, 256, 0, stream>>>(c2w, c3w, c4w, wt2, wt3, wt4);
    fc1w_transform_kernel<<<dim3(4, 128), 256, 0, stream>>>(f1w, w1t);

    // conv1: x -> H0 (256,64,64,32) NHWC fp16
    conv1_kernel<<<dim3(16, 1, 256), 256, 0, stream>>>(x, c1w, c1b, H0);
    stats_nhwc32_kernel<<<dim3(8, 1, 256), 256, 0, stream>>>(H0, part, 8);
    bn_finalize_kernel<<<32, 256, 0, stream>>>(part, 8, 1, 1.f / 1048576.f, g1, b1, ss1, 32);

    // conv2 (MFMA): bn1+relu(H0) -> H1 (256,64,64,32)
    conv_mfma_kernel<64, 32, 32><<<dim3(32, 1, 256), 256, 0, stream>>>(
        H0, wt2, c2b, ss1, H1, part);
    bn_finalize_kernel<<<32, 256, 0, stream>>>(part, 32, 1, 1.f / 1048576.f, g2, b2, ss2, 32);

    // pool1: bn2+relu(H1) pooled -> H0 (256,32,32,32)
    pool_nhwc_kernel<32><<<4096, 256, 0, stream>>>(H1, ss2, H0, 32, 1048576);

    // conv3 (MFMA): H0 (activated) -> H1 (256,32,32,64)
    conv_mfma_kernel<32, 32, 64><<<dim3(8, 2, 256), 256, 0, stream>>>(
        H0, wt3, c3b, nullptr, H1, part);
    bn_finalize_kernel<<<64, 256, 0, stream>>>(part, 8, 2, 1.f / 262144.f, g3, b3, ss3, 64);

    // conv4 (MFMA): bn3+relu(H1) -> H0 (256,32,32,64)
    conv_mfma_kernel<32, 64, 64><<<dim3(8, 2, 256), 256, 0, stream>>>(
        H1, wt4, c4b, ss3, H0, part);
    bn_finalize_kernel<<<64, 256, 0, stream>>>(part, 8, 2, 1.f / 262144.f, g4, b4, ss4, 64);

    // pool2: bn4+relu(H0) pooled -> H1 (256,16,16,64) == A matrix for fc1
    pool_nhwc_kernel<64><<<2048, 256, 0, stream>>>(H0, ss4, H1, 16, 524288);

    // fc1: MFMA GEMM K-split + reduce -> h1 (256,128)
    fc1_mfma_kernel<<<dim3(4, 32), 256, 0, stream>>>(H1, w1t, hp);
    fc1_reduce_kernel<<<128, 256, 0, stream>>>(hp, f1b, h1);

    // fc2 -> xq (256,10)
    fc2_kernel<<<256, 64, 0, stream>>>(h1, f2w, f2b, xqv);

    // quantum circuit + head -> out (256,10)
    quantum_head_kernel<<<256, 256, 0, stream>>>(xqv, qw, hw, hb, (float*)d_out);
}

// Round 6
// 301.110 us; speedup vs baseline: 6.0052x; 1.1475x over previous
//
#include <hip/hip_runtime.h>
#include <math.h>

#define PI_F 3.14159265358979323846f

typedef __attribute__((ext_vector_type(8))) _Float16 half8;
typedef __attribute__((ext_vector_type(4))) float f32x4;

// ---------------------------------------------------------------------------
// conv1: fp32 VALU direct conv (CIN=3) -> NHWC fp16 (pre-BN), no stats.
// ---------------------------------------------------------------------------
__global__ __launch_bounds__(256) void conv1_kernel(
    const float* __restrict__ in, const float* __restrict__ wgt,
    const float* __restrict__ bias, _Float16* __restrict__ out)
{
    __shared__ __align__(16) float s_in[3][6][66];
    __shared__ __align__(16) float s_w[27][32];    // [ci*9+tap][co]
    __shared__ __align__(16) half8 s_out[256][5];  // [pixel][c8], +1 pad

    const int t = threadIdx.x;
    const int x = t & 63;
    const int y = t >> 6;                 // 0..3
    const int y0 = blockIdx.x * 4;
    const int n = blockIdx.z;

    for (int idx = t; idx < 3 * 6 * 66; idx += 256) {
        int xl = idx % 66;
        int r1 = idx / 66;
        int yl = r1 % 6;
        int ci = r1 / 6;
        int gy = y0 + yl - 1, gx = xl - 1;
        float v = 0.f;
        if (gy >= 0 && gy < 64 && gx >= 0 && gx < 64)
            v = in[((size_t)(n * 3 + ci) * 64 + gy) * 64 + gx];
        s_in[ci][yl][xl] = v;
    }
    for (int idx = t; idx < 27 * 32; idx += 256) {
        int co = idx & 31;
        int r = idx >> 5;
        s_w[r][co] = wgt[co * 27 + r];
    }
    __syncthreads();

    float acc[32];
    #pragma unroll
    for (int c = 0; c < 32; ++c) acc[c] = bias[c];

    #pragma unroll
    for (int ci = 0; ci < 3; ++ci) {
        #pragma unroll
        for (int dy = 0; dy < 3; ++dy) {
            #pragma unroll
            for (int dx = 0; dx < 3; ++dx) {
                float iv = s_in[ci][y + dy][x + dx];
                #pragma unroll
                for (int c4 = 0; c4 < 8; ++c4) {
                    float4 wv = *(const float4*)&s_w[ci * 9 + dy * 3 + dx][c4 * 4];
                    acc[c4 * 4 + 0] += wv.x * iv;
                    acc[c4 * 4 + 1] += wv.y * iv;
                    acc[c4 * 4 + 2] += wv.z * iv;
                    acc[c4 * 4 + 3] += wv.w * iv;
                }
            }
        }
    }

    #pragma unroll
    for (int c8 = 0; c8 < 4; ++c8) {
        half8 h;
        #pragma unroll
        for (int j = 0; j < 8; ++j) h[j] = (_Float16)acc[c8 * 8 + j];
        s_out[t][c8] = h;
    }
    __syncthreads();

    size_t base = ((size_t)n * 64 + y0) * 2048;
    #pragma unroll
    for (int r = 0; r < 4; ++r) {
        int e = r * 256 + t;
        *(half8*)&out[base + (size_t)e * 8] = s_out[e >> 2][e & 3];
    }
}

// ---------------------------------------------------------------------------
// Per-channel sum/sumsq over NHWC fp16 tensor with C=32. grid (nx, 1, 256).
// ---------------------------------------------------------------------------
__global__ __launch_bounds__(256) void stats_nhwc32_kernel(
    const _Float16* __restrict__ in, float* __restrict__ partials, int nx)
{
    __shared__ float s_red[64];
    const int t = threadIdx.x;
    const int xt = blockIdx.x;
    const int n = blockIdx.z;
    const int c8 = t & 3;

    float sum[8], sq[8];
    #pragma unroll
    for (int j = 0; j < 8; ++j) { sum[j] = 0.f; sq[j] = 0.f; }

    size_t base = (size_t)n * 131072 + (size_t)xt * 16384;
    #pragma unroll
    for (int r = 0; r < 8; ++r) {
        int e = r * 256 + t;
        half8 v = *(const half8*)&in[base + (size_t)e * 8];
        #pragma unroll
        for (int j = 0; j < 8; ++j) {
            float f = (float)v[j];
            sum[j] += f; sq[j] += f * f;
        }
    }
    #pragma unroll
    for (int off = 4; off <= 32; off <<= 1) {
        #pragma unroll
        for (int j = 0; j < 8; ++j) {
            sum[j] += __shfl_xor(sum[j], off);
            sq[j]  += __shfl_xor(sq[j], off);
        }
    }
    if (t < 64) s_red[t] = 0.f;
    __syncthreads();
    if ((t & 63) < 4) {
        #pragma unroll
        for (int j = 0; j < 8; ++j) {
            atomicAdd(&s_red[c8 * 8 + j], sum[j]);
            atomicAdd(&s_red[32 + c8 * 8 + j], sq[j]);
        }
    }
    __syncthreads();
    if (t < 64)
        partials[((size_t)n * nx + xt) * 64 + t] = s_red[t];
}

// ---------------------------------------------------------------------------
// Weight transform to channel-blocked layout:
// out[((g*(K/8)+k8)*32+co)*8+j] = w[((g*32+co)*CIN + ci)*9 + tap],
// where k = k8*8+j, tap = k/CIN, ci = k%CIN.
// ---------------------------------------------------------------------------
__global__ __launch_bounds__(256) void wt_transform_kernel(
    const float* __restrict__ w2, const float* __restrict__ w3,
    const float* __restrict__ w4, _Float16* __restrict__ t2,
    _Float16* __restrict__ t3, _Float16* __restrict__ t4)
{
    int idx = blockIdx.x * 256 + threadIdx.x;
    if (idx < 9216) {               // conv2: K=288, CIN=32, 1 group
        int j = idx & 7, co = (idx >> 3) & 31, k8 = idx >> 8;
        int k = k8 * 8 + j, tap = k >> 5, ci = k & 31;
        t2[idx] = (_Float16)w2[(size_t)(co * 32 + ci) * 9 + tap];
    } else if (idx < 27648) {       // conv3: K=288, CIN=32, 2 groups
        int e = idx - 9216;
        int j = e & 7, co = (e >> 3) & 31, k8g = e >> 8;
        int k8 = k8g % 36, g = k8g / 36;
        int k = k8 * 8 + j, tap = k >> 5, ci = k & 31;
        t3[e] = (_Float16)w3[(size_t)((g * 32 + co) * 32 + ci) * 9 + tap];
    } else if (idx < 64512) {       // conv4: K=576, CIN=64, 2 groups
        int e = idx - 27648;
        int j = e & 7, co = (e >> 3) & 31, k8g = e >> 8;
        int k8 = k8g % 72, g = k8g / 72;
        int k = k8 * 8 + j, tap = k >> 6, ci = k & 63;
        t4[e] = (_Float16)w4[(size_t)((g * 32 + co) * 64 + ci) * 9 + tap];
    }
}

// ---------------------------------------------------------------------------
// fc1 weight transform: f1w [128][16384] fp32 NCHW-k -> w1t [128][16384] fp16
// NHWC-k: w1t[j][yx*64+c] = f1w[j][c*256+yx]. grid (4 yx-tiles, 128 j).
// ---------------------------------------------------------------------------
__global__ __launch_bounds__(256) void fc1w_transform_kernel(
    const float* __restrict__ w, _Float16* __restrict__ wt)
{
    __shared__ float lds[64][65];
    const int t = threadIdx.x;
    const int yx0 = blockIdx.x * 64;
    const int j = blockIdx.y;
    #pragma unroll
    for (int i = 0; i < 16; ++i) {
        int idx = t + 256 * i;
        int c = idx >> 6, yxl = idx & 63;
        lds[c][yxl] = w[(size_t)j * 16384 + c * 256 + yx0 + yxl];
    }
    __syncthreads();
    #pragma unroll
    for (int i = 0; i < 2; ++i) {
        int idx = t + 256 * i;
        int yxl = idx >> 3, c8 = idx & 7;
        half8 h;
        #pragma unroll
        for (int jj = 0; jj < 8; ++jj)
            h[jj] = (_Float16)lds[c8 * 8 + jj][yxl];
        *(half8*)&wt[(size_t)j * 16384 + (size_t)(yx0 + yxl) * 64 + c8 * 8] = h;
    }
}

// ---------------------------------------------------------------------------
// Implicit-GEMM 3x3 conv via MFMA f16. NHWC fp16 in/out (H=W).
// Block: 256 spatial x 32 cout, 4 waves; each wave 64 spatial x 32 cout.
// LDS layouts channel-blocked (conflict-free):
//   s_in[c8][pixel][8h], s_w[k8][co][8h] (weights pre-arranged on device).
// Per K-step: 4 A-reads + 2 B-reads -> 8 MFMAs.
// ---------------------------------------------------------------------------
template<int W, int CIN, int COUT>
__global__ __launch_bounds__(256) void conv_mfma_kernel(
    const _Float16* __restrict__ in, const _Float16* __restrict__ wt,
    const float* __restrict__ bias, const float* __restrict__ ss_in,
    _Float16* __restrict__ out, float* __restrict__ partials)
{
    constexpr int H = W;
    constexpr int ROWS = 256 / W;
    constexpr int TR = ROWS + 2;
    constexpr int TC = W + 2;
    constexpr int NPIX = TR * TC;
    constexpr int K = 9 * CIN;
    constexpr int C8N = CIN / 8;
    __shared__ __align__(16) _Float16 s_in[NPIX * CIN];   // (c8*NPIX + p)*8
    __shared__ __align__(16) _Float16 s_w[K * 32];        // (k8*32 + co)*8
    __shared__ float s_red[64];

    const int t = threadIdx.x;
    const int row0 = blockIdx.x * ROWS;
    const int g = blockIdx.y;
    const int cout0 = g * 32;
    const int n = blockIdx.z;

    // ---- stage weights: linear coalesced copy (pre-arranged layout) ----
    const _Float16* wg = wt + (size_t)g * K * 32;
    for (int idx = t; idx < K * 4; idx += 256)
        *(half8*)&s_w[idx * 8] = *(const half8*)&wg[(size_t)idx * 8];

    // ---- stage input tile: coalesced global, blocked LDS ----
    for (int idx = t; idx < NPIX * C8N; idx += 256) {
        int c8 = idx & (C8N - 1);
        int p = idx / C8N;
        int col = p % TC, r = p / TC;
        int gy = row0 + r - 1, gx = col - 1;
        half8 v;
        #pragma unroll
        for (int j = 0; j < 8; ++j) v[j] = (_Float16)0.f;
        if (gy >= 0 && gy < H && gx >= 0 && gx < W) {
            v = *(const half8*)&in[(((size_t)n * H + gy) * W + gx) * CIN + c8 * 8];
            if (ss_in) {
                #pragma unroll
                for (int j = 0; j < 8; ++j) {
                    int c = c8 * 8 + j;
                    float f = (float)v[j] * ss_in[c] + ss_in[CIN + c];
                    v[j] = (_Float16)fmaxf(0.f, f);
                }
            }
        }
        *(half8*)&s_in[(c8 * NPIX + p) * 8] = v;
    }
    if (t < 64) s_red[t] = 0.f;
    __syncthreads();

    const int w = t >> 6, l = t & 63;
    const int lm = l & 15, lg = l >> 4;
    int pA[4];   // pixel index (no halo offset) per fragment
    #pragma unroll
    for (int f = 0; f < 4; ++f) {
        int m = w * 64 + f * 16 + lm;
        pA[f] = (m / W) * TC + (m % W);
    }
    f32x4 zero4 = {0.f, 0.f, 0.f, 0.f};
    f32x4 acc[4][2];
    #pragma unroll
    for (int f = 0; f < 4; ++f) { acc[f][0] = zero4; acc[f][1] = zero4; }

    #pragma unroll
    for (int ks = 0; ks < K; ks += 32) {
        constexpr int dummy = 0; (void)dummy;
        const int tap = ks / CIN;
        const int ci0 = ks % CIN;
        const int dy = tap / 3, dx = tap % 3;
        const int poff = dy * TC + dx;
        const int c8b = ci0 / 8 + lg;
        half8 b0 = *(const half8*)&s_w[((ks / 8 + lg) * 32 + lm) * 8];
        half8 b1 = *(const half8*)&s_w[((ks / 8 + lg) * 32 + 16 + lm) * 8];
        #pragma unroll
        for (int f = 0; f < 4; ++f) {
            half8 a = *(const half8*)&s_in[(c8b * NPIX + pA[f] + poff) * 8];
            acc[f][0] = __builtin_amdgcn_mfma_f32_16x16x32_f16(a, b0, acc[f][0], 0, 0, 0);
            acc[f][1] = __builtin_amdgcn_mfma_f32_16x16x32_f16(a, b1, acc[f][1], 0, 0, 0);
        }
    }

    // ---- bias + NHWC fp16 store + stats ----
    float bv0 = bias[cout0 + lm];
    float bv1 = bias[cout0 + 16 + lm];
    float s0 = 0.f, s20 = 0.f, s1 = 0.f, s21 = 0.f;
    #pragma unroll
    for (int f = 0; f < 4; ++f) {
        #pragma unroll
        for (int r = 0; r < 4; ++r) {
            int m = w * 64 + f * 16 + lg * 4 + r;
            int yy = row0 + m / W, xo = m % W;
            size_t base = (((size_t)n * H + yy) * W + xo) * COUT + cout0;
            float v0 = acc[f][0][r] + bv0;
            float v1 = acc[f][1][r] + bv1;
            out[base + lm] = (_Float16)v0;
            out[base + 16 + lm] = (_Float16)v1;
            s0 += v0; s20 += v0 * v0;
            s1 += v1; s21 += v1 * v1;
        }
    }
    s0 += __shfl_xor(s0, 16);  s0 += __shfl_xor(s0, 32);
    s1 += __shfl_xor(s1, 16);  s1 += __shfl_xor(s1, 32);
    s20 += __shfl_xor(s20, 16); s20 += __shfl_xor(s20, 32);
    s21 += __shfl_xor(s21, 16); s21 += __shfl_xor(s21, 32);
    if (l < 16) {
        atomicAdd(&s_red[lm], s0);
        atomicAdd(&s_red[16 + lm], s1);
        atomicAdd(&s_red[32 + lm], s20);
        atomicAdd(&s_red[48 + lm], s21);
    }
    __syncthreads();
    if (t < 64) {
        size_t bid = ((size_t)n * gridDim.y + blockIdx.y) * gridDim.x + blockIdx.x;
        partials[bid * 64 + t] = s_red[t];
    }
}

// ---------------------------------------------------------------------------
// Reduce per-block partials -> BN scale/shift. grid = COUT blocks.
// ---------------------------------------------------------------------------
__global__ __launch_bounds__(256) void bn_finalize_kernel(
    const float* __restrict__ partials, int nx, int ng, float inv_count,
    const float* __restrict__ gamma, const float* __restrict__ beta,
    float* __restrict__ ss, int COUT)
{
    const int c = blockIdx.x;
    const int g = c >> 5, i = c & 31;
    const int t = threadIdx.x;
    float sum = 0.f, sq = 0.f;
    int total = 256 * nx;
    for (int e = t; e < total; e += 256) {
        int n = e / nx, xt = e - n * nx;
        size_t bid = ((size_t)(n * ng + g) * nx + xt) * 64;
        sum += partials[bid + i];
        sq  += partials[bid + 32 + i];
    }
    #pragma unroll
    for (int off = 32; off > 0; off >>= 1) {
        sum += __shfl_xor(sum, off);
        sq  += __shfl_xor(sq, off);
    }
    __shared__ float rs[4], rq[4];
    if ((t & 63) == 0) { rs[t >> 6] = sum; rq[t >> 6] = sq; }
    __syncthreads();
    if (t == 0) {
        sum = rs[0] + rs[1] + rs[2] + rs[3];
        sq  = rq[0] + rq[1] + rq[2] + rq[3];
        float mean = sum * inv_count;
        float var = sq * inv_count - mean * mean;
        float scale = gamma[c] * rsqrtf(var + 1e-5f);
        ss[c] = scale;
        ss[COUT + c] = beta[c] - mean * scale;
    }
}

// ---------------------------------------------------------------------------
// NHWC BN+ReLU + 2x2/2 maxpool, fp16 -> fp16.
// ---------------------------------------------------------------------------
template<int C>
__global__ __launch_bounds__(256) void pool_nhwc_kernel(
    const _Float16* __restrict__ in, const float* __restrict__ ss,
    _Float16* __restrict__ out, int HO, int total)
{
    int idx = blockIdx.x * 256 + threadIdx.x;
    if (idx >= total) return;
    int c8 = idx % (C / 8);
    int p = idx / (C / 8);
    int x = p % HO;
    int p2 = p / HO;
    int y = p2 % HO;
    int n = p2 / HO;
    int WI = 2 * HO;
    size_t b00 = (((size_t)n * WI + 2 * y) * WI + 2 * x) * C + c8 * 8;
    half8 v00 = *(const half8*)&in[b00];
    half8 v01 = *(const half8*)&in[b00 + C];
    half8 v10 = *(const half8*)&in[b00 + (size_t)WI * C];
    half8 v11 = *(const half8*)&in[b00 + (size_t)WI * C + C];
    half8 o;
    #pragma unroll
    for (int j = 0; j < 8; ++j) {
        int c = c8 * 8 + j;
        float sc = ss[c], sh = ss[C + c];
        float m = fmaxf(fmaxf((float)v00[j] * sc + sh, (float)v01[j] * sc + sh),
                        fmaxf((float)v10[j] * sc + sh, (float)v11[j] * sc + sh));
        o[j] = (_Float16)fmaxf(0.f, m);
    }
    *(half8*)&out[(((size_t)n * HO + y) * HO + x) * C + c8 * 8] = o;
}

// ---------------------------------------------------------------------------
// fc1 MFMA GEMM (K-split): A (256,16384) fp16 NHWC-k x w1t (128,16384) fp16
// ---------------------------------------------------------------------------
__global__ __launch_bounds__(256) void fc1_mfma_kernel(
    const _Float16* __restrict__ A, const _Float16* __restrict__ Bw,
    float* __restrict__ hp)
{
    __shared__ __align__(16) _Float16 As[64][72];
    __shared__ __align__(16) _Float16 Bs[128][72];
    const int t = threadIdx.x;
    const int mt = blockIdx.x;
    const int kc = blockIdx.y;
    const int w = t >> 6, l = t & 63;
    const int lm = l & 15, lg = l >> 4;

    f32x4 zero4 = {0.f, 0.f, 0.f, 0.f};
    f32x4 acc[8];
    #pragma unroll
    for (int nb = 0; nb < 8; ++nb) acc[nb] = zero4;

    const size_t a_base = (size_t)(mt * 64) * 16384 + (size_t)kc * 512;
    const size_t b_base = (size_t)kc * 512;

    for (int p = 0; p < 8; ++p) {
        __syncthreads();
        #pragma unroll
        for (int i = 0; i < 2; ++i) {
            int idx = t + 256 * i;
            int r = idx >> 3, c8 = idx & 7;
            *(half8*)&As[r][c8 * 8] =
                *(const half8*)&A[a_base + (size_t)r * 16384 + p * 64 + c8 * 8];
        }
        #pragma unroll
        for (int i = 0; i < 4; ++i) {
            int idx = t + 256 * i;
            int r = idx >> 3, c8 = idx & 7;
            *(half8*)&Bs[r][c8 * 8] =
                *(const half8*)&Bw[b_base + (size_t)r * 16384 + p * 64 + c8 * 8];
        }
        __syncthreads();
        #pragma unroll
        for (int ks = 0; ks < 64; ks += 32) {
            half8 a = *(const half8*)&As[w * 16 + lm][ks + lg * 8];
            #pragma unroll
            for (int nb = 0; nb < 8; ++nb) {
                half8 b = *(const half8*)&Bs[nb * 16 + lm][ks + lg * 8];
                acc[nb] = __builtin_amdgcn_mfma_f32_16x16x32_f16(a, b, acc[nb], 0, 0, 0);
            }
        }
    }
    #pragma unroll
    for (int nb = 0; nb < 8; ++nb) {
        #pragma unroll
        for (int r = 0; r < 4; ++r) {
            int row = mt * 64 + w * 16 + lg * 4 + r;
            hp[((size_t)kc * 256 + row) * 128 + nb * 16 + lm] = acc[nb][r];
        }
    }
}

__global__ __launch_bounds__(256) void fc1_reduce_kernel(
    const float* __restrict__ hp, const float* __restrict__ bias, float* __restrict__ h1)
{
    int gid = blockIdx.x * 256 + threadIdx.x;   // 32768
    int n = gid >> 7, j = gid & 127;
    float s = bias[j];
    #pragma unroll
    for (int kc = 0; kc < 32; ++kc) s += hp[((size_t)kc * 256 + n) * 128 + j];
    h1[gid] = fmaxf(0.f, s);
}

// ---------------------------------------------------------------------------
// fc2: (256,128) x (10,128)^T + b -> xq (256,10). One wave per batch element.
// ---------------------------------------------------------------------------
__global__ __launch_bounds__(64) void fc2_kernel(
    const float* __restrict__ h1, const float* __restrict__ w,
    const float* __restrict__ b, float* __restrict__ xq)
{
    int n = blockIdx.x, l = threadIdx.x;
    float a0 = h1[n * 128 + l], a1 = h1[n * 128 + 64 + l];
    float p[10];
    #pragma unroll
    for (int j = 0; j < 10; ++j)
        p[j] = w[j * 128 + l] * a0 + w[j * 128 + 64 + l] * a1;
    #pragma unroll
    for (int j = 0; j < 10; ++j) {
        #pragma unroll
        for (int off = 32; off > 0; off >>= 1) p[j] += __shfl_xor(p[j], off);
    }
    if (l == 0) {
        #pragma unroll
        for (int j = 0; j < 10; ++j) xq[n * 10 + j] = p[j] + b[j];
    }
}

// ---------------------------------------------------------------------------
// 10-qubit state-vector sim (1024 amplitudes in LDS) + Z expectations + head.
// ---------------------------------------------------------------------------
__global__ __launch_bounds__(256) void quantum_head_kernel(
    const float* __restrict__ xq, const float* __restrict__ qw,
    const float* __restrict__ head_w, const float* __restrict__ head_b,
    float* __restrict__ outp)
{
    __shared__ float sr[1024], si[1024];
    const int n = blockIdx.x, t = threadIdx.x;
    for (int i = t; i < 1024; i += 256) { sr[i] = 0.f; si[i] = 0.f; }
    __syncthreads();
    if (t == 0) sr[0] = 1.f;
    __syncthreads();

    for (int w = 0; w < 10; ++w) {
        float th = 0.5f * PI_F * xq[n * 10 + w];
        float c = cosf(th), s = sinf(th);
        int k = 9 - w, kb = 1 << k;
        #pragma unroll
        for (int pp = 0; pp < 2; ++pp) {
            int p = t + 256 * pp;
            int i0 = ((p >> k) << (k + 1)) | (p & (kb - 1));
            int i1 = i0 | kb;
            float ar = sr[i0], br = sr[i1], ai = si[i0], bi = si[i1];
            sr[i0] = c * ar - s * br;  si[i0] = c * ai - s * bi;
            sr[i1] = s * ar + c * br;  si[i1] = s * ai + c * bi;
        }
        __syncthreads();
    }

    for (int l = 0; l < 6; ++l) {
        for (int w = 0; w < 10; ++w) {
            const float* qp = qw + (l * 10 + w) * 3;
            float phi = qp[0], th = qp[1], om = qp[2];
            float c = cosf(0.5f * th), s = sinf(0.5f * th);
            float apo = 0.5f * (phi + om), amo = 0.5f * (phi - om);
            float cpo = cosf(apo), spo = sinf(apo);
            float cmo = cosf(amo), smo = sinf(amo);
            float m00r = cpo * c,  m00i = -spo * c;
            float m01r = -cmo * s, m01i = -smo * s;
            float m10r = cmo * s,  m10i = -smo * s;
            float m11r = cpo * c,  m11i = spo * c;
            int k = 9 - w, kb = 1 << k;
            #pragma unroll
            for (int pp = 0; pp < 2; ++pp) {
                int p = t + 256 * pp;
                int i0 = ((p >> k) << (k + 1)) | (p & (kb - 1));
                int i1 = i0 | kb;
                float ar = sr[i0], ai = si[i0], br = sr[i1], bi = si[i1];
                sr[i0] = m00r * ar - m00i * ai + m01r * br - m01i * bi;
                si[i0] = m00r * ai + m00i * ar + m01r * bi + m01i * br;
                sr[i1] = m10r * ar - m10i * ai + m11r * br - m11i * bi;
                si[i1] = m10r * ai + m10i * ar + m11r * bi + m11i * br;
            }
            __syncthreads();
        }
        int r = l % 9 + 1;
        float tr[4], ti[4];
        #pragma unroll
        for (int si_ = 0; si_ < 4; ++si_) {
            int i = t + 256 * si_;
            int jdx = i;
            #pragma unroll
            for (int w = 9; w >= 0; --w) {
                int tt = (w + r) % 10;
                int pc = 9 - w, pt = 9 - tt;
                jdx ^= ((jdx >> pc) & 1) << pt;
            }
            tr[si_] = sr[jdx]; ti[si_] = si[jdx];
        }
        __syncthreads();
        #pragma unroll
        for (int si_ = 0; si_ < 4; ++si_) {
            int i = t + 256 * si_;
            sr[i] = tr[si_]; si[i] = ti[si_];
        }
        __syncthreads();
    }

    float pk[10];
    #pragma unroll
    for (int w = 0; w < 10; ++w) pk[w] = 0.f;
    #pragma unroll
    for (int si_ = 0; si_ < 4; ++si_) {
        int i = t + 256 * si_;
        float pr = sr[i] * sr[i] + si[i] * si[i];
        #pragma unroll
        for (int w = 0; w < 10; ++w)
            pk[w] += ((i >> (9 - w)) & 1) ? -pr : pr;
    }
    __syncthreads();
    #pragma unroll
    for (int w = 0; w < 10; ++w) {
        #pragma unroll
        for (int off = 32; off > 0; off >>= 1) pk[w] += __shfl_xor(pk[w], off);
    }
    int wave = t >> 6, lane = t & 63;
    if (lane == 0) {
        #pragma unroll
        for (int w = 0; w < 10; ++w) sr[wave * 10 + w] = pk[w];
    }
    __syncthreads();
    if (t < 10) si[t] = sr[t] + sr[10 + t] + sr[20 + t] + sr[30 + t];
    __syncthreads();
    if (t < 10) {
        float o = head_b[t];
        #pragma unroll
        for (int kk = 0; kk < 10; ++kk) o += si[kk] * head_w[t * 10 + kk];
        outp[n * 10 + t] = o;
    }
}

// ---------------------------------------------------------------------------
// Workspace (≈145 MB)
// ---------------------------------------------------------------------------
extern "C" void kernel_launch(void* const* d_in, const int* in_sizes, int n_in,
                              void* d_out, int out_size, void* d_ws, size_t ws_size,
                              hipStream_t stream)
{
    const float* x   = (const float*)d_in[0];
    const float* c1w = (const float*)d_in[1];  const float* c1b = (const float*)d_in[2];
    const float* g1  = (const float*)d_in[3];  const float* b1  = (const float*)d_in[4];
    const float* c2w = (const float*)d_in[5];  const float* c2b = (const float*)d_in[6];
    const float* g2  = (const float*)d_in[7];  const float* b2  = (const float*)d_in[8];
    const float* c3w = (const float*)d_in[9];  const float* c3b = (const float*)d_in[10];
    const float* g3  = (const float*)d_in[11]; const float* b3  = (const float*)d_in[12];
    const float* c4w = (const float*)d_in[13]; const float* c4b = (const float*)d_in[14];
    const float* g4  = (const float*)d_in[15]; const float* b4  = (const float*)d_in[16];
    const float* f1w = (const float*)d_in[17]; const float* f1b = (const float*)d_in[18];
    const float* f2w = (const float*)d_in[19]; const float* f2b = (const float*)d_in[20];
    const float* qw  = (const float*)d_in[21];
    const float* hw  = (const float*)d_in[22]; const float* hb  = (const float*)d_in[23];

    float* ws = (float*)d_ws;
    _Float16* H0 = (_Float16*)ws;              // 33,554,432 halves
    _Float16* H1 = H0 + 33554432;              // 33,554,432 halves
    float* part = ws + 33554432;               // 524,288
    float* ss1  = part + 524288;               // 64
    float* ss2  = ss1 + 64;                    // 64
    float* ss3  = ss2 + 64;                    // 128
    float* ss4  = ss3 + 128;                   // 128
    float* hp   = ss4 + 128;                   // 1,048,576 (32*256*128)
    float* h1   = hp + 1048576;                // 32,768
    float* xqv  = h1 + 32768;                  // 2,560
    _Float16* wt2 = (_Float16*)(xqv + 2560);   // 9,216 halves
    _Float16* wt3 = wt2 + 9216;                // 18,432 halves
    _Float16* wt4 = wt3 + 18432;               // 36,864 halves
    _Float16* w1t = wt4 + 36864;               // 2,097,152 halves

    // one-time weight transforms (independent)
    wt_transform_kernel<<<252, 256, 0, stream>>>(c2w, c3w, c4w, wt2, wt3, wt4);
    fc1w_transform_kernel<<<dim3(4, 128), 256, 0, stream>>>(f1w, w1t);

    // conv1: x -> H0 (256,64,64,32) NHWC fp16
    conv1_kernel<<<dim3(16, 1, 256), 256, 0, stream>>>(x, c1w, c1b, H0);
    stats_nhwc32_kernel<<<dim3(8, 1, 256), 256, 0, stream>>>(H0, part, 8);
    bn_finalize_kernel<<<32, 256, 0, stream>>>(part, 8, 1, 1.f / 1048576.f, g1, b1, ss1, 32);

    // conv2 (MFMA): bn1+relu(H0) -> H1 (256,64,64,32)
    conv_mfma_kernel<64, 32, 32><<<dim3(16, 1, 256), 256, 0, stream>>>(
        H0, wt2, c2b, ss1, H1, part);
    bn_finalize_kernel<<<32, 256, 0, stream>>>(part, 16, 1, 1.f / 1048576.f, g2, b2, ss2, 32);

    // pool1: bn2+relu(H1) pooled -> H0 (256,32,32,32)
    pool_nhwc_kernel<32><<<4096, 256, 0, stream>>>(H1, ss2, H0, 32, 1048576);

    // conv3 (MFMA): H0 (activated) -> H1 (256,32,32,64)
    conv_mfma_kernel<32, 32, 64><<<dim3(4, 2, 256), 256, 0, stream>>>(
        H0, wt3, c3b, nullptr, H1, part);
    bn_finalize_kernel<<<64, 256, 0, stream>>>(part, 4, 2, 1.f / 262144.f, g3, b3, ss3, 64);

    // conv4 (MFMA): bn3+relu(H1) -> H0 (256,32,32,64)
    conv_mfma_kernel<32, 64, 64><<<dim3(4, 2, 256), 256, 0, stream>>>(
        H1, wt4, c4b, ss3, H0, part);
    bn_finalize_kernel<<<64, 256, 0, stream>>>(part, 4, 2, 1.f / 262144.f, g4, b4, ss4, 64);

    // pool2: bn4+relu(H0) pooled -> H1 (256,16,16,64) == A matrix for fc1
    pool_nhwc_kernel<64><<<2048, 256, 0, stream>>>(H0, ss4, H1, 16, 524288);

    // fc1: MFMA GEMM K-split + reduce -> h1 (256,128)
    fc1_mfma_kernel<<<dim3(4, 32), 256, 0, stream>>>(H1, w1t, hp);
    fc1_reduce_kernel<<<128, 256, 0, stream>>>(hp, f1b, h1);

    // fc2 -> xq (256,10)
    fc2_kernel<<<256, 64, 0, stream>>>(h1, f2w, f2b, xqv);

    // quantum circuit + head -> out (256,10)
    quantum_head_kernel<<<256, 256, 0, stream>>>(xqv, qw, hw, hb, (float*)d_out);
}

// Round 7
// 281.740 us; speedup vs baseline: 6.4181x; 1.0688x over previous
//
#include <hip/hip_runtime.h>
#include <math.h>

#define PI_F 3.14159265358979323846f

typedef __attribute__((ext_vector_type(8))) _Float16 half8;
typedef __attribute__((ext_vector_type(4))) float f32x4;

// ---------------------------------------------------------------------------
// conv1: fp32 VALU direct conv (CIN=3) -> NHWC fp16 (pre-BN), no stats.
// ---------------------------------------------------------------------------
__global__ __launch_bounds__(256) void conv1_kernel(
    const float* __restrict__ in, const float* __restrict__ wgt,
    const float* __restrict__ bias, _Float16* __restrict__ out)
{
    __shared__ __align__(16) float s_in[3][6][66];
    __shared__ __align__(16) float s_w[27][32];    // [ci*9+tap][co]
    __shared__ __align__(16) half8 s_out[256][5];  // [pixel][c8], +1 pad

    const int t = threadIdx.x;
    const int x = t & 63;
    const int y = t >> 6;                 // 0..3
    const int y0 = blockIdx.x * 4;
    const int n = blockIdx.z;

    for (int idx = t; idx < 3 * 6 * 66; idx += 256) {
        int xl = idx % 66;
        int r1 = idx / 66;
        int yl = r1 % 6;
        int ci = r1 / 6;
        int gy = y0 + yl - 1, gx = xl - 1;
        float v = 0.f;
        if (gy >= 0 && gy < 64 && gx >= 0 && gx < 64)
            v = in[((size_t)(n * 3 + ci) * 64 + gy) * 64 + gx];
        s_in[ci][yl][xl] = v;
    }
    for (int idx = t; idx < 27 * 32; idx += 256) {
        int co = idx & 31;
        int r = idx >> 5;
        s_w[r][co] = wgt[co * 27 + r];
    }
    __syncthreads();

    float acc[32];
    #pragma unroll
    for (int c = 0; c < 32; ++c) acc[c] = bias[c];

    #pragma unroll
    for (int ci = 0; ci < 3; ++ci) {
        #pragma unroll
        for (int dy = 0; dy < 3; ++dy) {
            #pragma unroll
            for (int dx = 0; dx < 3; ++dx) {
                float iv = s_in[ci][y + dy][x + dx];
                #pragma unroll
                for (int c4 = 0; c4 < 8; ++c4) {
                    float4 wv = *(const float4*)&s_w[ci * 9 + dy * 3 + dx][c4 * 4];
                    acc[c4 * 4 + 0] += wv.x * iv;
                    acc[c4 * 4 + 1] += wv.y * iv;
                    acc[c4 * 4 + 2] += wv.z * iv;
                    acc[c4 * 4 + 3] += wv.w * iv;
                }
            }
        }
    }

    #pragma unroll
    for (int c8 = 0; c8 < 4; ++c8) {
        half8 h;
        #pragma unroll
        for (int j = 0; j < 8; ++j) h[j] = (_Float16)acc[c8 * 8 + j];
        s_out[t][c8] = h;
    }
    __syncthreads();

    size_t base = ((size_t)n * 64 + y0) * 2048;
    #pragma unroll
    for (int r = 0; r < 4; ++r) {
        int e = r * 256 + t;
        *(half8*)&out[base + (size_t)e * 8] = s_out[e >> 2][e & 3];
    }
}

// ---------------------------------------------------------------------------
// Per-channel sum/sumsq over NHWC fp16 tensor with C=32. grid (nx, 1, 256).
// ---------------------------------------------------------------------------
__global__ __launch_bounds__(256) void stats_nhwc32_kernel(
    const _Float16* __restrict__ in, float* __restrict__ partials, int nx)
{
    __shared__ float s_red[64];
    const int t = threadIdx.x;
    const int xt = blockIdx.x;
    const int n = blockIdx.z;
    const int c8 = t & 3;

    float sum[8], sq[8];
    #pragma unroll
    for (int j = 0; j < 8; ++j) { sum[j] = 0.f; sq[j] = 0.f; }

    size_t base = (size_t)n * 131072 + (size_t)xt * 16384;
    #pragma unroll
    for (int r = 0; r < 8; ++r) {
        int e = r * 256 + t;
        half8 v = *(const half8*)&in[base + (size_t)e * 8];
        #pragma unroll
        for (int j = 0; j < 8; ++j) {
            float f = (float)v[j];
            sum[j] += f; sq[j] += f * f;
        }
    }
    #pragma unroll
    for (int off = 4; off <= 32; off <<= 1) {
        #pragma unroll
        for (int j = 0; j < 8; ++j) {
            sum[j] += __shfl_xor(sum[j], off);
            sq[j]  += __shfl_xor(sq[j], off);
        }
    }
    if (t < 64) s_red[t] = 0.f;
    __syncthreads();
    if ((t & 63) < 4) {
        #pragma unroll
        for (int j = 0; j < 8; ++j) {
            atomicAdd(&s_red[c8 * 8 + j], sum[j]);
            atomicAdd(&s_red[32 + c8 * 8 + j], sq[j]);
        }
    }
    __syncthreads();
    if (t < 64)
        partials[((size_t)n * nx + xt) * 64 + t] = s_red[t];
}

// ---------------------------------------------------------------------------
// Weight transform to channel-blocked layout.
// ---------------------------------------------------------------------------
__global__ __launch_bounds__(256) void wt_transform_kernel(
    const float* __restrict__ w2, const float* __restrict__ w3,
    const float* __restrict__ w4, _Float16* __restrict__ t2,
    _Float16* __restrict__ t3, _Float16* __restrict__ t4)
{
    int idx = blockIdx.x * 256 + threadIdx.x;
    if (idx < 9216) {               // conv2: K=288, CIN=32, 1 group
        int j = idx & 7, co = (idx >> 3) & 31, k8 = idx >> 8;
        int k = k8 * 8 + j, tap = k >> 5, ci = k & 31;
        t2[idx] = (_Float16)w2[(size_t)(co * 32 + ci) * 9 + tap];
    } else if (idx < 27648) {       // conv3: K=288, CIN=32, 2 groups
        int e = idx - 9216;
        int j = e & 7, co = (e >> 3) & 31, k8g = e >> 8;
        int k8 = k8g % 36, g = k8g / 36;
        int k = k8 * 8 + j, tap = k >> 5, ci = k & 31;
        t3[e] = (_Float16)w3[(size_t)((g * 32 + co) * 32 + ci) * 9 + tap];
    } else if (idx < 64512) {       // conv4: K=576, CIN=64, 2 groups
        int e = idx - 27648;
        int j = e & 7, co = (e >> 3) & 31, k8g = e >> 8;
        int k8 = k8g % 72, g = k8g / 72;
        int k = k8 * 8 + j, tap = k >> 6, ci = k & 63;
        t4[e] = (_Float16)w4[(size_t)((g * 32 + co) * 64 + ci) * 9 + tap];
    }
}

// ---------------------------------------------------------------------------
// fc1 weight transform: f1w [128][16384] fp32 NCHW-k -> w1t fp16 NHWC-k.
// ---------------------------------------------------------------------------
__global__ __launch_bounds__(256) void fc1w_transform_kernel(
    const float* __restrict__ w, _Float16* __restrict__ wt)
{
    __shared__ float lds[64][65];
    const int t = threadIdx.x;
    const int yx0 = blockIdx.x * 64;
    const int j = blockIdx.y;
    #pragma unroll
    for (int i = 0; i < 16; ++i) {
        int idx = t + 256 * i;
        int c = idx >> 6, yxl = idx & 63;
        lds[c][yxl] = w[(size_t)j * 16384 + c * 256 + yx0 + yxl];
    }
    __syncthreads();
    #pragma unroll
    for (int i = 0; i < 2; ++i) {
        int idx = t + 256 * i;
        int yxl = idx >> 3, c8 = idx & 7;
        half8 h;
        #pragma unroll
        for (int jj = 0; jj < 8; ++jj)
            h[jj] = (_Float16)lds[c8 * 8 + jj][yxl];
        *(half8*)&wt[(size_t)j * 16384 + (size_t)(yx0 + yxl) * 64 + c8 * 8] = h;
    }
}

// ---------------------------------------------------------------------------
// quantum_prep: 60 Rot matrices (8 fl each) + 6x1024 u16 perm table.
// Depends only on qw -> launched first, L2-resident for the final kernel.
// ---------------------------------------------------------------------------
__global__ __launch_bounds__(256) void quantum_prep_kernel(
    const float* __restrict__ qw, float* __restrict__ rotm,
    unsigned short* __restrict__ perm)
{
    int t = threadIdx.x;
    if (t < 60) {
        float phi = qw[t * 3], th = qw[t * 3 + 1], om = qw[t * 3 + 2];
        float c = cosf(0.5f * th), s = sinf(0.5f * th);
        float apo = 0.5f * (phi + om), amo = 0.5f * (phi - om);
        float cpo = cosf(apo), spo = sinf(apo);
        float cmo = cosf(amo), smo = sinf(amo);
        rotm[t * 8 + 0] = cpo * c;  rotm[t * 8 + 1] = -spo * c;
        rotm[t * 8 + 2] = -cmo * s; rotm[t * 8 + 3] = -smo * s;
        rotm[t * 8 + 4] = cmo * s;  rotm[t * 8 + 5] = -smo * s;
        rotm[t * 8 + 6] = cpo * c;  rotm[t * 8 + 7] = spo * c;
    }
    for (int e = t; e < 6144; e += 256) {
        int layer = e >> 10, i = e & 1023;
        int r = layer % 9 + 1;
        int jdx = i;
        for (int w = 9; w >= 0; --w) {
            int tt = (w + r) % 10;
            int pc = 9 - w, pt_ = 9 - tt;
            jdx ^= ((jdx >> pc) & 1) << pt_;
        }
        perm[e] = (unsigned short)jdx;
    }
}

// ---------------------------------------------------------------------------
// Implicit-GEMM 3x3 conv via MFMA f16 (channel-blocked LDS, conflict-free).
// ---------------------------------------------------------------------------
template<int W, int CIN, int COUT>
__global__ __launch_bounds__(256) void conv_mfma_kernel(
    const _Float16* __restrict__ in, const _Float16* __restrict__ wt,
    const float* __restrict__ bias, const float* __restrict__ ss_in,
    _Float16* __restrict__ out, float* __restrict__ partials)
{
    constexpr int H = W;
    constexpr int ROWS = 256 / W;
    constexpr int TR = ROWS + 2;
    constexpr int TC = W + 2;
    constexpr int NPIX = TR * TC;
    constexpr int K = 9 * CIN;
    constexpr int C8N = CIN / 8;
    __shared__ __align__(16) _Float16 s_in[NPIX * CIN];   // (c8*NPIX + p)*8
    __shared__ __align__(16) _Float16 s_w[K * 32];        // (k8*32 + co)*8
    __shared__ float s_red[64];

    const int t = threadIdx.x;
    const int row0 = blockIdx.x * ROWS;
    const int g = blockIdx.y;
    const int cout0 = g * 32;
    const int n = blockIdx.z;

    const _Float16* wg = wt + (size_t)g * K * 32;
    for (int idx = t; idx < K * 4; idx += 256)
        *(half8*)&s_w[idx * 8] = *(const half8*)&wg[(size_t)idx * 8];

    for (int idx = t; idx < NPIX * C8N; idx += 256) {
        int c8 = idx & (C8N - 1);
        int p = idx / C8N;
        int col = p % TC, r = p / TC;
        int gy = row0 + r - 1, gx = col - 1;
        half8 v;
        #pragma unroll
        for (int j = 0; j < 8; ++j) v[j] = (_Float16)0.f;
        if (gy >= 0 && gy < H && gx >= 0 && gx < W) {
            v = *(const half8*)&in[(((size_t)n * H + gy) * W + gx) * CIN + c8 * 8];
            if (ss_in) {
                #pragma unroll
                for (int j = 0; j < 8; ++j) {
                    int c = c8 * 8 + j;
                    float f = (float)v[j] * ss_in[c] + ss_in[CIN + c];
                    v[j] = (_Float16)fmaxf(0.f, f);
                }
            }
        }
        *(half8*)&s_in[(c8 * NPIX + p) * 8] = v;
    }
    if (t < 64) s_red[t] = 0.f;
    __syncthreads();

    const int w = t >> 6, l = t & 63;
    const int lm = l & 15, lg = l >> 4;
    int pA[4];
    #pragma unroll
    for (int f = 0; f < 4; ++f) {
        int m = w * 64 + f * 16 + lm;
        pA[f] = (m / W) * TC + (m % W);
    }
    f32x4 zero4 = {0.f, 0.f, 0.f, 0.f};
    f32x4 acc[4][2];
    #pragma unroll
    for (int f = 0; f < 4; ++f) { acc[f][0] = zero4; acc[f][1] = zero4; }

    #pragma unroll
    for (int ks = 0; ks < K; ks += 32) {
        const int tap = ks / CIN;
        const int ci0 = ks % CIN;
        const int dy = tap / 3, dx = tap % 3;
        const int poff = dy * TC + dx;
        const int c8b = ci0 / 8 + lg;
        half8 b0 = *(const half8*)&s_w[((ks / 8 + lg) * 32 + lm) * 8];
        half8 b1 = *(const half8*)&s_w[((ks / 8 + lg) * 32 + 16 + lm) * 8];
        #pragma unroll
        for (int f = 0; f < 4; ++f) {
            half8 a = *(const half8*)&s_in[(c8b * NPIX + pA[f] + poff) * 8];
            acc[f][0] = __builtin_amdgcn_mfma_f32_16x16x32_f16(a, b0, acc[f][0], 0, 0, 0);
            acc[f][1] = __builtin_amdgcn_mfma_f32_16x16x32_f16(a, b1, acc[f][1], 0, 0, 0);
        }
    }

    float bv0 = bias[cout0 + lm];
    float bv1 = bias[cout0 + 16 + lm];
    float s0 = 0.f, s20 = 0.f, s1 = 0.f, s21 = 0.f;
    #pragma unroll
    for (int f = 0; f < 4; ++f) {
        #pragma unroll
        for (int r = 0; r < 4; ++r) {
            int m = w * 64 + f * 16 + lg * 4 + r;
            int yy = row0 + m / W, xo = m % W;
            size_t base = (((size_t)n * H + yy) * W + xo) * COUT + cout0;
            float v0 = acc[f][0][r] + bv0;
            float v1 = acc[f][1][r] + bv1;
            out[base + lm] = (_Float16)v0;
            out[base + 16 + lm] = (_Float16)v1;
            s0 += v0; s20 += v0 * v0;
            s1 += v1; s21 += v1 * v1;
        }
    }
    s0 += __shfl_xor(s0, 16);  s0 += __shfl_xor(s0, 32);
    s1 += __shfl_xor(s1, 16);  s1 += __shfl_xor(s1, 32);
    s20 += __shfl_xor(s20, 16); s20 += __shfl_xor(s20, 32);
    s21 += __shfl_xor(s21, 16); s21 += __shfl_xor(s21, 32);
    if (l < 16) {
        atomicAdd(&s_red[lm], s0);
        atomicAdd(&s_red[16 + lm], s1);
        atomicAdd(&s_red[32 + lm], s20);
        atomicAdd(&s_red[48 + lm], s21);
    }
    __syncthreads();
    if (t < 64) {
        size_t bid = ((size_t)n * gridDim.y + blockIdx.y) * gridDim.x + blockIdx.x;
        partials[bid * 64 + t] = s_red[t];
    }
}

// ---------------------------------------------------------------------------
// Reduce per-block partials -> BN scale/shift. grid = COUT blocks.
// ---------------------------------------------------------------------------
__global__ __launch_bounds__(256) void bn_finalize_kernel(
    const float* __restrict__ partials, int nx, int ng, float inv_count,
    const float* __restrict__ gamma, const float* __restrict__ beta,
    float* __restrict__ ss, int COUT)
{
    const int c = blockIdx.x;
    const int g = c >> 5, i = c & 31;
    const int t = threadIdx.x;
    float sum = 0.f, sq = 0.f;
    int total = 256 * nx;
    for (int e = t; e < total; e += 256) {
        int n = e / nx, xt = e - n * nx;
        size_t bid = ((size_t)(n * ng + g) * nx + xt) * 64;
        sum += partials[bid + i];
        sq  += partials[bid + 32 + i];
    }
    #pragma unroll
    for (int off = 32; off > 0; off >>= 1) {
        sum += __shfl_xor(sum, off);
        sq  += __shfl_xor(sq, off);
    }
    __shared__ float rs[4], rq[4];
    if ((t & 63) == 0) { rs[t >> 6] = sum; rq[t >> 6] = sq; }
    __syncthreads();
    if (t == 0) {
        sum = rs[0] + rs[1] + rs[2] + rs[3];
        sq  = rq[0] + rq[1] + rq[2] + rq[3];
        float mean = sum * inv_count;
        float var = sq * inv_count - mean * mean;
        float scale = gamma[c] * rsqrtf(var + 1e-5f);
        ss[c] = scale;
        ss[COUT + c] = beta[c] - mean * scale;
    }
}

// ---------------------------------------------------------------------------
// NHWC BN+ReLU + 2x2/2 maxpool, fp16 -> fp16.
// ---------------------------------------------------------------------------
template<int C>
__global__ __launch_bounds__(256) void pool_nhwc_kernel(
    const _Float16* __restrict__ in, const float* __restrict__ ss,
    _Float16* __restrict__ out, int HO, int total)
{
    int idx = blockIdx.x * 256 + threadIdx.x;
    if (idx >= total) return;
    int c8 = idx % (C / 8);
    int p = idx / (C / 8);
    int x = p % HO;
    int p2 = p / HO;
    int y = p2 % HO;
    int n = p2 / HO;
    int WI = 2 * HO;
    size_t b00 = (((size_t)n * WI + 2 * y) * WI + 2 * x) * C + c8 * 8;
    half8 v00 = *(const half8*)&in[b00];
    half8 v01 = *(const half8*)&in[b00 + C];
    half8 v10 = *(const half8*)&in[b00 + (size_t)WI * C];
    half8 v11 = *(const half8*)&in[b00 + (size_t)WI * C + C];
    half8 o;
    #pragma unroll
    for (int j = 0; j < 8; ++j) {
        int c = c8 * 8 + j;
        float sc = ss[c], sh = ss[C + c];
        float m = fmaxf(fmaxf((float)v00[j] * sc + sh, (float)v01[j] * sc + sh),
                        fmaxf((float)v10[j] * sc + sh, (float)v11[j] * sc + sh));
        o[j] = (_Float16)fmaxf(0.f, m);
    }
    *(half8*)&out[(((size_t)n * HO + y) * HO + x) * C + c8 * 8] = o;
}

// ---------------------------------------------------------------------------
// fc1 MFMA GEMM (K-split): A (256,16384) fp16 NHWC-k x w1t (128,16384) fp16
// ---------------------------------------------------------------------------
__global__ __launch_bounds__(256) void fc1_mfma_kernel(
    const _Float16* __restrict__ A, const _Float16* __restrict__ Bw,
    float* __restrict__ hp)
{
    __shared__ __align__(16) _Float16 As[64][72];
    __shared__ __align__(16) _Float16 Bs[128][72];
    const int t = threadIdx.x;
    const int mt = blockIdx.x;
    const int kc = blockIdx.y;
    const int w = t >> 6, l = t & 63;
    const int lm = l & 15, lg = l >> 4;

    f32x4 zero4 = {0.f, 0.f, 0.f, 0.f};
    f32x4 acc[8];
    #pragma unroll
    for (int nb = 0; nb < 8; ++nb) acc[nb] = zero4;

    const size_t a_base = (size_t)(mt * 64) * 16384 + (size_t)kc * 512;
    const size_t b_base = (size_t)kc * 512;

    for (int p = 0; p < 8; ++p) {
        __syncthreads();
        #pragma unroll
        for (int i = 0; i < 2; ++i) {
            int idx = t + 256 * i;
            int r = idx >> 3, c8 = idx & 7;
            *(half8*)&As[r][c8 * 8] =
                *(const half8*)&A[a_base + (size_t)r * 16384 + p * 64 + c8 * 8];
        }
        #pragma unroll
        for (int i = 0; i < 4; ++i) {
            int idx = t + 256 * i;
            int r = idx >> 3, c8 = idx & 7;
            *(half8*)&Bs[r][c8 * 8] =
                *(const half8*)&Bw[b_base + (size_t)r * 16384 + p * 64 + c8 * 8];
        }
        __syncthreads();
        #pragma unroll
        for (int ks = 0; ks < 64; ks += 32) {
            half8 a = *(const half8*)&As[w * 16 + lm][ks + lg * 8];
            #pragma unroll
            for (int nb = 0; nb < 8; ++nb) {
                half8 b = *(const half8*)&Bs[nb * 16 + lm][ks + lg * 8];
                acc[nb] = __builtin_amdgcn_mfma_f32_16x16x32_f16(a, b, acc[nb], 0, 0, 0);
            }
        }
    }
    #pragma unroll
    for (int nb = 0; nb < 8; ++nb) {
        #pragma unroll
        for (int r = 0; r < 4; ++r) {
            int row = mt * 64 + w * 16 + lg * 4 + r;
            hp[((size_t)kc * 256 + row) * 128 + nb * 16 + lm] = acc[nb][r];
        }
    }
}

__global__ __launch_bounds__(256) void fc1_reduce_kernel(
    const float* __restrict__ hp, const float* __restrict__ bias, float* __restrict__ h1)
{
    int gid = blockIdx.x * 256 + threadIdx.x;   // 32768
    int n = gid >> 7, j = gid & 127;
    float s = bias[j];
    #pragma unroll
    for (int kc = 0; kc < 32; ++kc) s += hp[((size_t)kc * 256 + n) * 128 + j];
    h1[gid] = fmaxf(0.f, s);
}

// ---------------------------------------------------------------------------
// fc2: (256,128) x (10,128)^T + b -> xq (256,10). One wave per batch element.
// ---------------------------------------------------------------------------
__global__ __launch_bounds__(64) void fc2_kernel(
    const float* __restrict__ h1, const float* __restrict__ w,
    const float* __restrict__ b, float* __restrict__ xq)
{
    int n = blockIdx.x, l = threadIdx.x;
    float a0 = h1[n * 128 + l], a1 = h1[n * 128 + 64 + l];
    float p[10];
    #pragma unroll
    for (int j = 0; j < 10; ++j)
        p[j] = w[j * 128 + l] * a0 + w[j * 128 + 64 + l] * a1;
    #pragma unroll
    for (int j = 0; j < 10; ++j) {
        #pragma unroll
        for (int off = 32; off > 0; off >>= 1) p[j] += __shfl_xor(p[j], off);
    }
    if (l == 0) {
        #pragma unroll
        for (int j = 0; j < 10; ++j) xq[n * 10 + j] = p[j] + b[j];
    }
}

// ---------------------------------------------------------------------------
// Quantum circuit + Z-exp + head: ONE WAVE per batch element.
// State: 1024 amplitudes, i = (r<<6)|lane, 16 complex per lane in registers.
//  - wires 0..3 (bits 9..6 = reg bits): in-register rotations
//  - wires 4..9 (bits 5..0 = lane bits): __shfl_xor + per-lane coef select
//  - layer perms: LDS roundtrip with precomputed u16 gather table
//  - Rot matrices precomputed in quantum_prep (shared by all batches)
// ---------------------------------------------------------------------------
__global__ __launch_bounds__(64) void quantum_head_kernel(
    const float* __restrict__ xq, const float* __restrict__ rotm,
    const unsigned short* __restrict__ perm,
    const float* __restrict__ head_w, const float* __restrict__ head_b,
    float* __restrict__ outp)
{
    __shared__ float lds[2048];
    const int n = blockIdx.x;
    const int l = threadIdx.x;

    float ar[16], ai[16];
    #pragma unroll
    for (int r = 0; r < 16; ++r) { ar[r] = 0.f; ai[r] = 0.f; }
    if (l == 0) ar[0] = 1.f;

    // ---- RY encoding (state stays real) ----
    #pragma unroll
    for (int w = 0; w < 10; ++w) {
        float th = 0.5f * PI_F * xq[n * 10 + w];
        float c = cosf(th), s = sinf(th);
        const int k = 9 - w;
        if (k >= 6) {
            const int b = k - 6;
            #pragma unroll
            for (int r = 0; r < 16; ++r) {
                if (!(r & (1 << b))) {
                    int r1 = r | (1 << b);
                    float a0 = ar[r], a1 = ar[r1];
                    ar[r]  = c * a0 - s * a1;
                    ar[r1] = s * a0 + c * a1;
                }
            }
        } else {
            float ss = ((l >> k) & 1) ? s : -s;
            #pragma unroll
            for (int r = 0; r < 16; ++r) {
                float p = __shfl_xor(ar[r], 1 << k);
                ar[r] = c * ar[r] + ss * p;
            }
        }
    }

    // ---- 6 layers of Rot + CNOT-ring perm ----
    #pragma unroll 1
    for (int layer = 0; layer < 6; ++layer) {
        #pragma unroll
        for (int w = 0; w < 10; ++w) {
            const float* m = rotm + (layer * 10 + w) * 8;
            float m00r = m[0], m00i = m[1], m01r = m[2], m01i = m[3];
            float m10r = m[4], m10i = m[5], m11r = m[6], m11i = m[7];
            const int k = 9 - w;
            if (k >= 6) {
                const int b = k - 6;
                #pragma unroll
                for (int r = 0; r < 16; ++r) {
                    if (!(r & (1 << b))) {
                        int r1 = r | (1 << b);
                        float a0r = ar[r], a0i = ai[r];
                        float a1r = ar[r1], a1i = ai[r1];
                        ar[r]  = m00r * a0r - m00i * a0i + m01r * a1r - m01i * a1i;
                        ai[r]  = m00r * a0i + m00i * a0r + m01r * a1i + m01i * a1r;
                        ar[r1] = m10r * a0r - m10i * a0i + m11r * a1r - m11i * a1i;
                        ai[r1] = m10r * a0i + m10i * a0r + m11r * a1i + m11i * a1r;
                    }
                }
            } else {
                int bit = (l >> k) & 1;
                float mAr = bit ? m11r : m00r, mAi = bit ? m11i : m00i;
                float mBr = bit ? m10r : m01r, mBi = bit ? m10i : m01i;
                #pragma unroll
                for (int r = 0; r < 16; ++r) {
                    float pr = __shfl_xor(ar[r], 1 << k);
                    float pi = __shfl_xor(ai[r], 1 << k);
                    float mr = ar[r], mi = ai[r];
                    ar[r] = mAr * mr - mAi * mi + mBr * pr - mBi * pi;
                    ai[r] = mAr * mi + mAi * mr + mBr * pi + mBi * pr;
                }
            }
        }
        // permutation: new[i] = old[perm[i]] via LDS gather
        #pragma unroll
        for (int r = 0; r < 16; ++r) {
            lds[(r << 6) | l] = ar[r];
            lds[1024 + ((r << 6) | l)] = ai[r];
        }
        __syncthreads();
        const unsigned short* pt = perm + layer * 1024;
        #pragma unroll
        for (int r = 0; r < 16; ++r) {
            int ji = pt[(r << 6) | l];
            ar[r] = lds[ji];
            ai[r] = lds[1024 + ji];
        }
        __syncthreads();
    }

    // ---- Z expectations ----
    float S = 0.f, T0 = 0.f, T1 = 0.f, T2 = 0.f, T3 = 0.f;
    #pragma unroll
    for (int r = 0; r < 16; ++r) {
        float pr = ar[r] * ar[r] + ai[r] * ai[r];
        S += pr;
        T0 += (r & 1) ? -pr : pr;
        T1 += (r & 2) ? -pr : pr;
        T2 += (r & 4) ? -pr : pr;
        T3 += (r & 8) ? -pr : pr;
    }
    float pk[10];
    pk[0] = T3; pk[1] = T2; pk[2] = T1; pk[3] = T0;
    #pragma unroll
    for (int w = 4; w < 10; ++w)
        pk[w] = ((l >> (9 - w)) & 1) ? -S : S;
    #pragma unroll
    for (int w = 0; w < 10; ++w) {
        #pragma unroll
        for (int off = 1; off < 64; off <<= 1)
            pk[w] += __shfl_xor(pk[w], off);
    }
    if (l < 10) {
        float o = head_b[l];
        #pragma unroll
        for (int kk = 0; kk < 10; ++kk) o += pk[kk] * head_w[l * 10 + kk];
        outp[n * 10 + l] = o;
    }
}

// ---------------------------------------------------------------------------
// Workspace (≈145 MB)
// ---------------------------------------------------------------------------
extern "C" void kernel_launch(void* const* d_in, const int* in_sizes, int n_in,
                              void* d_out, int out_size, void* d_ws, size_t ws_size,
                              hipStream_t stream)
{
    const float* x   = (const float*)d_in[0];
    const float* c1w = (const float*)d_in[1];  const float* c1b = (const float*)d_in[2];
    const float* g1  = (const float*)d_in[3];  const float* b1  = (const float*)d_in[4];
    const float* c2w = (const float*)d_in[5];  const float* c2b = (const float*)d_in[6];
    const float* g2  = (const float*)d_in[7];  const float* b2  = (const float*)d_in[8];
    const float* c3w = (const float*)d_in[9];  const float* c3b = (const float*)d_in[10];
    const float* g3  = (const float*)d_in[11]; const float* b3  = (const float*)d_in[12];
    const float* c4w = (const float*)d_in[13]; const float* c4b = (const float*)d_in[14];
    const float* g4  = (const float*)d_in[15]; const float* b4  = (const float*)d_in[16];
    const float* f1w = (const float*)d_in[17]; const float* f1b = (const float*)d_in[18];
    const float* f2w = (const float*)d_in[19]; const float* f2b = (const float*)d_in[20];
    const float* qw  = (const float*)d_in[21];
    const float* hw  = (const float*)d_in[22]; const float* hb  = (const float*)d_in[23];

    float* ws = (float*)d_ws;
    _Float16* H0 = (_Float16*)ws;              // 33,554,432 halves
    _Float16* H1 = H0 + 33554432;              // 33,554,432 halves
    float* part = ws + 33554432;               // 524,288
    float* ss1  = part + 524288;               // 64
    float* ss2  = ss1 + 64;                    // 64
    float* ss3  = ss2 + 64;                    // 128
    float* ss4  = ss3 + 128;                   // 128
    float* hp   = ss4 + 128;                   // 1,048,576 (32*256*128)
    float* h1   = hp + 1048576;                // 32,768
    float* xqv  = h1 + 32768;                  // 2,560
    float* rotm = xqv + 2560;                  // 480
    unsigned short* perm16 = (unsigned short*)(rotm + 480);   // 6,144 u16
    _Float16* wt2 = (_Float16*)(perm16 + 6144);// 9,216 halves
    _Float16* wt3 = wt2 + 9216;                // 18,432 halves
    _Float16* wt4 = wt3 + 18432;               // 36,864 halves
    _Float16* w1t = wt4 + 36864;               // 2,097,152 halves

    // one-time precomputes (independent of the conv pipeline)
    quantum_prep_kernel<<<1, 256, 0, stream>>>(qw, rotm, perm16);
    wt_transform_kernel<<<252, 256, 0, stream>>>(c2w, c3w, c4w, wt2, wt3, wt4);
    fc1w_transform_kernel<<<dim3(4, 128), 256, 0, stream>>>(f1w, w1t);

    // conv1: x -> H0 (256,64,64,32) NHWC fp16
    conv1_kernel<<<dim3(16, 1, 256), 256, 0, stream>>>(x, c1w, c1b, H0);
    stats_nhwc32_kernel<<<dim3(8, 1, 256), 256, 0, stream>>>(H0, part, 8);
    bn_finalize_kernel<<<32, 256, 0, stream>>>(part, 8, 1, 1.f / 1048576.f, g1, b1, ss1, 32);

    // conv2 (MFMA): bn1+relu(H0) -> H1 (256,64,64,32)
    conv_mfma_kernel<64, 32, 32><<<dim3(16, 1, 256), 256, 0, stream>>>(
        H0, wt2, c2b, ss1, H1, part);
    bn_finalize_kernel<<<32, 256, 0, stream>>>(part, 16, 1, 1.f / 1048576.f, g2, b2, ss2, 32);

    // pool1: bn2+relu(H1) pooled -> H0 (256,32,32,32)
    pool_nhwc_kernel<32><<<4096, 256, 0, stream>>>(H1, ss2, H0, 32, 1048576);

    // conv3 (MFMA): H0 (activated) -> H1 (256,32,32,64)
    conv_mfma_kernel<32, 32, 64><<<dim3(4, 2, 256), 256, 0, stream>>>(
        H0, wt3, c3b, nullptr, H1, part);
    bn_finalize_kernel<<<64, 256, 0, stream>>>(part, 4, 2, 1.f / 262144.f, g3, b3, ss3, 64);

    // conv4 (MFMA): bn3+relu(H1) -> H0 (256,32,32,64)
    conv_mfma_kernel<32, 64, 64><<<dim3(4, 2, 256), 256, 0, stream>>>(
        H1, wt4, c4b, ss3, H0, part);
    bn_finalize_kernel<<<64, 256, 0, stream>>>(part, 4, 2, 1.f / 262144.f, g4, b4, ss4, 64);

    // pool2: bn4+relu(H0) pooled -> H1 (256,16,16,64) == A matrix for fc1
    pool_nhwc_kernel<64><<<2048, 256, 0, stream>>>(H0, ss4, H1, 16, 524288);

    // fc1: MFMA GEMM K-split + reduce -> h1 (256,128)
    fc1_mfma_kernel<<<dim3(4, 32), 256, 0, stream>>>(H1, w1t, hp);
    fc1_reduce_kernel<<<128, 256, 0, stream>>>(hp, f1b, h1);

    // fc2 -> xq (256,10)
    fc2_kernel<<<256, 64, 0, stream>>>(h1, f2w, f2b, xqv);

    // quantum circuit + head -> out (256,10)
    quantum_head_kernel<<<256, 64, 0, stream>>>(xqv, rotm, perm16, hw, hb, (float*)d_out);
}

// Round 8
// 239.953 us; speedup vs baseline: 7.5357x; 1.1741x over previous
//
#include <hip/hip_runtime.h>
#include <math.h>

#define PI_F 3.14159265358979323846f

typedef __attribute__((ext_vector_type(8))) _Float16 half8;
typedef __attribute__((ext_vector_type(4))) _Float16 half4;
typedef __attribute__((ext_vector_type(4))) float f32x4;

// ---------------------------------------------------------------------------
// x (256,3,64,64) fp32 -> X4 (256,64,64,4) fp16, channel 3 zero-padded.
// One thread = 2 pixels. grid 2048 x 256.
// ---------------------------------------------------------------------------
__global__ __launch_bounds__(256) void x_to_nhwc4_kernel(
    const float* __restrict__ x, _Float16* __restrict__ X4)
{
    int idx = blockIdx.x * 256 + threadIdx.x;      // 524,288
    int n = idx >> 11;
    int p = (idx & 2047) * 2;
    const float* xb = x + (size_t)n * 12288;
    float2 c0 = *(const float2*)&xb[p];
    float2 c1 = *(const float2*)&xb[4096 + p];
    float2 c2 = *(const float2*)&xb[8192 + p];
    half8 o;
    o[0] = (_Float16)c0.x; o[1] = (_Float16)c1.x; o[2] = (_Float16)c2.x; o[3] = (_Float16)0.f;
    o[4] = (_Float16)c0.y; o[5] = (_Float16)c1.y; o[6] = (_Float16)c2.y; o[7] = (_Float16)0.f;
    *(half8*)&X4[(size_t)idx * 8] = o;
}

// ---------------------------------------------------------------------------
// Weight transforms to channel-blocked fp16 layouts. grid 260 x 256.
// conv2/3: (g, k8, co, j), k=(tap,ci), CIN=32.
// conv4:   (g*2+cc, k8l, co, j), per ci-chunk cc of 32.
// conv1:   [8][32][8], k=tap*4+ci (tap<9, ci<3 real, else 0).
// ---------------------------------------------------------------------------
__global__ __launch_bounds__(256) void wt_transform_kernel(
    const float* __restrict__ w1, const float* __restrict__ w2,
    const float* __restrict__ w3, const float* __restrict__ w4,
    _Float16* __restrict__ t1, _Float16* __restrict__ t2,
    _Float16* __restrict__ t3, _Float16* __restrict__ t4)
{
    int idx = blockIdx.x * 256 + threadIdx.x;
    if (idx < 9216) {               // conv2: K=288, 1 group
        int j = idx & 7, co = (idx >> 3) & 31, k8 = idx >> 8;
        int k = k8 * 8 + j, tap = k >> 5, ci = k & 31;
        t2[idx] = (_Float16)w2[(size_t)(co * 32 + ci) * 9 + tap];
    } else if (idx < 27648) {       // conv3: K=288, 2 cout groups
        int e = idx - 9216;
        int j = e & 7, co = (e >> 3) & 31, r = e >> 8;
        int k8 = r % 36, gg = r / 36;
        int k = k8 * 8 + j, tap = k >> 5, ci = k & 31;
        t3[e] = (_Float16)w3[(size_t)((gg * 32 + co) * 32 + ci) * 9 + tap];
    } else if (idx < 64512) {       // conv4: 2 cout groups x 2 ci-chunks
        int e = idx - 27648;
        int j = e & 7, co = (e >> 3) & 31, r = e >> 8;   // r 0..143
        int k8 = r % 36, gc = r / 36;                    // gc = g*2+cc
        int g = gc >> 1, cc = gc & 1;
        int kl = k8 * 8 + j, tap = kl >> 5, ci = cc * 32 + (kl & 31);
        t4[e] = (_Float16)w4[(size_t)((g * 32 + co) * 64 + ci) * 9 + tap];
    } else if (idx < 66560) {       // conv1: K=64 padded
        int e = idx - 64512;
        int j = e & 7, co = (e >> 3) & 31, k8 = e >> 8;  // 0..7
        int k = k8 * 8 + j, tap = k >> 2, ci = k & 3;
        t1[e] = (_Float16)((tap < 9 && ci < 3) ? w1[(size_t)(co * 3 + ci) * 9 + tap] : 0.f);
    }
}

// ---------------------------------------------------------------------------
// fc1 weight transform: f1w [128][16384] fp32 NCHW-k -> w1t fp16 NHWC-k.
// ---------------------------------------------------------------------------
__global__ __launch_bounds__(256) void fc1w_transform_kernel(
    const float* __restrict__ w, _Float16* __restrict__ wt)
{
    __shared__ float lds[64][65];
    const int t = threadIdx.x;
    const int yx0 = blockIdx.x * 64;
    const int j = blockIdx.y;
    #pragma unroll
    for (int i = 0; i < 16; ++i) {
        int idx = t + 256 * i;
        int c = idx >> 6, yxl = idx & 63;
        lds[c][yxl] = w[(size_t)j * 16384 + c * 256 + yx0 + yxl];
    }
    __syncthreads();
    #pragma unroll
    for (int i = 0; i < 2; ++i) {
        int idx = t + 256 * i;
        int yxl = idx >> 3, c8 = idx & 7;
        half8 h;
        #pragma unroll
        for (int jj = 0; jj < 8; ++jj)
            h[jj] = (_Float16)lds[c8 * 8 + jj][yxl];
        *(half8*)&wt[(size_t)j * 16384 + (size_t)(yx0 + yxl) * 64 + c8 * 8] = h;
    }
}

// ---------------------------------------------------------------------------
// quantum_prep: 60 Rot matrices + 6x1024 u16 perm table (depends only on qw).
// ---------------------------------------------------------------------------
__global__ __launch_bounds__(256) void quantum_prep_kernel(
    const float* __restrict__ qw, float* __restrict__ rotm,
    unsigned short* __restrict__ perm)
{
    int t = threadIdx.x;
    if (t < 60) {
        float phi = qw[t * 3], th = qw[t * 3 + 1], om = qw[t * 3 + 2];
        float c = cosf(0.5f * th), s = sinf(0.5f * th);
        float apo = 0.5f * (phi + om), amo = 0.5f * (phi - om);
        float cpo = cosf(apo), spo = sinf(apo);
        float cmo = cosf(amo), smo = sinf(amo);
        rotm[t * 8 + 0] = cpo * c;  rotm[t * 8 + 1] = -spo * c;
        rotm[t * 8 + 2] = -cmo * s; rotm[t * 8 + 3] = -smo * s;
        rotm[t * 8 + 4] = cmo * s;  rotm[t * 8 + 5] = -smo * s;
        rotm[t * 8 + 6] = cpo * c;  rotm[t * 8 + 7] = spo * c;
    }
    for (int e = t; e < 6144; e += 256) {
        int layer = e >> 10, i = e & 1023;
        int r = layer % 9 + 1;
        int jdx = i;
        for (int w = 9; w >= 0; --w) {
            int tt = (w + r) % 10;
            int pc = 9 - w, pt_ = 9 - tt;
            jdx ^= ((jdx >> pc) & 1) << pt_;
        }
        perm[e] = (unsigned short)jdx;
    }
}

// ---------------------------------------------------------------------------
// conv1 via MFMA: X4 NHWC4 fp16 -> out (256,64,64,32) fp16 + stats.
// K = 64 (36 real, rest zero-weighted). Block 256 spatial x 32 cout, 4 waves.
// LDS pixel-major [462][4] halves (row 6 zeroed for tap-9 reads).
// ---------------------------------------------------------------------------
__global__ __launch_bounds__(256) void conv1_mfma_kernel(
    const _Float16* __restrict__ X4, const _Float16* __restrict__ w1m,
    const float* __restrict__ bias, _Float16* __restrict__ out,
    float* __restrict__ partials)
{
    constexpr int TC = 66, TR = 6;
    constexpr int NPIX = (TR + 1) * TC;     // 462
    __shared__ __align__(16) _Float16 s_in[NPIX * 4];
    __shared__ __align__(16) _Float16 s_w[2048];
    __shared__ float s_red[64];

    const int t = threadIdx.x;
    const int row0 = blockIdx.x * 4;
    const int n = blockIdx.z;

    *(half8*)&s_w[t * 8] = *(const half8*)&w1m[t * 8];

    for (int p = t; p < NPIX; p += 256) {
        int col = p % TC, r = p / TC;
        int gy = row0 + r - 1, gx = col - 1;
        float v = 0.f;   // 8B zero via two stores? use uint2
        uint2 u = make_uint2(0u, 0u);
        if (r < TR && gy >= 0 && gy < 64 && gx >= 0 && gx < 64)
            u = *(const uint2*)&X4[(((size_t)n << 12) + (gy << 6) + gx) * 4];
        (void)v;
        *(uint2*)&s_in[p * 4] = u;
    }
    if (t < 64) s_red[t] = 0.f;
    __syncthreads();

    const int w = t >> 6, l = t & 63;
    const int lm = l & 15, lg = l >> 4;
    int pA[4];
    #pragma unroll
    for (int f = 0; f < 4; ++f) {
        int m = w * 64 + f * 16 + lm;
        pA[f] = (m >> 6) * TC + (m & 63);
    }
    f32x4 zero4 = {0.f, 0.f, 0.f, 0.f};
    f32x4 acc[4][2];
    #pragma unroll
    for (int f = 0; f < 4; ++f) { acc[f][0] = zero4; acc[f][1] = zero4; }

    // ks = 0: taps (2*lg, 2*lg+1)
    {
        const int t0 = lg * 2;
        const int off0 = (t0 / 3) * TC + (t0 % 3);
        const int off1 = ((t0 + 1) / 3) * TC + ((t0 + 1) % 3);
        half8 b0 = *(const half8*)&s_w[(lg * 32 + lm) * 8];
        half8 b1 = *(const half8*)&s_w[(lg * 32 + 16 + lm) * 8];
        #pragma unroll
        for (int f = 0; f < 4; ++f) {
            half4 alo = *(const half4*)&s_in[(pA[f] + off0) * 4];
            half4 ahi = *(const half4*)&s_in[(pA[f] + off1) * 4];
            half8 a;
            #pragma unroll
            for (int j = 0; j < 4; ++j) { a[j] = alo[j]; a[4 + j] = ahi[j]; }
            acc[f][0] = __builtin_amdgcn_mfma_f32_16x16x32_f16(a, b0, acc[f][0], 0, 0, 0);
            acc[f][1] = __builtin_amdgcn_mfma_f32_16x16x32_f16(a, b1, acc[f][1], 0, 0, 0);
        }
    }
    // ks = 32: lg 0 -> taps 8 (real) and 9 (zero-row); lg 1..3 -> zero A (B=0)
    {
        half8 b0 = *(const half8*)&s_w[((4 + lg) * 32 + lm) * 8];
        half8 b1 = *(const half8*)&s_w[((4 + lg) * 32 + 16 + lm) * 8];
        #pragma unroll
        for (int f = 0; f < 4; ++f) {
            half8 a;
            #pragma unroll
            for (int j = 0; j < 8; ++j) a[j] = (_Float16)0.f;
            if (lg == 0) {
                half4 alo = *(const half4*)&s_in[(pA[f] + 134) * 4];  // tap8 (2,2)
                half4 ahi = *(const half4*)&s_in[(pA[f] + 198) * 4];  // tap9 -> row+3
                #pragma unroll
                for (int j = 0; j < 4; ++j) { a[j] = alo[j]; a[4 + j] = ahi[j]; }
            }
            acc[f][0] = __builtin_amdgcn_mfma_f32_16x16x32_f16(a, b0, acc[f][0], 0, 0, 0);
            acc[f][1] = __builtin_amdgcn_mfma_f32_16x16x32_f16(a, b1, acc[f][1], 0, 0, 0);
        }
    }

    float bv0 = bias[lm];
    float bv1 = bias[16 + lm];
    float s0 = 0.f, s20 = 0.f, s1 = 0.f, s21 = 0.f;
    #pragma unroll
    for (int f = 0; f < 4; ++f) {
        #pragma unroll
        for (int r = 0; r < 4; ++r) {
            int m = w * 64 + f * 16 + lg * 4 + r;
            int yy = row0 + (m >> 6), xo = m & 63;
            size_t base = (((size_t)n * 64 + yy) * 64 + xo) * 32;
            float v0 = acc[f][0][r] + bv0;
            float v1 = acc[f][1][r] + bv1;
            out[base + lm] = (_Float16)v0;
            out[base + 16 + lm] = (_Float16)v1;
            s0 += v0; s20 += v0 * v0;
            s1 += v1; s21 += v1 * v1;
        }
    }
    s0 += __shfl_xor(s0, 16);  s0 += __shfl_xor(s0, 32);
    s1 += __shfl_xor(s1, 16);  s1 += __shfl_xor(s1, 32);
    s20 += __shfl_xor(s20, 16); s20 += __shfl_xor(s20, 32);
    s21 += __shfl_xor(s21, 16); s21 += __shfl_xor(s21, 32);
    if (l < 16) {
        atomicAdd(&s_red[lm], s0);
        atomicAdd(&s_red[16 + lm], s1);
        atomicAdd(&s_red[32 + lm], s20);
        atomicAdd(&s_red[48 + lm], s21);
    }
    __syncthreads();
    if (t < 64)
        partials[((size_t)n * 16 + blockIdx.x) * 64 + t] = s_red[t];
}

// ---------------------------------------------------------------------------
// Implicit-GEMM 3x3 conv via MFMA (channel-blocked LDS, ci-chunked staging).
// NCH = CIN/32 chunks staged serially (acc carries) -> LDS fits 3 blocks/CU.
// BN+ReLU on input staging in packed fp16.
// ---------------------------------------------------------------------------
template<int W, int CIN, int COUT, int NCH>
__global__ __launch_bounds__(256) void conv_mfma_kernel(
    const _Float16* __restrict__ in, const _Float16* __restrict__ wt,
    const float* __restrict__ bias, const _Float16* __restrict__ ssh_in,
    _Float16* __restrict__ out, float* __restrict__ partials)
{
    constexpr int H = W;
    constexpr int ROWS = 256 / W;
    constexpr int TR = ROWS + 2;
    constexpr int TC = W + 2;
    constexpr int NPIX = TR * TC;
    constexpr int CCI = CIN / NCH;          // 32
    constexpr int KC = 9 * CCI;             // 288
    __shared__ __align__(16) _Float16 s_in[NPIX * CCI];
    __shared__ __align__(16) _Float16 s_w[KC * 32];
    __shared__ float s_red[64];

    const int t = threadIdx.x;
    const int row0 = blockIdx.x * ROWS;
    const int g = blockIdx.y;
    const int cout0 = g * 32;
    const int n = blockIdx.z;

    const int w = t >> 6, l = t & 63;
    const int lm = l & 15, lg = l >> 4;
    int pA[4];
    #pragma unroll
    for (int f = 0; f < 4; ++f) {
        int m = w * 64 + f * 16 + lm;
        pA[f] = (m / W) * TC + (m % W);
    }
    f32x4 zero4 = {0.f, 0.f, 0.f, 0.f};
    f32x4 acc[4][2];
    #pragma unroll
    for (int f = 0; f < 4; ++f) { acc[f][0] = zero4; acc[f][1] = zero4; }
    if (t < 64) s_red[t] = 0.f;

    #pragma unroll
    for (int cc = 0; cc < NCH; ++cc) {
        __syncthreads();
        // ---- stage weights chunk (linear, pre-arranged) ----
        const _Float16* wg = wt + (size_t)(g * NCH + cc) * KC * 32;
        for (int idx = t; idx < KC * 4; idx += 256)
            *(half8*)&s_w[idx * 8] = *(const half8*)&wg[(size_t)idx * 8];
        // ---- stage input chunk ----
        for (int idx = t; idx < NPIX * 4; idx += 256) {
            int c8 = idx & 3;
            int p = idx >> 2;
            int col = p % TC, r = p / TC;
            int gy = row0 + r - 1, gx = col - 1;
            half8 v;
            #pragma unroll
            for (int j = 0; j < 8; ++j) v[j] = (_Float16)0.f;
            if (gy >= 0 && gy < H && gx >= 0 && gx < W) {
                v = *(const half8*)&in[(((size_t)n * H + gy) * W + gx) * CIN + cc * CCI + c8 * 8];
                if (ssh_in) {
                    half8 sc = *(const half8*)&ssh_in[cc * CCI + c8 * 8];
                    half8 sh = *(const half8*)&ssh_in[CIN + cc * CCI + c8 * 8];
                    #pragma unroll
                    for (int j = 0; j < 8; ++j) {
                        _Float16 f = v[j] * sc[j] + sh[j];
                        v[j] = f > (_Float16)0.f ? f : (_Float16)0.f;
                    }
                }
            }
            *(half8*)&s_in[(c8 * NPIX + p) * 8] = v;
        }
        __syncthreads();
        // ---- compute chunk: 9 K-steps, 8 MFMA each ----
        #pragma unroll
        for (int ksl = 0; ksl < KC; ksl += 32) {
            const int tap = ksl >> 5;
            const int dy = tap / 3, dx = tap % 3;
            const int poff = dy * TC + dx;
            half8 b0 = *(const half8*)&s_w[((tap * 4 + lg) * 32 + lm) * 8];
            half8 b1 = *(const half8*)&s_w[((tap * 4 + lg) * 32 + 16 + lm) * 8];
            #pragma unroll
            for (int f = 0; f < 4; ++f) {
                half8 a = *(const half8*)&s_in[(lg * NPIX + pA[f] + poff) * 8];
                acc[f][0] = __builtin_amdgcn_mfma_f32_16x16x32_f16(a, b0, acc[f][0], 0, 0, 0);
                acc[f][1] = __builtin_amdgcn_mfma_f32_16x16x32_f16(a, b1, acc[f][1], 0, 0, 0);
            }
        }
    }

    // ---- bias + NHWC fp16 store + stats ----
    float bv0 = bias[cout0 + lm];
    float bv1 = bias[cout0 + 16 + lm];
    float s0 = 0.f, s20 = 0.f, s1 = 0.f, s21 = 0.f;
    #pragma unroll
    for (int f = 0; f < 4; ++f) {
        #pragma unroll
        for (int r = 0; r < 4; ++r) {
            int m = w * 64 + f * 16 + lg * 4 + r;
            int yy = row0 + m / W, xo = m % W;
            size_t base = (((size_t)n * H + yy) * W + xo) * COUT + cout0;
            float v0 = acc[f][0][r] + bv0;
            float v1 = acc[f][1][r] + bv1;
            out[base + lm] = (_Float16)v0;
            out[base + 16 + lm] = (_Float16)v1;
            s0 += v0; s20 += v0 * v0;
            s1 += v1; s21 += v1 * v1;
        }
    }
    s0 += __shfl_xor(s0, 16);  s0 += __shfl_xor(s0, 32);
    s1 += __shfl_xor(s1, 16);  s1 += __shfl_xor(s1, 32);
    s20 += __shfl_xor(s20, 16); s20 += __shfl_xor(s20, 32);
    s21 += __shfl_xor(s21, 16); s21 += __shfl_xor(s21, 32);
    if (l < 16) {
        atomicAdd(&s_red[lm], s0);
        atomicAdd(&s_red[16 + lm], s1);
        atomicAdd(&s_red[32 + lm], s20);
        atomicAdd(&s_red[48 + lm], s21);
    }
    __syncthreads();
    if (t < 64) {
        size_t bid = ((size_t)n * gridDim.y + blockIdx.y) * gridDim.x + blockIdx.x;
        partials[bid * 64 + t] = s_red[t];
    }
}

// ---------------------------------------------------------------------------
// Reduce per-block partials -> BN scale/shift (fp32 + fp16 mirrors).
// ---------------------------------------------------------------------------
__global__ __launch_bounds__(256) void bn_finalize_kernel(
    const float* __restrict__ partials, int nx, int ng, float inv_count,
    const float* __restrict__ gamma, const float* __restrict__ beta,
    float* __restrict__ ss, _Float16* __restrict__ ssh, int COUT)
{
    const int c = blockIdx.x;
    const int g = c >> 5, i = c & 31;
    const int t = threadIdx.x;
    float sum = 0.f, sq = 0.f;
    int total = 256 * nx;
    for (int e = t; e < total; e += 256) {
        int n = e / nx, xt = e - n * nx;
        size_t bid = ((size_t)(n * ng + g) * nx + xt) * 64;
        sum += partials[bid + i];
        sq  += partials[bid + 32 + i];
    }
    #pragma unroll
    for (int off = 32; off > 0; off >>= 1) {
        sum += __shfl_xor(sum, off);
        sq  += __shfl_xor(sq, off);
    }
    __shared__ float rs[4], rq[4];
    if ((t & 63) == 0) { rs[t >> 6] = sum; rq[t >> 6] = sq; }
    __syncthreads();
    if (t == 0) {
        sum = rs[0] + rs[1] + rs[2] + rs[3];
        sq  = rq[0] + rq[1] + rq[2] + rq[3];
        float mean = sum * inv_count;
        float var = sq * inv_count - mean * mean;
        float scale = gamma[c] * rsqrtf(var + 1e-5f);
        float shift = beta[c] - mean * scale;
        ss[c] = scale;
        ss[COUT + c] = shift;
        ssh[c] = (_Float16)scale;
        ssh[COUT + c] = (_Float16)shift;
    }
}

// ---------------------------------------------------------------------------
// NHWC BN+ReLU + 2x2/2 maxpool, fp16 -> fp16.
// ---------------------------------------------------------------------------
template<int C>
__global__ __launch_bounds__(256) void pool_nhwc_kernel(
    const _Float16* __restrict__ in, const float* __restrict__ ss,
    _Float16* __restrict__ out, int HO, int total)
{
    int idx = blockIdx.x * 256 + threadIdx.x;
    if (idx >= total) return;
    int c8 = idx % (C / 8);
    int p = idx / (C / 8);
    int x = p % HO;
    int p2 = p / HO;
    int y = p2 % HO;
    int n = p2 / HO;
    int WI = 2 * HO;
    size_t b00 = (((size_t)n * WI + 2 * y) * WI + 2 * x) * C + c8 * 8;
    half8 v00 = *(const half8*)&in[b00];
    half8 v01 = *(const half8*)&in[b00 + C];
    half8 v10 = *(const half8*)&in[b00 + (size_t)WI * C];
    half8 v11 = *(const half8*)&in[b00 + (size_t)WI * C + C];
    half8 o;
    #pragma unroll
    for (int j = 0; j < 8; ++j) {
        int c = c8 * 8 + j;
        float sc = ss[c], sh = ss[C + c];
        float m = fmaxf(fmaxf((float)v00[j] * sc + sh, (float)v01[j] * sc + sh),
                        fmaxf((float)v10[j] * sc + sh, (float)v11[j] * sc + sh));
        o[j] = (_Float16)fmaxf(0.f, m);
    }
    *(half8*)&out[(((size_t)n * HO + y) * HO + x) * C + c8 * 8] = o;
}

// ---------------------------------------------------------------------------
// fc1 MFMA GEMM (K-split): A (256,16384) fp16 NHWC-k x w1t (128,16384) fp16
// ---------------------------------------------------------------------------
__global__ __launch_bounds__(256) void fc1_mfma_kernel(
    const _Float16* __restrict__ A, const _Float16* __restrict__ Bw,
    float* __restrict__ hp)
{
    __shared__ __align__(16) _Float16 As[64][72];
    __shared__ __align__(16) _Float16 Bs[128][72];
    const int t = threadIdx.x;
    const int mt = blockIdx.x;
    const int kc = blockIdx.y;
    const int w = t >> 6, l = t & 63;
    const int lm = l & 15, lg = l >> 4;

    f32x4 zero4 = {0.f, 0.f, 0.f, 0.f};
    f32x4 acc[8];
    #pragma unroll
    for (int nb = 0; nb < 8; ++nb) acc[nb] = zero4;

    const size_t a_base = (size_t)(mt * 64) * 16384 + (size_t)kc * 512;
    const size_t b_base = (size_t)kc * 512;

    for (int p = 0; p < 8; ++p) {
        __syncthreads();
        #pragma unroll
        for (int i = 0; i < 2; ++i) {
            int idx = t + 256 * i;
            int r = idx >> 3, c8 = idx & 7;
            *(half8*)&As[r][c8 * 8] =
                *(const half8*)&A[a_base + (size_t)r * 16384 + p * 64 + c8 * 8];
        }
        #pragma unroll
        for (int i = 0; i < 4; ++i) {
            int idx = t + 256 * i;
            int r = idx >> 3, c8 = idx & 7;
            *(half8*)&Bs[r][c8 * 8] =
                *(const half8*)&Bw[b_base + (size_t)r * 16384 + p * 64 + c8 * 8];
        }
        __syncthreads();
        #pragma unroll
        for (int ks = 0; ks < 64; ks += 32) {
            half8 a = *(const half8*)&As[w * 16 + lm][ks + lg * 8];
            #pragma unroll
            for (int nb = 0; nb < 8; ++nb) {
                half8 b = *(const half8*)&Bs[nb * 16 + lm][ks + lg * 8];
                acc[nb] = __builtin_amdgcn_mfma_f32_16x16x32_f16(a, b, acc[nb], 0, 0, 0);
            }
        }
    }
    #pragma unroll
    for (int nb = 0; nb < 8; ++nb) {
        #pragma unroll
        for (int r = 0; r < 4; ++r) {
            int row = mt * 64 + w * 16 + lg * 4 + r;
            hp[((size_t)kc * 256 + row) * 128 + nb * 16 + lm] = acc[nb][r];
        }
    }
}

__global__ __launch_bounds__(256) void fc1_reduce_kernel(
    const float* __restrict__ hp, const float* __restrict__ bias, float* __restrict__ h1)
{
    int gid = blockIdx.x * 256 + threadIdx.x;   // 32768
    int n = gid >> 7, j = gid & 127;
    float s = bias[j];
    #pragma unroll
    for (int kc = 0; kc < 32; ++kc) s += hp[((size_t)kc * 256 + n) * 128 + j];
    h1[gid] = fmaxf(0.f, s);
}

// ---------------------------------------------------------------------------
// fc2: (256,128) x (10,128)^T + b -> xq (256,10). One wave per batch element.
// ---------------------------------------------------------------------------
__global__ __launch_bounds__(64) void fc2_kernel(
    const float* __restrict__ h1, const float* __restrict__ w,
    const float* __restrict__ b, float* __restrict__ xq)
{
    int n = blockIdx.x, l = threadIdx.x;
    float a0 = h1[n * 128 + l], a1 = h1[n * 128 + 64 + l];
    float p[10];
    #pragma unroll
    for (int j = 0; j < 10; ++j)
        p[j] = w[j * 128 + l] * a0 + w[j * 128 + 64 + l] * a1;
    #pragma unroll
    for (int j = 0; j < 10; ++j) {
        #pragma unroll
        for (int off = 32; off > 0; off >>= 1) p[j] += __shfl_xor(p[j], off);
    }
    if (l == 0) {
        #pragma unroll
        for (int j = 0; j < 10; ++j) xq[n * 10 + j] = p[j] + b[j];
    }
}

// ---------------------------------------------------------------------------
// Quantum circuit + Z-exp + head: ONE WAVE per batch element (reg-resident).
// ---------------------------------------------------------------------------
__global__ __launch_bounds__(64) void quantum_head_kernel(
    const float* __restrict__ xq, const float* __restrict__ rotm,
    const unsigned short* __restrict__ perm,
    const float* __restrict__ head_w, const float* __restrict__ head_b,
    float* __restrict__ outp)
{
    __shared__ float lds[2048];
    const int n = blockIdx.x;
    const int l = threadIdx.x;

    float ar[16], ai[16];
    #pragma unroll
    for (int r = 0; r < 16; ++r) { ar[r] = 0.f; ai[r] = 0.f; }
    if (l == 0) ar[0] = 1.f;

    #pragma unroll
    for (int w = 0; w < 10; ++w) {
        float th = 0.5f * PI_F * xq[n * 10 + w];
        float c = cosf(th), s = sinf(th);
        const int k = 9 - w;
        if (k >= 6) {
            const int b = k - 6;
            #pragma unroll
            for (int r = 0; r < 16; ++r) {
                if (!(r & (1 << b))) {
                    int r1 = r | (1 << b);
                    float a0 = ar[r], a1 = ar[r1];
                    ar[r]  = c * a0 - s * a1;
                    ar[r1] = s * a0 + c * a1;
                }
            }
        } else {
            float ss = ((l >> k) & 1) ? s : -s;
            #pragma unroll
            for (int r = 0; r < 16; ++r) {
                float p = __shfl_xor(ar[r], 1 << k);
                ar[r] = c * ar[r] + ss * p;
            }
        }
    }

    #pragma unroll 1
    for (int layer = 0; layer < 6; ++layer) {
        #pragma unroll
        for (int w = 0; w < 10; ++w) {
            const float* m = rotm + (layer * 10 + w) * 8;
            float m00r = m[0], m00i = m[1], m01r = m[2], m01i = m[3];
            float m10r = m[4], m10i = m[5], m11r = m[6], m11i = m[7];
            const int k = 9 - w;
            if (k >= 6) {
                const int b = k - 6;
                #pragma unroll
                for (int r = 0; r < 16; ++r) {
                    if (!(r & (1 << b))) {
                        int r1 = r | (1 << b);
                        float a0r = ar[r], a0i = ai[r];
                        float a1r = ar[r1], a1i = ai[r1];
                        ar[r]  = m00r * a0r - m00i * a0i + m01r * a1r - m01i * a1i;
                        ai[r]  = m00r * a0i + m00i * a0r + m01r * a1i + m01i * a1r;
                        ar[r1] = m10r * a0r - m10i * a0i + m11r * a1r - m11i * a1i;
                        ai[r1] = m10r * a0i + m10i * a0r + m11r * a1i + m11i * a1r;
                    }
                }
            } else {
                int bit = (l >> k) & 1;
                float mAr = bit ? m11r : m00r, mAi = bit ? m11i : m00i;
                float mBr = bit ? m10r : m01r, mBi = bit ? m10i : m01i;
                #pragma unroll
                for (int r = 0; r < 16; ++r) {
                    float pr = __shfl_xor(ar[r], 1 << k);
                    float pi = __shfl_xor(ai[r], 1 << k);
                    float mr = ar[r], mi = ai[r];
                    ar[r] = mAr * mr - mAi * mi + mBr * pr - mBi * pi;
                    ai[r] = mAr * mi + mAi * mr + mBr * pi + mBi * pr;
                }
            }
        }
        #pragma unroll
        for (int r = 0; r < 16; ++r) {
            lds[(r << 6) | l] = ar[r];
            lds[1024 + ((r << 6) | l)] = ai[r];
        }
        __syncthreads();
        const unsigned short* pt = perm + layer * 1024;
        #pragma unroll
        for (int r = 0; r < 16; ++r) {
            int ji = pt[(r << 6) | l];
            ar[r] = lds[ji];
            ai[r] = lds[1024 + ji];
        }
        __syncthreads();
    }

    float S = 0.f, T0 = 0.f, T1 = 0.f, T2 = 0.f, T3 = 0.f;
    #pragma unroll
    for (int r = 0; r < 16; ++r) {
        float pr = ar[r] * ar[r] + ai[r] * ai[r];
        S += pr;
        T0 += (r & 1) ? -pr : pr;
        T1 += (r & 2) ? -pr : pr;
        T2 += (r & 4) ? -pr : pr;
        T3 += (r & 8) ? -pr : pr;
    }
    float pk[10];
    pk[0] = T3; pk[1] = T2; pk[2] = T1; pk[3] = T0;
    #pragma unroll
    for (int w = 4; w < 10; ++w)
        pk[w] = ((l >> (9 - w)) & 1) ? -S : S;
    #pragma unroll
    for (int w = 0; w < 10; ++w) {
        #pragma unroll
        for (int off = 1; off < 64; off <<= 1)
            pk[w] += __shfl_xor(pk[w], off);
    }
    if (l < 10) {
        float o = head_b[l];
        #pragma unroll
        for (int kk = 0; kk < 10; ++kk) o += pk[kk] * head_w[l * 10 + kk];
        outp[n * 10 + l] = o;
    }
}

// ---------------------------------------------------------------------------
extern "C" void kernel_launch(void* const* d_in, const int* in_sizes, int n_in,
                              void* d_out, int out_size, void* d_ws, size_t ws_size,
                              hipStream_t stream)
{
    const float* x   = (const float*)d_in[0];
    const float* c1w = (const float*)d_in[1];  const float* c1b = (const float*)d_in[2];
    const float* g1  = (const float*)d_in[3];  const float* b1  = (const float*)d_in[4];
    const float* c2w = (const float*)d_in[5];  const float* c2b = (const float*)d_in[6];
    const float* g2  = (const float*)d_in[7];  const float* b2  = (const float*)d_in[8];
    const float* c3w = (const float*)d_in[9];  const float* c3b = (const float*)d_in[10];
    const float* g3  = (const float*)d_in[11]; const float* b3  = (const float*)d_in[12];
    const float* c4w = (const float*)d_in[13]; const float* c4b = (const float*)d_in[14];
    const float* g4  = (const float*)d_in[15]; const float* b4  = (const float*)d_in[16];
    const float* f1w = (const float*)d_in[17]; const float* f1b = (const float*)d_in[18];
    const float* f2w = (const float*)d_in[19]; const float* f2b = (const float*)d_in[20];
    const float* qw  = (const float*)d_in[21];
    const float* hw  = (const float*)d_in[22]; const float* hb  = (const float*)d_in[23];

    float* ws = (float*)d_ws;
    _Float16* H0 = (_Float16*)ws;              // 33,554,432 halves (64 MB)
    _Float16* H1 = H0 + 33554432;              // 33,554,432 halves (64 MB)
    float* part = ws + 33554432;               // 524,288
    float* ss1  = part + 524288;               // 64
    float* ss2  = ss1 + 64;                    // 64
    float* ss3  = ss2 + 64;                    // 128
    float* ss4  = ss3 + 128;                   // 128
    float* hp   = ss4 + 128;                   // 1,048,576
    float* h1   = hp + 1048576;                // 32,768
    float* xqv  = h1 + 32768;                  // 2,560
    float* rotm = xqv + 2560;                  // 480
    unsigned short* perm16 = (unsigned short*)(rotm + 480);   // 6,144 u16
    _Float16* ssh1 = (_Float16*)(perm16 + 6144);   // 128 halves
    _Float16* ssh2 = ssh1 + 128;               // 128
    _Float16* ssh3 = ssh2 + 128;               // 256
    _Float16* ssh4 = ssh3 + 256;               // 256
    _Float16* wt2  = ssh4 + 256;               // 9,216
    _Float16* wt3  = wt2 + 9216;               // 18,432
    _Float16* wt4  = wt3 + 18432;              // 36,864
    _Float16* w1m  = wt4 + 36864;              // 2,048
    _Float16* w1t  = w1m + 2048;               // 2,097,152
    _Float16* X4   = w1t + 2097152;            // 4,194,304 (8 MB)

    // one-time precomputes
    quantum_prep_kernel<<<1, 256, 0, stream>>>(qw, rotm, perm16);
    wt_transform_kernel<<<260, 256, 0, stream>>>(c1w, c2w, c3w, c4w, w1m, wt2, wt3, wt4);
    fc1w_transform_kernel<<<dim3(4, 128), 256, 0, stream>>>(f1w, w1t);
    x_to_nhwc4_kernel<<<2048, 256, 0, stream>>>(x, X4);

    // conv1 (MFMA): X4 -> H0 (256,64,64,32) + stats
    conv1_mfma_kernel<<<dim3(16, 1, 256), 256, 0, stream>>>(X4, w1m, c1b, H0, part);
    bn_finalize_kernel<<<32, 256, 0, stream>>>(part, 16, 1, 1.f / 1048576.f, g1, b1, ss1, ssh1, 32);

    // conv2 (MFMA): bn1+relu(H0) -> H1 (256,64,64,32)
    conv_mfma_kernel<64, 32, 32, 1><<<dim3(16, 1, 256), 256, 0, stream>>>(
        H0, wt2, c2b, ssh1, H1, part);
    bn_finalize_kernel<<<32, 256, 0, stream>>>(part, 16, 1, 1.f / 1048576.f, g2, b2, ss2, ssh2, 32);

    // pool1: bn2+relu(H1) pooled -> H0 (256,32,32,32)
    pool_nhwc_kernel<32><<<4096, 256, 0, stream>>>(H1, ss2, H0, 32, 1048576);

    // conv3 (MFMA): H0 (activated) -> H1 (256,32,32,64)
    conv_mfma_kernel<32, 32, 64, 1><<<dim3(4, 2, 256), 256, 0, stream>>>(
        H0, wt3, c3b, nullptr, H1, part);
    bn_finalize_kernel<<<64, 256, 0, stream>>>(part, 4, 2, 1.f / 262144.f, g3, b3, ss3, ssh3, 64);

    // conv4 (MFMA, 2 ci-chunks): bn3+relu(H1) -> H0 (256,32,32,64)
    conv_mfma_kernel<32, 64, 64, 2><<<dim3(4, 2, 256), 256, 0, stream>>>(
        H1, wt4, c4b, ssh3, H0, part);
    bn_finalize_kernel<<<64, 256, 0, stream>>>(part, 4, 2, 1.f / 262144.f, g4, b4, ss4, ssh4, 64);

    // pool2: bn4+relu(H0) pooled -> H1 (256,16,16,64) == A matrix for fc1
    pool_nhwc_kernel<64><<<2048, 256, 0, stream>>>(H0, ss4, H1, 16, 524288);

    // fc1: MFMA GEMM K-split + reduce -> h1 (256,128)
    fc1_mfma_kernel<<<dim3(4, 32), 256, 0, stream>>>(H1, w1t, hp);
    fc1_reduce_kernel<<<128, 256, 0, stream>>>(hp, f1b, h1);

    // fc2 -> xq (256,10)
    fc2_kernel<<<256, 64, 0, stream>>>(h1, f2w, f2b, xqv);

    // quantum circuit + head -> out (256,10)
    quantum_head_kernel<<<256, 64, 0, stream>>>(xqv, rotm, perm16, hw, hb, (float*)d_out);
}

// Round 9
// 236.005 us; speedup vs baseline: 7.6618x; 1.0167x over previous
//
#include <hip/hip_runtime.h>
#include <math.h>

#define PI_F 3.14159265358979323846f

typedef __attribute__((ext_vector_type(8))) _Float16 half8;
typedef __attribute__((ext_vector_type(4))) _Float16 half4;
typedef __attribute__((ext_vector_type(4))) float f32x4;

// ---------------------------------------------------------------------------
// x (256,3,64,64) fp32 -> X4 (256,64,64,4) fp16, channel 3 zero-padded.
// ---------------------------------------------------------------------------
__global__ __launch_bounds__(256) void x_to_nhwc4_kernel(
    const float* __restrict__ x, _Float16* __restrict__ X4)
{
    int idx = blockIdx.x * 256 + threadIdx.x;      // 524,288
    int n = idx >> 11;
    int p = (idx & 2047) * 2;
    const float* xb = x + (size_t)n * 12288;
    float2 c0 = *(const float2*)&xb[p];
    float2 c1 = *(const float2*)&xb[4096 + p];
    float2 c2 = *(const float2*)&xb[8192 + p];
    half8 o;
    o[0] = (_Float16)c0.x; o[1] = (_Float16)c1.x; o[2] = (_Float16)c2.x; o[3] = (_Float16)0.f;
    o[4] = (_Float16)c0.y; o[5] = (_Float16)c1.y; o[6] = (_Float16)c2.y; o[7] = (_Float16)0.f;
    *(half8*)&X4[(size_t)idx * 8] = o;
}

// ---------------------------------------------------------------------------
// Weight transforms to channel-blocked fp16 layouts.
// ---------------------------------------------------------------------------
__global__ __launch_bounds__(256) void wt_transform_kernel(
    const float* __restrict__ w1, const float* __restrict__ w2,
    const float* __restrict__ w3, const float* __restrict__ w4,
    _Float16* __restrict__ t1, _Float16* __restrict__ t2,
    _Float16* __restrict__ t3, _Float16* __restrict__ t4)
{
    int idx = blockIdx.x * 256 + threadIdx.x;
    if (idx < 9216) {               // conv2: K=288, 1 group
        int j = idx & 7, co = (idx >> 3) & 31, k8 = idx >> 8;
        int k = k8 * 8 + j, tap = k >> 5, ci = k & 31;
        t2[idx] = (_Float16)w2[(size_t)(co * 32 + ci) * 9 + tap];
    } else if (idx < 27648) {       // conv3: K=288, 2 cout groups
        int e = idx - 9216;
        int j = e & 7, co = (e >> 3) & 31, r = e >> 8;
        int k8 = r % 36, gg = r / 36;
        int k = k8 * 8 + j, tap = k >> 5, ci = k & 31;
        t3[e] = (_Float16)w3[(size_t)((gg * 32 + co) * 32 + ci) * 9 + tap];
    } else if (idx < 64512) {       // conv4: 2 cout groups x 2 ci-chunks
        int e = idx - 27648;
        int j = e & 7, co = (e >> 3) & 31, r = e >> 8;   // r 0..143
        int k8 = r % 36, gc = r / 36;                    // gc = g*2+cc
        int g = gc >> 1, cc = gc & 1;
        int kl = k8 * 8 + j, tap = kl >> 5, ci = cc * 32 + (kl & 31);
        t4[e] = (_Float16)w4[(size_t)((g * 32 + co) * 64 + ci) * 9 + tap];
    } else if (idx < 66560) {       // conv1: K=64 padded
        int e = idx - 64512;
        int j = e & 7, co = (e >> 3) & 31, k8 = e >> 8;  // 0..7
        int k = k8 * 8 + j, tap = k >> 2, ci = k & 3;
        t1[e] = (_Float16)((tap < 9 && ci < 3) ? w1[(size_t)(co * 3 + ci) * 9 + tap] : 0.f);
    }
}

// ---------------------------------------------------------------------------
// fc1 weight transform: f1w [128][16384] fp32 NCHW-k -> w1t fp16 NHWC-k.
// ---------------------------------------------------------------------------
__global__ __launch_bounds__(256) void fc1w_transform_kernel(
    const float* __restrict__ w, _Float16* __restrict__ wt)
{
    __shared__ float lds[64][65];
    const int t = threadIdx.x;
    const int yx0 = blockIdx.x * 64;
    const int j = blockIdx.y;
    #pragma unroll
    for (int i = 0; i < 16; ++i) {
        int idx = t + 256 * i;
        int c = idx >> 6, yxl = idx & 63;
        lds[c][yxl] = w[(size_t)j * 16384 + c * 256 + yx0 + yxl];
    }
    __syncthreads();
    #pragma unroll
    for (int i = 0; i < 2; ++i) {
        int idx = t + 256 * i;
        int yxl = idx >> 3, c8 = idx & 7;
        half8 h;
        #pragma unroll
        for (int jj = 0; jj < 8; ++jj)
            h[jj] = (_Float16)lds[c8 * 8 + jj][yxl];
        *(half8*)&wt[(size_t)j * 16384 + (size_t)(yx0 + yxl) * 64 + c8 * 8] = h;
    }
}

// ---------------------------------------------------------------------------
// quantum_prep: 60 Rot matrices + 6x1024 u16 perm table (depends only on qw).
// ---------------------------------------------------------------------------
__global__ __launch_bounds__(256) void quantum_prep_kernel(
    const float* __restrict__ qw, float* __restrict__ rotm,
    unsigned short* __restrict__ perm)
{
    int t = threadIdx.x;
    if (t < 60) {
        float phi = qw[t * 3], th = qw[t * 3 + 1], om = qw[t * 3 + 2];
        float c = cosf(0.5f * th), s = sinf(0.5f * th);
        float apo = 0.5f * (phi + om), amo = 0.5f * (phi - om);
        float cpo = cosf(apo), spo = sinf(apo);
        float cmo = cosf(amo), smo = sinf(amo);
        rotm[t * 8 + 0] = cpo * c;  rotm[t * 8 + 1] = -spo * c;
        rotm[t * 8 + 2] = -cmo * s; rotm[t * 8 + 3] = -smo * s;
        rotm[t * 8 + 4] = cmo * s;  rotm[t * 8 + 5] = -smo * s;
        rotm[t * 8 + 6] = cpo * c;  rotm[t * 8 + 7] = spo * c;
    }
    for (int e = t; e < 6144; e += 256) {
        int layer = e >> 10, i = e & 1023;
        int r = layer % 9 + 1;
        int jdx = i;
        for (int w = 9; w >= 0; --w) {
            int tt = (w + r) % 10;
            int pc = 9 - w, pt_ = 9 - tt;
            jdx ^= ((jdx >> pc) & 1) << pt_;
        }
        perm[e] = (unsigned short)jdx;
    }
}

// ---------------------------------------------------------------------------
// conv1 via MFMA: X4 NHWC4 fp16 -> out (256,64,64,32) fp16 + stats.
// ---------------------------------------------------------------------------
__global__ __launch_bounds__(256) void conv1_mfma_kernel(
    const _Float16* __restrict__ X4, const _Float16* __restrict__ w1m,
    const float* __restrict__ bias, _Float16* __restrict__ out,
    float* __restrict__ partials)
{
    constexpr int TC = 66, TR = 6;
    constexpr int NPIX = (TR + 1) * TC;     // 462
    __shared__ __align__(16) _Float16 s_in[NPIX * 4];
    __shared__ __align__(16) _Float16 s_w[2048];
    __shared__ float s_red[64];

    const int t = threadIdx.x;
    const int row0 = blockIdx.x * 4;
    const int n = blockIdx.z;

    *(half8*)&s_w[t * 8] = *(const half8*)&w1m[t * 8];

    for (int p = t; p < NPIX; p += 256) {
        int col = p % TC, r = p / TC;
        int gy = row0 + r - 1, gx = col - 1;
        uint2 u = make_uint2(0u, 0u);
        if (r < TR && gy >= 0 && gy < 64 && gx >= 0 && gx < 64)
            u = *(const uint2*)&X4[(((size_t)n << 12) + (gy << 6) + gx) * 4];
        *(uint2*)&s_in[p * 4] = u;
    }
    if (t < 64) s_red[t] = 0.f;
    __syncthreads();

    const int w = t >> 6, l = t & 63;
    const int lm = l & 15, lg = l >> 4;
    int pA[4];
    #pragma unroll
    for (int f = 0; f < 4; ++f) {
        int m = w * 64 + f * 16 + lm;
        pA[f] = (m >> 6) * TC + (m & 63);
    }
    f32x4 zero4 = {0.f, 0.f, 0.f, 0.f};
    f32x4 acc[4][2];
    #pragma unroll
    for (int f = 0; f < 4; ++f) { acc[f][0] = zero4; acc[f][1] = zero4; }

    {
        const int t0 = lg * 2;
        const int off0 = (t0 / 3) * TC + (t0 % 3);
        const int off1 = ((t0 + 1) / 3) * TC + ((t0 + 1) % 3);
        half8 b0 = *(const half8*)&s_w[(lg * 32 + lm) * 8];
        half8 b1 = *(const half8*)&s_w[(lg * 32 + 16 + lm) * 8];
        #pragma unroll
        for (int f = 0; f < 4; ++f) {
            half4 alo = *(const half4*)&s_in[(pA[f] + off0) * 4];
            half4 ahi = *(const half4*)&s_in[(pA[f] + off1) * 4];
            half8 a;
            #pragma unroll
            for (int j = 0; j < 4; ++j) { a[j] = alo[j]; a[4 + j] = ahi[j]; }
            acc[f][0] = __builtin_amdgcn_mfma_f32_16x16x32_f16(a, b0, acc[f][0], 0, 0, 0);
            acc[f][1] = __builtin_amdgcn_mfma_f32_16x16x32_f16(a, b1, acc[f][1], 0, 0, 0);
        }
    }
    {
        half8 b0 = *(const half8*)&s_w[((4 + lg) * 32 + lm) * 8];
        half8 b1 = *(const half8*)&s_w[((4 + lg) * 32 + 16 + lm) * 8];
        #pragma unroll
        for (int f = 0; f < 4; ++f) {
            half8 a;
            #pragma unroll
            for (int j = 0; j < 8; ++j) a[j] = (_Float16)0.f;
            if (lg == 0) {
                half4 alo = *(const half4*)&s_in[(pA[f] + 134) * 4];
                half4 ahi = *(const half4*)&s_in[(pA[f] + 198) * 4];
                #pragma unroll
                for (int j = 0; j < 4; ++j) { a[j] = alo[j]; a[4 + j] = ahi[j]; }
            }
            acc[f][0] = __builtin_amdgcn_mfma_f32_16x16x32_f16(a, b0, acc[f][0], 0, 0, 0);
            acc[f][1] = __builtin_amdgcn_mfma_f32_16x16x32_f16(a, b1, acc[f][1], 0, 0, 0);
        }
    }

    float bv0 = bias[lm];
    float bv1 = bias[16 + lm];
    float s0 = 0.f, s20 = 0.f, s1 = 0.f, s21 = 0.f;
    #pragma unroll
    for (int f = 0; f < 4; ++f) {
        #pragma unroll
        for (int r = 0; r < 4; ++r) {
            int m = w * 64 + f * 16 + lg * 4 + r;
            int yy = row0 + (m >> 6), xo = m & 63;
            size_t base = (((size_t)n * 64 + yy) * 64 + xo) * 32;
            float v0 = acc[f][0][r] + bv0;
            float v1 = acc[f][1][r] + bv1;
            out[base + lm] = (_Float16)v0;
            out[base + 16 + lm] = (_Float16)v1;
            s0 += v0; s20 += v0 * v0;
            s1 += v1; s21 += v1 * v1;
        }
    }
    s0 += __shfl_xor(s0, 16);  s0 += __shfl_xor(s0, 32);
    s1 += __shfl_xor(s1, 16);  s1 += __shfl_xor(s1, 32);
    s20 += __shfl_xor(s20, 16); s20 += __shfl_xor(s20, 32);
    s21 += __shfl_xor(s21, 16); s21 += __shfl_xor(s21, 32);
    if (l < 16) {
        atomicAdd(&s_red[lm], s0);
        atomicAdd(&s_red[16 + lm], s1);
        atomicAdd(&s_red[32 + lm], s20);
        atomicAdd(&s_red[48 + lm], s21);
    }
    __syncthreads();
    if (t < 64)
        partials[((size_t)n * 16 + blockIdx.x) * 64 + t] = s_red[t];
}

// ---------------------------------------------------------------------------
// Implicit-GEMM 3x3 conv via MFMA (channel-blocked LDS, ci-chunked staging).
// MMIN: input is pooled pre-BN (min,max) pair; stage relu(max*sA+min*sB+sh).
// POOL: write 2x2-pooled pre-BN (min,max) pair instead of full-res output.
// Always emits per-block per-cout sum/sumsq of full-res conv+bias output.
// ---------------------------------------------------------------------------
template<int W, int CIN, int COUT, int NCH, bool MMIN, bool POOL>
__global__ __launch_bounds__(256) void conv_mfma_kernel(
    const _Float16* __restrict__ in0, const _Float16* __restrict__ in1,
    const _Float16* __restrict__ coef, const _Float16* __restrict__ wt,
    const float* __restrict__ bias,
    _Float16* __restrict__ out0, _Float16* __restrict__ out1,
    float* __restrict__ partials)
{
    constexpr int H = W;
    constexpr int ROWS = 256 / W;
    constexpr int TR = ROWS + 2;
    constexpr int TC = W + 2;
    constexpr int NPIX = TR * TC;
    constexpr int CCI = 32;
    constexpr int KC = 9 * CCI;             // 288
    __shared__ __align__(16) _Float16 s_in[NPIX * CCI];
    __shared__ __align__(16) _Float16 s_w[KC * 32];
    __shared__ float s_red[64];

    const int t = threadIdx.x;
    const int row0 = blockIdx.x * ROWS;
    const int g = blockIdx.y;
    const int cout0 = g * 32;
    const int n = blockIdx.z;

    const int w = t >> 6, l = t & 63;
    const int lm = l & 15, lg = l >> 4;
    int pA[4];
    #pragma unroll
    for (int f = 0; f < 4; ++f) {
        int m = w * 64 + f * 16 + lm;
        pA[f] = (m / W) * TC + (m % W);
    }
    f32x4 zero4 = {0.f, 0.f, 0.f, 0.f};
    f32x4 acc[4][2];
    #pragma unroll
    for (int f = 0; f < 4; ++f) { acc[f][0] = zero4; acc[f][1] = zero4; }
    if (t < 64) s_red[t] = 0.f;

    #pragma unroll
    for (int cc = 0; cc < NCH; ++cc) {
        __syncthreads();
        // ---- stage weights chunk (linear, pre-arranged) ----
        const _Float16* wg = wt + (size_t)(g * NCH + cc) * KC * 32;
        for (int idx = t; idx < KC * 4; idx += 256)
            *(half8*)&s_w[idx * 8] = *(const half8*)&wg[(size_t)idx * 8];
        // ---- stage input chunk ----
        for (int idx = t; idx < NPIX * 4; idx += 256) {
            int c8 = idx & 3;
            int p = idx >> 2;
            int col = p % TC, r = p / TC;
            int gy = row0 + r - 1, gx = col - 1;
            half8 v;
            #pragma unroll
            for (int j = 0; j < 8; ++j) v[j] = (_Float16)0.f;
            if (gy >= 0 && gy < H && gx >= 0 && gx < W) {
                size_t gidx = (((size_t)n * H + gy) * W + gx) * CIN + cc * CCI + c8 * 8;
                if (MMIN) {
                    half8 mn = *(const half8*)&in0[gidx];
                    half8 mx = *(const half8*)&in1[gidx];
                    half8 sa = *(const half8*)&coef[cc * CCI + c8 * 8];
                    half8 sb = *(const half8*)&coef[CIN + cc * CCI + c8 * 8];
                    half8 sh = *(const half8*)&coef[2 * CIN + cc * CCI + c8 * 8];
                    #pragma unroll
                    for (int j = 0; j < 8; ++j) {
                        _Float16 f = mx[j] * sa[j] + mn[j] * sb[j] + sh[j];
                        v[j] = f > (_Float16)0.f ? f : (_Float16)0.f;
                    }
                } else {
                    v = *(const half8*)&in0[gidx];
                    if (coef) {
                        half8 sc = *(const half8*)&coef[cc * CCI + c8 * 8];
                        half8 sh = *(const half8*)&coef[CIN + cc * CCI + c8 * 8];
                        #pragma unroll
                        for (int j = 0; j < 8; ++j) {
                            _Float16 f = v[j] * sc[j] + sh[j];
                            v[j] = f > (_Float16)0.f ? f : (_Float16)0.f;
                        }
                    }
                }
            }
            *(half8*)&s_in[(c8 * NPIX + p) * 8] = v;
        }
        __syncthreads();
        // ---- compute chunk: 9 K-steps, 8 MFMA each ----
        #pragma unroll
        for (int ksl = 0; ksl < KC; ksl += 32) {
            const int tap = ksl >> 5;
            const int dy = tap / 3, dx = tap % 3;
            const int poff = dy * TC + dx;
            half8 b0 = *(const half8*)&s_w[((tap * 4 + lg) * 32 + lm) * 8];
            half8 b1 = *(const half8*)&s_w[((tap * 4 + lg) * 32 + 16 + lm) * 8];
            #pragma unroll
            for (int f = 0; f < 4; ++f) {
                half8 a = *(const half8*)&s_in[(lg * NPIX + pA[f] + poff) * 8];
                acc[f][0] = __builtin_amdgcn_mfma_f32_16x16x32_f16(a, b0, acc[f][0], 0, 0, 0);
                acc[f][1] = __builtin_amdgcn_mfma_f32_16x16x32_f16(a, b1, acc[f][1], 0, 0, 0);
            }
        }
    }

    // ---- stats over full-res conv+bias output ----
    float bv0 = bias[cout0 + lm];
    float bv1 = bias[cout0 + 16 + lm];
    float s0 = 0.f, s20 = 0.f, s1 = 0.f, s21 = 0.f;
    #pragma unroll
    for (int f = 0; f < 4; ++f) {
        #pragma unroll
        for (int r = 0; r < 4; ++r) {
            float v0 = acc[f][0][r] + bv0;
            float v1 = acc[f][1][r] + bv1;
            if (!POOL) {
                int m = w * 64 + f * 16 + lg * 4 + r;
                int yy = row0 + m / W, xo = m % W;
                size_t base = (((size_t)n * H + yy) * W + xo) * COUT + cout0;
                out0[base + lm] = (_Float16)v0;
                out0[base + 16 + lm] = (_Float16)v1;
            }
            s0 += v0; s20 += v0 * v0;
            s1 += v1; s21 += v1 * v1;
        }
    }
    s0 += __shfl_xor(s0, 16);  s0 += __shfl_xor(s0, 32);
    s1 += __shfl_xor(s1, 16);  s1 += __shfl_xor(s1, 32);
    s20 += __shfl_xor(s20, 16); s20 += __shfl_xor(s20, 32);
    s21 += __shfl_xor(s21, 16); s21 += __shfl_xor(s21, 32);
    if (l < 16) {
        atomicAdd(&s_red[lm], s0);
        atomicAdd(&s_red[16 + lm], s1);
        atomicAdd(&s_red[32 + lm], s20);
        atomicAdd(&s_red[48 + lm], s21);
    }

    if (POOL) {
        if (W == 32) {
            // fully in-lane: vertical (f, f+2), horizontal (2rp, 2rp+1)
            #pragma unroll
            for (int b = 0; b < 2; ++b) {
                float bv = b ? bv1 : bv0;
                #pragma unroll
                for (int fh = 0; fh < 2; ++fh) {
                    #pragma unroll
                    for (int rp = 0; rp < 2; ++rp) {
                        float a0 = acc[fh][b][2 * rp] + bv;
                        float a1 = acc[fh][b][2 * rp + 1] + bv;
                        float a2 = acc[fh + 2][b][2 * rp] + bv;
                        float a3 = acc[fh + 2][b][2 * rp + 1] + bv;
                        float mn = fminf(fminf(a0, a1), fminf(a2, a3));
                        float mx = fmaxf(fmaxf(a0, a1), fmaxf(a2, a3));
                        int xp = fh * 8 + lg * 2 + rp;
                        int yp = (row0 >> 1) + w;
                        size_t ob = (((size_t)n * (W / 2) + yp) * (W / 2) + xp) * COUT
                                    + cout0 + b * 16 + lm;
                        out0[ob] = (_Float16)mn;
                        out1[ob] = (_Float16)mx;
                    }
                }
            }
        } else {
            // W == 64: horizontal in-lane, vertical via LDS (reuse s_w: 16KB)
            __syncthreads();
            _Float16* vp = s_w;
            #pragma unroll
            for (int b = 0; b < 2; ++b) {
                float bv = b ? bv1 : bv0;
                #pragma unroll
                for (int f = 0; f < 4; ++f) {
                    #pragma unroll
                    for (int rp = 0; rp < 2; ++rp) {
                        float a0 = acc[f][b][2 * rp] + bv;
                        float a1 = acc[f][b][2 * rp + 1] + bv;
                        int xp = f * 8 + lg * 2 + rp;
                        int o = (w * 32 + xp) * 32 + b * 16 + lm;
                        vp[o] = (_Float16)fminf(a0, a1);
                        vp[4096 + o] = (_Float16)fmaxf(a0, a1);
                    }
                }
            }
            __syncthreads();
            int wp = t >> 7, e = t & 127;
            int xp = e >> 2, c8 = e & 3;
            half8 mnA = *(const half8*)&vp[((2 * wp) * 32 + xp) * 32 + c8 * 8];
            half8 mnB = *(const half8*)&vp[((2 * wp + 1) * 32 + xp) * 32 + c8 * 8];
            half8 mxA = *(const half8*)&vp[4096 + ((2 * wp) * 32 + xp) * 32 + c8 * 8];
            half8 mxB = *(const half8*)&vp[4096 + ((2 * wp + 1) * 32 + xp) * 32 + c8 * 8];
            half8 mn, mx;
            #pragma unroll
            for (int j = 0; j < 8; ++j) {
                mn[j] = mnA[j] < mnB[j] ? mnA[j] : mnB[j];
                mx[j] = mxA[j] > mxB[j] ? mxA[j] : mxB[j];
            }
            size_t ob = (((size_t)n * (W / 2) + (row0 >> 1) + wp) * (W / 2) + xp) * COUT
                        + cout0 + c8 * 8;
            *(half8*)&out0[ob] = mn;
            *(half8*)&out1[ob] = mx;
        }
    }

    __syncthreads();
    if (t < 64) {
        size_t bid = ((size_t)n * gridDim.y + blockIdx.y) * gridDim.x + blockIdx.x;
        partials[bid * 64 + t] = s_red[t];
    }
}

// ---------------------------------------------------------------------------
// Reduce per-block partials -> BN coefficients:
// ss (fp32 pair), ssh (fp16 pair), sab (fp16 triple sA,sB,sh for minmax).
// ---------------------------------------------------------------------------
__global__ __launch_bounds__(256) void bn_finalize_kernel(
    const float* __restrict__ partials, int nx, int ng, float inv_count,
    const float* __restrict__ gamma, const float* __restrict__ beta,
    float* __restrict__ ss, _Float16* __restrict__ ssh,
    _Float16* __restrict__ sab, int COUT)
{
    const int c = blockIdx.x;
    const int g = c >> 5, i = c & 31;
    const int t = threadIdx.x;
    float sum = 0.f, sq = 0.f;
    int total = 256 * nx;
    for (int e = t; e < total; e += 256) {
        int n = e / nx, xt = e - n * nx;
        size_t bid = ((size_t)(n * ng + g) * nx + xt) * 64;
        sum += partials[bid + i];
        sq  += partials[bid + 32 + i];
    }
    #pragma unroll
    for (int off = 32; off > 0; off >>= 1) {
        sum += __shfl_xor(sum, off);
        sq  += __shfl_xor(sq, off);
    }
    __shared__ float rs[4], rq[4];
    if ((t & 63) == 0) { rs[t >> 6] = sum; rq[t >> 6] = sq; }
    __syncthreads();
    if (t == 0) {
        sum = rs[0] + rs[1] + rs[2] + rs[3];
        sq  = rq[0] + rq[1] + rq[2] + rq[3];
        float mean = sum * inv_count;
        float var = sq * inv_count - mean * mean;
        float scale = gamma[c] * rsqrtf(var + 1e-5f);
        float shift = beta[c] - mean * scale;
        ss[c] = scale;
        ss[COUT + c] = shift;
        if (ssh) {
            ssh[c] = (_Float16)scale;
            ssh[COUT + c] = (_Float16)shift;
        }
        if (sab) {
            sab[c] = (_Float16)(scale > 0.f ? scale : 0.f);
            sab[COUT + c] = (_Float16)(scale > 0.f ? 0.f : scale);
            sab[2 * COUT + c] = (_Float16)shift;
        }
    }
}

// ---------------------------------------------------------------------------
// fc1 MFMA GEMM (K-split): A = relu(bn4(pooled minmax pair)) on the fly.
// ---------------------------------------------------------------------------
__global__ __launch_bounds__(256) void fc1_mfma_kernel(
    const _Float16* __restrict__ Amin, const _Float16* __restrict__ Amax,
    const _Float16* __restrict__ sab, const _Float16* __restrict__ Bw,
    float* __restrict__ hp)
{
    __shared__ __align__(16) _Float16 As[64][72];
    __shared__ __align__(16) _Float16 Bs[128][72];
    const int t = threadIdx.x;
    const int mt = blockIdx.x;
    const int kc = blockIdx.y;
    const int w = t >> 6, l = t & 63;
    const int lm = l & 15, lg = l >> 4;

    f32x4 zero4 = {0.f, 0.f, 0.f, 0.f};
    f32x4 acc[8];
    #pragma unroll
    for (int nb = 0; nb < 8; ++nb) acc[nb] = zero4;

    const size_t a_base = (size_t)(mt * 64) * 16384 + (size_t)kc * 512;
    const size_t b_base = (size_t)kc * 512;

    for (int p = 0; p < 8; ++p) {
        __syncthreads();
        #pragma unroll
        for (int i = 0; i < 2; ++i) {
            int idx = t + 256 * i;
            int r = idx >> 3, c8 = idx & 7;
            size_t off = a_base + (size_t)r * 16384 + p * 64 + c8 * 8;
            half8 mn = *(const half8*)&Amin[off];
            half8 mx = *(const half8*)&Amax[off];
            half8 sa = *(const half8*)&sab[c8 * 8];
            half8 sb = *(const half8*)&sab[64 + c8 * 8];
            half8 sh = *(const half8*)&sab[128 + c8 * 8];
            half8 v;
            #pragma unroll
            for (int j = 0; j < 8; ++j) {
                _Float16 f = mx[j] * sa[j] + mn[j] * sb[j] + sh[j];
                v[j] = f > (_Float16)0.f ? f : (_Float16)0.f;
            }
            *(half8*)&As[r][c8 * 8] = v;
        }
        #pragma unroll
        for (int i = 0; i < 4; ++i) {
            int idx = t + 256 * i;
            int r = idx >> 3, c8 = idx & 7;
            *(half8*)&Bs[r][c8 * 8] =
                *(const half8*)&Bw[b_base + (size_t)r * 16384 + p * 64 + c8 * 8];
        }
        __syncthreads();
        #pragma unroll
        for (int ks = 0; ks < 64; ks += 32) {
            half8 a = *(const half8*)&As[w * 16 + lm][ks + lg * 8];
            #pragma unroll
            for (int nb = 0; nb < 8; ++nb) {
                half8 b = *(const half8*)&Bs[nb * 16 + lm][ks + lg * 8];
                acc[nb] = __builtin_amdgcn_mfma_f32_16x16x32_f16(a, b, acc[nb], 0, 0, 0);
            }
        }
    }
    #pragma unroll
    for (int nb = 0; nb < 8; ++nb) {
        #pragma unroll
        for (int r = 0; r < 4; ++r) {
            int row = mt * 64 + w * 16 + lg * 4 + r;
            hp[((size_t)kc * 256 + row) * 128 + nb * 16 + lm] = acc[nb][r];
        }
    }
}

__global__ __launch_bounds__(256) void fc1_reduce_kernel(
    const float* __restrict__ hp, const float* __restrict__ bias, float* __restrict__ h1)
{
    int gid = blockIdx.x * 256 + threadIdx.x;   // 32768
    int n = gid >> 7, j = gid & 127;
    float s = bias[j];
    #pragma unroll
    for (int kc = 0; kc < 32; ++kc) s += hp[((size_t)kc * 256 + n) * 128 + j];
    h1[gid] = fmaxf(0.f, s);
}

// ---------------------------------------------------------------------------
// fc2: (256,128) x (10,128)^T + b -> xq (256,10). One wave per batch element.
// ---------------------------------------------------------------------------
__global__ __launch_bounds__(64) void fc2_kernel(
    const float* __restrict__ h1, const float* __restrict__ w,
    const float* __restrict__ b, float* __restrict__ xq)
{
    int n = blockIdx.x, l = threadIdx.x;
    float a0 = h1[n * 128 + l], a1 = h1[n * 128 + 64 + l];
    float p[10];
    #pragma unroll
    for (int j = 0; j < 10; ++j)
        p[j] = w[j * 128 + l] * a0 + w[j * 128 + 64 + l] * a1;
    #pragma unroll
    for (int j = 0; j < 10; ++j) {
        #pragma unroll
        for (int off = 32; off > 0; off >>= 1) p[j] += __shfl_xor(p[j], off);
    }
    if (l == 0) {
        #pragma unroll
        for (int j = 0; j < 10; ++j) xq[n * 10 + j] = p[j] + b[j];
    }
}

// ---------------------------------------------------------------------------
// Quantum circuit + Z-exp + head: ONE WAVE per batch element (reg-resident).
// ---------------------------------------------------------------------------
__global__ __launch_bounds__(64) void quantum_head_kernel(
    const float* __restrict__ xq, const float* __restrict__ rotm,
    const unsigned short* __restrict__ perm,
    const float* __restrict__ head_w, const float* __restrict__ head_b,
    float* __restrict__ outp)
{
    __shared__ float lds[2048];
    const int n = blockIdx.x;
    const int l = threadIdx.x;

    float ar[16], ai[16];
    #pragma unroll
    for (int r = 0; r < 16; ++r) { ar[r] = 0.f; ai[r] = 0.f; }
    if (l == 0) ar[0] = 1.f;

    #pragma unroll
    for (int w = 0; w < 10; ++w) {
        float th = 0.5f * PI_F * xq[n * 10 + w];
        float c = cosf(th), s = sinf(th);
        const int k = 9 - w;
        if (k >= 6) {
            const int b = k - 6;
            #pragma unroll
            for (int r = 0; r < 16; ++r) {
                if (!(r & (1 << b))) {
                    int r1 = r | (1 << b);
                    float a0 = ar[r], a1 = ar[r1];
                    ar[r]  = c * a0 - s * a1;
                    ar[r1] = s * a0 + c * a1;
                }
            }
        } else {
            float ss = ((l >> k) & 1) ? s : -s;
            #pragma unroll
            for (int r = 0; r < 16; ++r) {
                float p = __shfl_xor(ar[r], 1 << k);
                ar[r] = c * ar[r] + ss * p;
            }
        }
    }

    #pragma unroll 1
    for (int layer = 0; layer < 6; ++layer) {
        #pragma unroll
        for (int w = 0; w < 10; ++w) {
            const float* m = rotm + (layer * 10 + w) * 8;
            float m00r = m[0], m00i = m[1], m01r = m[2], m01i = m[3];
            float m10r = m[4], m10i = m[5], m11r = m[6], m11i = m[7];
            const int k = 9 - w;
            if (k >= 6) {
                const int b = k - 6;
                #pragma unroll
                for (int r = 0; r < 16; ++r) {
                    if (!(r & (1 << b))) {
                        int r1 = r | (1 << b);
                        float a0r = ar[r], a0i = ai[r];
                        float a1r = ar[r1], a1i = ai[r1];
                        ar[r]  = m00r * a0r - m00i * a0i + m01r * a1r - m01i * a1i;
                        ai[r]  = m00r * a0i + m00i * a0r + m01r * a1i + m01i * a1r;
                        ar[r1] = m10r * a0r - m10i * a0i + m11r * a1r - m11i * a1i;
                        ai[r1] = m10r * a0i + m10i * a0r + m11r * a1i + m11i * a1r;
                    }
                }
            } else {
                int bit = (l >> k) & 1;
                float mAr = bit ? m11r : m00r, mAi = bit ? m11i : m00i;
                float mBr = bit ? m10r : m01r, mBi = bit ? m10i : m01i;
                #pragma unroll
                for (int r = 0; r < 16; ++r) {
                    float pr = __shfl_xor(ar[r], 1 << k);
                    float pi = __shfl_xor(ai[r], 1 << k);
                    float mr = ar[r], mi = ai[r];
                    ar[r] = mAr * mr - mAi * mi + mBr * pr - mBi * pi;
                    ai[r] = mAr * mi + mAi * mr + mBr * pi + mBi * pr;
                }
            }
        }
        #pragma unroll
        for (int r = 0; r < 16; ++r) {
            lds[(r << 6) | l] = ar[r];
            lds[1024 + ((r << 6) | l)] = ai[r];
        }
        __syncthreads();
        const unsigned short* pt = perm + layer * 1024;
        #pragma unroll
        for (int r = 0; r < 16; ++r) {
            int ji = pt[(r << 6) | l];
            ar[r] = lds[ji];
            ai[r] = lds[1024 + ji];
        }
        __syncthreads();
    }

    float S = 0.f, T0 = 0.f, T1 = 0.f, T2 = 0.f, T3 = 0.f;
    #pragma unroll
    for (int r = 0; r < 16; ++r) {
        float pr = ar[r] * ar[r] + ai[r] * ai[r];
        S += pr;
        T0 += (r & 1) ? -pr : pr;
        T1 += (r & 2) ? -pr : pr;
        T2 += (r & 4) ? -pr : pr;
        T3 += (r & 8) ? -pr : pr;
    }
    float pk[10];
    pk[0] = T3; pk[1] = T2; pk[2] = T1; pk[3] = T0;
    #pragma unroll
    for (int w = 4; w < 10; ++w)
        pk[w] = ((l >> (9 - w)) & 1) ? -S : S;
    #pragma unroll
    for (int w = 0; w < 10; ++w) {
        #pragma unroll
        for (int off = 1; off < 64; off <<= 1)
            pk[w] += __shfl_xor(pk[w], off);
    }
    if (l < 10) {
        float o = head_b[l];
        #pragma unroll
        for (int kk = 0; kk < 10; ++kk) o += pk[kk] * head_w[l * 10 + kk];
        outp[n * 10 + l] = o;
    }
}

// ---------------------------------------------------------------------------
extern "C" void kernel_launch(void* const* d_in, const int* in_sizes, int n_in,
                              void* d_out, int out_size, void* d_ws, size_t ws_size,
                              hipStream_t stream)
{
    const float* x   = (const float*)d_in[0];
    const float* c1w = (const float*)d_in[1];  const float* c1b = (const float*)d_in[2];
    const float* g1  = (const float*)d_in[3];  const float* b1  = (const float*)d_in[4];
    const float* c2w = (const float*)d_in[5];  const float* c2b = (const float*)d_in[6];
    const float* g2  = (const float*)d_in[7];  const float* b2  = (const float*)d_in[8];
    const float* c3w = (const float*)d_in[9];  const float* c3b = (const float*)d_in[10];
    const float* g3  = (const float*)d_in[11]; const float* b3  = (const float*)d_in[12];
    const float* c4w = (const float*)d_in[13]; const float* c4b = (const float*)d_in[14];
    const float* g4  = (const float*)d_in[15]; const float* b4  = (const float*)d_in[16];
    const float* f1w = (const float*)d_in[17]; const float* f1b = (const float*)d_in[18];
    const float* f2w = (const float*)d_in[19]; const float* f2b = (const float*)d_in[20];
    const float* qw  = (const float*)d_in[21];
    const float* hw  = (const float*)d_in[22]; const float* hb  = (const float*)d_in[23];

    float* ws = (float*)d_ws;
    _Float16* H0 = (_Float16*)ws;              // 33,554,432 halves (64 MB)
    _Float16* H1 = H0 + 33554432;              // 33,554,432 halves (64 MB)
    float* part = ws + 33554432;               // 524,288
    float* ss1  = part + 524288;               // 64
    float* ss2  = ss1 + 64;                    // 64
    float* ss3  = ss2 + 64;                    // 128
    float* ss4  = ss3 + 128;                   // 128
    float* hp   = ss4 + 128;                   // 1,048,576
    float* h1   = hp + 1048576;                // 32,768
    float* xqv  = h1 + 32768;                  // 2,560
    float* rotm = xqv + 2560;                  // 480
    unsigned short* perm16 = (unsigned short*)(rotm + 480);   // 6,144 u16
    _Float16* ssh1 = (_Float16*)(perm16 + 6144);   // 64 halves
    _Float16* ssh3 = ssh1 + 64;                // 128
    _Float16* sab2 = ssh3 + 128;               // 96
    _Float16* sab4 = sab2 + 96;                // 192
    _Float16* wt2  = sab4 + 192;               // 9,216
    _Float16* wt3  = wt2 + 9216;               // 18,432
    _Float16* wt4  = wt3 + 18432;              // 36,864
    _Float16* w1m  = wt4 + 36864;              // 2,048
    _Float16* w1t  = w1m + 2048;               // 2,097,152
    _Float16* X4   = w1t + 2097152;            // 4,194,304 (8 MB)

    // overlays on H1 (sequential lifetimes)
    _Float16* minT2 = H1;                      // (256,32,32,32)
    _Float16* maxT2 = H1 + 8388608;
    _Float16* minT4 = H1;                      // (256,16,16,64)
    _Float16* maxT4 = H1 + 4194304;

    // one-time precomputes
    quantum_prep_kernel<<<1, 256, 0, stream>>>(qw, rotm, perm16);
    wt_transform_kernel<<<260, 256, 0, stream>>>(c1w, c2w, c3w, c4w, w1m, wt2, wt3, wt4);
    fc1w_transform_kernel<<<dim3(4, 128), 256, 0, stream>>>(f1w, w1t);
    x_to_nhwc4_kernel<<<2048, 256, 0, stream>>>(x, X4);

    // conv1 (MFMA): X4 -> H0 (256,64,64,32) + stats
    conv1_mfma_kernel<<<dim3(16, 1, 256), 256, 0, stream>>>(X4, w1m, c1b, H0, part);
    bn_finalize_kernel<<<32, 256, 0, stream>>>(part, 16, 1, 1.f / 1048576.f,
                                               g1, b1, ss1, ssh1, nullptr, 32);

    // conv2 (fused 2x2 min/max pool): bn1+relu(H0) -> minT2/maxT2 + stats
    conv_mfma_kernel<64, 32, 32, 1, false, true><<<dim3(16, 1, 256), 256, 0, stream>>>(
        H0, nullptr, ssh1, wt2, c2b, minT2, maxT2, part);
    bn_finalize_kernel<<<32, 256, 0, stream>>>(part, 16, 1, 1.f / 1048576.f,
                                               g2, b2, ss2, nullptr, sab2, 32);

    // conv3 (minmax input): relu(bn2(pool1)) -> H0 (256,32,32,64) + stats
    conv_mfma_kernel<32, 32, 64, 1, true, false><<<dim3(4, 2, 256), 256, 0, stream>>>(
        minT2, maxT2, sab2, wt3, c3b, H0, nullptr, part);
    bn_finalize_kernel<<<64, 256, 0, stream>>>(part, 4, 2, 1.f / 262144.f,
                                               g3, b3, ss3, ssh3, nullptr, 64);

    // conv4 (2 ci-chunks, fused pool): bn3+relu(H0) -> minT4/maxT4 + stats
    conv_mfma_kernel<32, 64, 64, 2, false, true><<<dim3(4, 2, 256), 256, 0, stream>>>(
        H0, nullptr, ssh3, wt4, c4b, minT4, maxT4, part);
    bn_finalize_kernel<<<64, 256, 0, stream>>>(part, 4, 2, 1.f / 262144.f,
                                               g4, b4, ss4, nullptr, sab4, 64);

    // fc1: MFMA GEMM with on-the-fly relu(bn4(pool2)) + reduce -> h1
    fc1_mfma_kernel<<<dim3(4, 32), 256, 0, stream>>>(minT4, maxT4, sab4, w1t, hp);
    fc1_reduce_kernel<<<128, 256, 0, stream>>>(hp, f1b, h1);

    // fc2 -> xq (256,10)
    fc2_kernel<<<256, 64, 0, stream>>>(h1, f2w, f2b, xqv);

    // quantum circuit + head -> out (256,10)
    quantum_head_kernel<<<256, 64, 0, stream>>>(xqv, rotm, perm16, hw, hb, (float*)d_out);
}

// Round 10
// 221.808 us; speedup vs baseline: 8.1522x; 1.0640x over previous
//
#include <hip/hip_runtime.h>
#include <math.h>

#define PI_F 3.14159265358979323846f

typedef __attribute__((ext_vector_type(8))) _Float16 half8;
typedef __attribute__((ext_vector_type(4))) _Float16 half4;
typedef __attribute__((ext_vector_type(4))) float f32x4;

// ---------------------------------------------------------------------------
// x (256,3,64,64) fp32 -> X4 (256,64,64,4) fp16, channel 3 zero-padded.
// ---------------------------------------------------------------------------
__global__ __launch_bounds__(256) void x_to_nhwc4_kernel(
    const float* __restrict__ x, _Float16* __restrict__ X4)
{
    int idx = blockIdx.x * 256 + threadIdx.x;      // 524,288
    int n = idx >> 11;
    int p = (idx & 2047) * 2;
    const float* xb = x + (size_t)n * 12288;
    float2 c0 = *(const float2*)&xb[p];
    float2 c1 = *(const float2*)&xb[4096 + p];
    float2 c2 = *(const float2*)&xb[8192 + p];
    half8 o;
    o[0] = (_Float16)c0.x; o[1] = (_Float16)c1.x; o[2] = (_Float16)c2.x; o[3] = (_Float16)0.f;
    o[4] = (_Float16)c0.y; o[5] = (_Float16)c1.y; o[6] = (_Float16)c2.y; o[7] = (_Float16)0.f;
    *(half8*)&X4[(size_t)idx * 8] = o;
}

// ---------------------------------------------------------------------------
// Weight transforms to channel-blocked fp16 layouts.
// ---------------------------------------------------------------------------
__global__ __launch_bounds__(256) void wt_transform_kernel(
    const float* __restrict__ w1, const float* __restrict__ w2,
    const float* __restrict__ w3, const float* __restrict__ w4,
    _Float16* __restrict__ t1, _Float16* __restrict__ t2,
    _Float16* __restrict__ t3, _Float16* __restrict__ t4)
{
    int idx = blockIdx.x * 256 + threadIdx.x;
    if (idx < 9216) {               // conv2: K=288, 1 group
        int j = idx & 7, co = (idx >> 3) & 31, k8 = idx >> 8;
        int k = k8 * 8 + j, tap = k >> 5, ci = k & 31;
        t2[idx] = (_Float16)w2[(size_t)(co * 32 + ci) * 9 + tap];
    } else if (idx < 27648) {       // conv3: K=288, 2 cout groups
        int e = idx - 9216;
        int j = e & 7, co = (e >> 3) & 31, r = e >> 8;
        int k8 = r % 36, gg = r / 36;
        int k = k8 * 8 + j, tap = k >> 5, ci = k & 31;
        t3[e] = (_Float16)w3[(size_t)((gg * 32 + co) * 32 + ci) * 9 + tap];
    } else if (idx < 64512) {       // conv4: 2 cout groups x 2 ci-chunks
        int e = idx - 27648;
        int j = e & 7, co = (e >> 3) & 31, r = e >> 8;   // r 0..143
        int k8 = r % 36, gc = r / 36;                    // gc = g*2+cc
        int g = gc >> 1, cc = gc & 1;
        int kl = k8 * 8 + j, tap = kl >> 5, ci = cc * 32 + (kl & 31);
        t4[e] = (_Float16)w4[(size_t)((g * 32 + co) * 64 + ci) * 9 + tap];
    } else if (idx < 66560) {       // conv1: K=64 padded
        int e = idx - 64512;
        int j = e & 7, co = (e >> 3) & 31, k8 = e >> 8;  // 0..7
        int k = k8 * 8 + j, tap = k >> 2, ci = k & 3;
        t1[e] = (_Float16)((tap < 9 && ci < 3) ? w1[(size_t)(co * 3 + ci) * 9 + tap] : 0.f);
    }
}

// ---------------------------------------------------------------------------
// fc1 weight transform: f1w [128][16384] fp32 NCHW-k -> w1t fp16 NHWC-k.
// ---------------------------------------------------------------------------
__global__ __launch_bounds__(256) void fc1w_transform_kernel(
    const float* __restrict__ w, _Float16* __restrict__ wt)
{
    __shared__ float lds[64][65];
    const int t = threadIdx.x;
    const int yx0 = blockIdx.x * 64;
    const int j = blockIdx.y;
    #pragma unroll
    for (int i = 0; i < 16; ++i) {
        int idx = t + 256 * i;
        int c = idx >> 6, yxl = idx & 63;
        lds[c][yxl] = w[(size_t)j * 16384 + c * 256 + yx0 + yxl];
    }
    __syncthreads();
    #pragma unroll
    for (int i = 0; i < 2; ++i) {
        int idx = t + 256 * i;
        int yxl = idx >> 3, c8 = idx & 7;
        half8 h;
        #pragma unroll
        for (int jj = 0; jj < 8; ++jj)
            h[jj] = (_Float16)lds[c8 * 8 + jj][yxl];
        *(half8*)&wt[(size_t)j * 16384 + (size_t)(yx0 + yxl) * 64 + c8 * 8] = h;
    }
}

// ---------------------------------------------------------------------------
// quantum_prep: 60 Rot matrices + 6x1024 u16 perm table (depends only on qw).
// ---------------------------------------------------------------------------
__global__ __launch_bounds__(256) void quantum_prep_kernel(
    const float* __restrict__ qw, float* __restrict__ rotm,
    unsigned short* __restrict__ perm)
{
    int t = threadIdx.x;
    if (t < 60) {
        float phi = qw[t * 3], th = qw[t * 3 + 1], om = qw[t * 3 + 2];
        float c = cosf(0.5f * th), s = sinf(0.5f * th);
        float apo = 0.5f * (phi + om), amo = 0.5f * (phi - om);
        float cpo = cosf(apo), spo = sinf(apo);
        float cmo = cosf(amo), smo = sinf(amo);
        rotm[t * 8 + 0] = cpo * c;  rotm[t * 8 + 1] = -spo * c;
        rotm[t * 8 + 2] = -cmo * s; rotm[t * 8 + 3] = -smo * s;
        rotm[t * 8 + 4] = cmo * s;  rotm[t * 8 + 5] = -smo * s;
        rotm[t * 8 + 6] = cpo * c;  rotm[t * 8 + 7] = spo * c;
    }
    for (int e = t; e < 6144; e += 256) {
        int layer = e >> 10, i = e & 1023;
        int r = layer % 9 + 1;
        int jdx = i;
        for (int w = 9; w >= 0; --w) {
            int tt = (w + r) % 10;
            int pc = 9 - w, pt_ = 9 - tt;
            jdx ^= ((jdx >> pc) & 1) << pt_;
        }
        perm[e] = (unsigned short)jdx;
    }
}

// ---------------------------------------------------------------------------
// conv1 via MFMA: X4 NHWC4 fp16 -> out (256,64,64,32) fp16 + stats.
// ---------------------------------------------------------------------------
__global__ __launch_bounds__(256) void conv1_mfma_kernel(
    const _Float16* __restrict__ X4, const _Float16* __restrict__ w1m,
    const float* __restrict__ bias, _Float16* __restrict__ out,
    float* __restrict__ partials)
{
    constexpr int TC = 66, TR = 6;
    constexpr int NPIX = (TR + 1) * TC;     // 462
    __shared__ __align__(16) _Float16 s_in[NPIX * 4];
    __shared__ __align__(16) _Float16 s_w[2048];
    __shared__ float s_red[64];

    const int t = threadIdx.x;
    const int row0 = blockIdx.x * 4;
    const int n = blockIdx.z;

    *(half8*)&s_w[t * 8] = *(const half8*)&w1m[t * 8];

    for (int p = t; p < NPIX; p += 256) {
        int col = p % TC, r = p / TC;
        int gy = row0 + r - 1, gx = col - 1;
        uint2 u = make_uint2(0u, 0u);
        if (r < TR && gy >= 0 && gy < 64 && gx >= 0 && gx < 64)
            u = *(const uint2*)&X4[(((size_t)n << 12) + (gy << 6) + gx) * 4];
        *(uint2*)&s_in[p * 4] = u;
    }
    if (t < 64) s_red[t] = 0.f;
    __syncthreads();

    const int w = t >> 6, l = t & 63;
    const int lm = l & 15, lg = l >> 4;
    int pA[4];
    #pragma unroll
    for (int f = 0; f < 4; ++f) {
        int m = w * 64 + f * 16 + lm;
        pA[f] = (m >> 6) * TC + (m & 63);
    }
    f32x4 zero4 = {0.f, 0.f, 0.f, 0.f};
    f32x4 acc[4][2];
    #pragma unroll
    for (int f = 0; f < 4; ++f) { acc[f][0] = zero4; acc[f][1] = zero4; }

    {
        const int t0 = lg * 2;
        const int off0 = (t0 / 3) * TC + (t0 % 3);
        const int off1 = ((t0 + 1) / 3) * TC + ((t0 + 1) % 3);
        half8 b0 = *(const half8*)&s_w[(lg * 32 + lm) * 8];
        half8 b1 = *(const half8*)&s_w[(lg * 32 + 16 + lm) * 8];
        #pragma unroll
        for (int f = 0; f < 4; ++f) {
            half4 alo = *(const half4*)&s_in[(pA[f] + off0) * 4];
            half4 ahi = *(const half4*)&s_in[(pA[f] + off1) * 4];
            half8 a;
            #pragma unroll
            for (int j = 0; j < 4; ++j) { a[j] = alo[j]; a[4 + j] = ahi[j]; }
            acc[f][0] = __builtin_amdgcn_mfma_f32_16x16x32_f16(a, b0, acc[f][0], 0, 0, 0);
            acc[f][1] = __builtin_amdgcn_mfma_f32_16x16x32_f16(a, b1, acc[f][1], 0, 0, 0);
        }
    }
    {
        half8 b0 = *(const half8*)&s_w[((4 + lg) * 32 + lm) * 8];
        half8 b1 = *(const half8*)&s_w[((4 + lg) * 32 + 16 + lm) * 8];
        #pragma unroll
        for (int f = 0; f < 4; ++f) {
            half8 a;
            #pragma unroll
            for (int j = 0; j < 8; ++j) a[j] = (_Float16)0.f;
            if (lg == 0) {
                half4 alo = *(const half4*)&s_in[(pA[f] + 134) * 4];
                half4 ahi = *(const half4*)&s_in[(pA[f] + 198) * 4];
                #pragma unroll
                for (int j = 0; j < 4; ++j) { a[j] = alo[j]; a[4 + j] = ahi[j]; }
            }
            acc[f][0] = __builtin_amdgcn_mfma_f32_16x16x32_f16(a, b0, acc[f][0], 0, 0, 0);
            acc[f][1] = __builtin_amdgcn_mfma_f32_16x16x32_f16(a, b1, acc[f][1], 0, 0, 0);
        }
    }

    float bv0 = bias[lm];
    float bv1 = bias[16 + lm];
    float s0 = 0.f, s20 = 0.f, s1 = 0.f, s21 = 0.f;
    #pragma unroll
    for (int f = 0; f < 4; ++f) {
        #pragma unroll
        for (int r = 0; r < 4; ++r) {
            int m = w * 64 + f * 16 + lg * 4 + r;
            int yy = row0 + (m >> 6), xo = m & 63;
            size_t base = (((size_t)n * 64 + yy) * 64 + xo) * 32;
            float v0 = acc[f][0][r] + bv0;
            float v1 = acc[f][1][r] + bv1;
            out[base + lm] = (_Float16)v0;
            out[base + 16 + lm] = (_Float16)v1;
            s0 += v0; s20 += v0 * v0;
            s1 += v1; s21 += v1 * v1;
        }
    }
    s0 += __shfl_xor(s0, 16);  s0 += __shfl_xor(s0, 32);
    s1 += __shfl_xor(s1, 16);  s1 += __shfl_xor(s1, 32);
    s20 += __shfl_xor(s20, 16); s20 += __shfl_xor(s20, 32);
    s21 += __shfl_xor(s21, 16); s21 += __shfl_xor(s21, 32);
    if (l < 16) {
        atomicAdd(&s_red[lm], s0);
        atomicAdd(&s_red[16 + lm], s1);
        atomicAdd(&s_red[32 + lm], s20);
        atomicAdd(&s_red[48 + lm], s21);
    }
    __syncthreads();
    if (t < 64)
        partials[((size_t)n * 16 + blockIdx.x) * 64 + t] = s_red[t];
}

// ---------------------------------------------------------------------------
// Implicit-GEMM 3x3 conv via MFMA, BLOCK threads (BLOCK/64 waves, BLOCK
// spatial pixels per block). Channel-blocked LDS, ci-chunked staging.
// MMIN: input is pooled pre-BN (min,max) pair; stage relu(max*sA+min*sB+sh).
// POOL: write 2x2-pooled pre-BN (min,max) pair instead of full-res output.
// Always emits per-block per-cout sum/sumsq of full-res conv+bias output.
// ---------------------------------------------------------------------------
template<int BLOCK, int W, int CIN, int COUT, int NCH, bool MMIN, bool POOL>
__global__ __launch_bounds__(BLOCK) void conv_mfma_kernel(
    const _Float16* __restrict__ in0, const _Float16* __restrict__ in1,
    const _Float16* __restrict__ coef, const _Float16* __restrict__ wt,
    const float* __restrict__ bias,
    _Float16* __restrict__ out0, _Float16* __restrict__ out1,
    float* __restrict__ partials)
{
    constexpr int H = W;
    constexpr int NW = BLOCK / 64;          // waves
    constexpr int ROWS = BLOCK / W;
    constexpr int TR = ROWS + 2;
    constexpr int TC = W + 2;
    constexpr int NPIX = TR * TC;
    constexpr int CCI = 32;
    constexpr int KC = 9 * CCI;             // 288
    __shared__ __align__(16) _Float16 s_in[NPIX * CCI];
    __shared__ __align__(16) _Float16 s_w[KC * 32];
    __shared__ float s_red[64];

    const int t = threadIdx.x;
    const int row0 = blockIdx.x * ROWS;
    const int g = blockIdx.y;
    const int cout0 = g * 32;
    const int n = blockIdx.z;

    const int w = t >> 6, l = t & 63;
    const int lm = l & 15, lg = l >> 4;
    int pA[4];
    #pragma unroll
    for (int f = 0; f < 4; ++f) {
        int m = w * 64 + f * 16 + lm;
        pA[f] = (m / W) * TC + (m % W);
    }
    f32x4 zero4 = {0.f, 0.f, 0.f, 0.f};
    f32x4 acc[4][2];
    #pragma unroll
    for (int f = 0; f < 4; ++f) { acc[f][0] = zero4; acc[f][1] = zero4; }
    if (t < 64) s_red[t] = 0.f;

    #pragma unroll
    for (int cc = 0; cc < NCH; ++cc) {
        __syncthreads();
        // ---- stage weights chunk (linear, pre-arranged) ----
        const _Float16* wg = wt + (size_t)(g * NCH + cc) * KC * 32;
        for (int idx = t; idx < KC * 4; idx += BLOCK)
            *(half8*)&s_w[idx * 8] = *(const half8*)&wg[(size_t)idx * 8];
        // ---- stage input chunk ----
        for (int idx = t; idx < NPIX * 4; idx += BLOCK) {
            int c8 = idx & 3;
            int p = idx >> 2;
            int col = p % TC, r = p / TC;
            int gy = row0 + r - 1, gx = col - 1;
            half8 v;
            #pragma unroll
            for (int j = 0; j < 8; ++j) v[j] = (_Float16)0.f;
            if (gy >= 0 && gy < H && gx >= 0 && gx < W) {
                size_t gidx = (((size_t)n * H + gy) * W + gx) * CIN + cc * CCI + c8 * 8;
                if (MMIN) {
                    half8 mn = *(const half8*)&in0[gidx];
                    half8 mx = *(const half8*)&in1[gidx];
                    half8 sa = *(const half8*)&coef[cc * CCI + c8 * 8];
                    half8 sb = *(const half8*)&coef[CIN + cc * CCI + c8 * 8];
                    half8 sh = *(const half8*)&coef[2 * CIN + cc * CCI + c8 * 8];
                    #pragma unroll
                    for (int j = 0; j < 8; ++j) {
                        _Float16 f = mx[j] * sa[j] + mn[j] * sb[j] + sh[j];
                        v[j] = f > (_Float16)0.f ? f : (_Float16)0.f;
                    }
                } else {
                    v = *(const half8*)&in0[gidx];
                    if (coef) {
                        half8 sc = *(const half8*)&coef[cc * CCI + c8 * 8];
                        half8 sh = *(const half8*)&coef[CIN + cc * CCI + c8 * 8];
                        #pragma unroll
                        for (int j = 0; j < 8; ++j) {
                            _Float16 f = v[j] * sc[j] + sh[j];
                            v[j] = f > (_Float16)0.f ? f : (_Float16)0.f;
                        }
                    }
                }
            }
            *(half8*)&s_in[(c8 * NPIX + p) * 8] = v;
        }
        __syncthreads();
        // ---- compute chunk: 9 K-steps, 8 MFMA each ----
        #pragma unroll
        for (int ksl = 0; ksl < KC; ksl += 32) {
            const int tap = ksl >> 5;
            const int dy = tap / 3, dx = tap % 3;
            const int poff = dy * TC + dx;
            half8 b0 = *(const half8*)&s_w[((tap * 4 + lg) * 32 + lm) * 8];
            half8 b1 = *(const half8*)&s_w[((tap * 4 + lg) * 32 + 16 + lm) * 8];
            #pragma unroll
            for (int f = 0; f < 4; ++f) {
                half8 a = *(const half8*)&s_in[(lg * NPIX + pA[f] + poff) * 8];
                acc[f][0] = __builtin_amdgcn_mfma_f32_16x16x32_f16(a, b0, acc[f][0], 0, 0, 0);
                acc[f][1] = __builtin_amdgcn_mfma_f32_16x16x32_f16(a, b1, acc[f][1], 0, 0, 0);
            }
        }
    }

    // ---- stats over full-res conv+bias output ----
    float bv0 = bias[cout0 + lm];
    float bv1 = bias[cout0 + 16 + lm];
    float s0 = 0.f, s20 = 0.f, s1 = 0.f, s21 = 0.f;
    #pragma unroll
    for (int f = 0; f < 4; ++f) {
        #pragma unroll
        for (int r = 0; r < 4; ++r) {
            float v0 = acc[f][0][r] + bv0;
            float v1 = acc[f][1][r] + bv1;
            if (!POOL) {
                int m = w * 64 + f * 16 + lg * 4 + r;
                int yy = row0 + m / W, xo = m % W;
                size_t base = (((size_t)n * H + yy) * W + xo) * COUT + cout0;
                out0[base + lm] = (_Float16)v0;
                out0[base + 16 + lm] = (_Float16)v1;
            }
            s0 += v0; s20 += v0 * v0;
            s1 += v1; s21 += v1 * v1;
        }
    }
    s0 += __shfl_xor(s0, 16);  s0 += __shfl_xor(s0, 32);
    s1 += __shfl_xor(s1, 16);  s1 += __shfl_xor(s1, 32);
    s20 += __shfl_xor(s20, 16); s20 += __shfl_xor(s20, 32);
    s21 += __shfl_xor(s21, 16); s21 += __shfl_xor(s21, 32);
    if (l < 16) {
        atomicAdd(&s_red[lm], s0);
        atomicAdd(&s_red[16 + lm], s1);
        atomicAdd(&s_red[32 + lm], s20);
        atomicAdd(&s_red[48 + lm], s21);
    }

    if (POOL) {
        if (W == 32) {
            // fully in-lane: vertical (f, f+2), horizontal (2rp, 2rp+1)
            #pragma unroll
            for (int b = 0; b < 2; ++b) {
                float bv = b ? bv1 : bv0;
                #pragma unroll
                for (int fh = 0; fh < 2; ++fh) {
                    #pragma unroll
                    for (int rp = 0; rp < 2; ++rp) {
                        float a0 = acc[fh][b][2 * rp] + bv;
                        float a1 = acc[fh][b][2 * rp + 1] + bv;
                        float a2 = acc[fh + 2][b][2 * rp] + bv;
                        float a3 = acc[fh + 2][b][2 * rp + 1] + bv;
                        float mn = fminf(fminf(a0, a1), fminf(a2, a3));
                        float mx = fmaxf(fmaxf(a0, a1), fmaxf(a2, a3));
                        int xp = fh * 8 + lg * 2 + rp;
                        int yp = (row0 >> 1) + w;
                        size_t ob = (((size_t)n * (W / 2) + yp) * (W / 2) + xp) * COUT
                                    + cout0 + b * 16 + lm;
                        out0[ob] = (_Float16)mn;
                        out1[ob] = (_Float16)mx;
                    }
                }
            }
        } else {
            // W == 64: horizontal in-lane; vertical via LDS exchange.
            // Each wave owns one full row. Reuse s_in as the exchange buffer:
            // MM entries of min + MM of max, MM = NW*32*32.
            constexpr int MM = NW * 32 * 32;
            static_assert(MM * 2 <= NPIX * CCI, "exchange buffer fits in s_in");
            __syncthreads();               // all MFMA reads of s_in done
            _Float16* vp = s_in;
            #pragma unroll
            for (int b = 0; b < 2; ++b) {
                float bv = b ? bv1 : bv0;
                #pragma unroll
                for (int f = 0; f < 4; ++f) {
                    #pragma unroll
                    for (int rp = 0; rp < 2; ++rp) {
                        float a0 = acc[f][b][2 * rp] + bv;
                        float a1 = acc[f][b][2 * rp + 1] + bv;
                        int xp = f * 8 + lg * 2 + rp;
                        int o = (w * 32 + xp) * 32 + b * 16 + lm;
                        vp[o] = (_Float16)fminf(a0, a1);
                        vp[MM + o] = (_Float16)fmaxf(a0, a1);
                    }
                }
            }
            __syncthreads();
            // gather vertical pairs: pooled rows = ROWS/2, 128 threads each
            constexpr int PR = ROWS / 2;
            if (t < PR * 128) {
                int wp = t >> 7, e = t & 127;
                int xp = e >> 2, c8 = e & 3;
                half8 mnA = *(const half8*)&vp[((2 * wp) * 32 + xp) * 32 + c8 * 8];
                half8 mnB = *(const half8*)&vp[((2 * wp + 1) * 32 + xp) * 32 + c8 * 8];
                half8 mxA = *(const half8*)&vp[MM + ((2 * wp) * 32 + xp) * 32 + c8 * 8];
                half8 mxB = *(const half8*)&vp[MM + ((2 * wp + 1) * 32 + xp) * 32 + c8 * 8];
                half8 mn, mx;
                #pragma unroll
                for (int j = 0; j < 8; ++j) {
                    mn[j] = mnA[j] < mnB[j] ? mnA[j] : mnB[j];
                    mx[j] = mxA[j] > mxB[j] ? mxA[j] : mxB[j];
                }
                size_t ob = (((size_t)n * (W / 2) + (row0 >> 1) + wp) * (W / 2) + xp) * COUT
                            + cout0 + c8 * 8;
                *(half8*)&out0[ob] = mn;
                *(half8*)&out1[ob] = mx;
            }
        }
    }

    __syncthreads();
    if (t < 64) {
        size_t bid = ((size_t)n * gridDim.y + blockIdx.y) * gridDim.x + blockIdx.x;
        partials[bid * 64 + t] = s_red[t];
    }
}

// ---------------------------------------------------------------------------
// Reduce per-block partials -> BN coefficients:
// ss (fp32 pair), ssh (fp16 pair), sab (fp16 triple sA,sB,sh for minmax).
// ---------------------------------------------------------------------------
__global__ __launch_bounds__(256) void bn_finalize_kernel(
    const float* __restrict__ partials, int nx, int ng, float inv_count,
    const float* __restrict__ gamma, const float* __restrict__ beta,
    float* __restrict__ ss, _Float16* __restrict__ ssh,
    _Float16* __restrict__ sab, int COUT)
{
    const int c = blockIdx.x;
    const int g = c >> 5, i = c & 31;
    const int t = threadIdx.x;
    float sum = 0.f, sq = 0.f;
    int total = 256 * nx;
    for (int e = t; e < total; e += 256) {
        int n = e / nx, xt = e - n * nx;
        size_t bid = ((size_t)(n * ng + g) * nx + xt) * 64;
        sum += partials[bid + i];
        sq  += partials[bid + 32 + i];
    }
    #pragma unroll
    for (int off = 32; off > 0; off >>= 1) {
        sum += __shfl_xor(sum, off);
        sq  += __shfl_xor(sq, off);
    }
    __shared__ float rs[4], rq[4];
    if ((t & 63) == 0) { rs[t >> 6] = sum; rq[t >> 6] = sq; }
    __syncthreads();
    if (t == 0) {
        sum = rs[0] + rs[1] + rs[2] + rs[3];
        sq  = rq[0] + rq[1] + rq[2] + rq[3];
        float mean = sum * inv_count;
        float var = sq * inv_count - mean * mean;
        float scale = gamma[c] * rsqrtf(var + 1e-5f);
        float shift = beta[c] - mean * scale;
        ss[c] = scale;
        ss[COUT + c] = shift;
        if (ssh) {
            ssh[c] = (_Float16)scale;
            ssh[COUT + c] = (_Float16)shift;
        }
        if (sab) {
            sab[c] = (_Float16)(scale > 0.f ? scale : 0.f);
            sab[COUT + c] = (_Float16)(scale > 0.f ? 0.f : scale);
            sab[2 * COUT + c] = (_Float16)shift;
        }
    }
}

// ---------------------------------------------------------------------------
// fc1 MFMA GEMM (K-split): A = relu(bn4(pooled minmax pair)) on the fly.
// ---------------------------------------------------------------------------
__global__ __launch_bounds__(256) void fc1_mfma_kernel(
    const _Float16* __restrict__ Amin, const _Float16* __restrict__ Amax,
    const _Float16* __restrict__ sab, const _Float16* __restrict__ Bw,
    float* __restrict__ hp)
{
    __shared__ __align__(16) _Float16 As[64][72];
    __shared__ __align__(16) _Float16 Bs[128][72];
    const int t = threadIdx.x;
    const int mt = blockIdx.x;
    const int kc = blockIdx.y;
    const int w = t >> 6, l = t & 63;
    const int lm = l & 15, lg = l >> 4;

    f32x4 zero4 = {0.f, 0.f, 0.f, 0.f};
    f32x4 acc[8];
    #pragma unroll
    for (int nb = 0; nb < 8; ++nb) acc[nb] = zero4;

    const size_t a_base = (size_t)(mt * 64) * 16384 + (size_t)kc * 512;
    const size_t b_base = (size_t)kc * 512;

    for (int p = 0; p < 8; ++p) {
        __syncthreads();
        #pragma unroll
        for (int i = 0; i < 2; ++i) {
            int idx = t + 256 * i;
            int r = idx >> 3, c8 = idx & 7;
            size_t off = a_base + (size_t)r * 16384 + p * 64 + c8 * 8;
            half8 mn = *(const half8*)&Amin[off];
            half8 mx = *(const half8*)&Amax[off];
            half8 sa = *(const half8*)&sab[c8 * 8];
            half8 sb = *(const half8*)&sab[64 + c8 * 8];
            half8 sh = *(const half8*)&sab[128 + c8 * 8];
            half8 v;
            #pragma unroll
            for (int j = 0; j < 8; ++j) {
                _Float16 f = mx[j] * sa[j] + mn[j] * sb[j] + sh[j];
                v[j] = f > (_Float16)0.f ? f : (_Float16)0.f;
            }
            *(half8*)&As[r][c8 * 8] = v;
        }
        #pragma unroll
        for (int i = 0; i < 4; ++i) {
            int idx = t + 256 * i;
            int r = idx >> 3, c8 = idx & 7;
            *(half8*)&Bs[r][c8 * 8] =
                *(const half8*)&Bw[b_base + (size_t)r * 16384 + p * 64 + c8 * 8];
        }
        __syncthreads();
        #pragma unroll
        for (int ks = 0; ks < 64; ks += 32) {
            half8 a = *(const half8*)&As[w * 16 + lm][ks + lg * 8];
            #pragma unroll
            for (int nb = 0; nb < 8; ++nb) {
                half8 b = *(const half8*)&Bs[nb * 16 + lm][ks + lg * 8];
                acc[nb] = __builtin_amdgcn_mfma_f32_16x16x32_f16(a, b, acc[nb], 0, 0, 0);
            }
        }
    }
    #pragma unroll
    for (int nb = 0; nb < 8; ++nb) {
        #pragma unroll
        for (int r = 0; r < 4; ++r) {
            int row = mt * 64 + w * 16 + lg * 4 + r;
            hp[((size_t)kc * 256 + row) * 128 + nb * 16 + lm] = acc[nb][r];
        }
    }
}

__global__ __launch_bounds__(256) void fc1_reduce_kernel(
    const float* __restrict__ hp, const float* __restrict__ bias, float* __restrict__ h1)
{
    int gid = blockIdx.x * 256 + threadIdx.x;   // 32768
    int n = gid >> 7, j = gid & 127;
    float s = bias[j];
    #pragma unroll
    for (int kc = 0; kc < 32; ++kc) s += hp[((size_t)kc * 256 + n) * 128 + j];
    h1[gid] = fmaxf(0.f, s);
}

// ---------------------------------------------------------------------------
// fc2: (256,128) x (10,128)^T + b -> xq (256,10). One wave per batch element.
// ---------------------------------------------------------------------------
__global__ __launch_bounds__(64) void fc2_kernel(
    const float* __restrict__ h1, const float* __restrict__ w,
    const float* __restrict__ b, float* __restrict__ xq)
{
    int n = blockIdx.x, l = threadIdx.x;
    float a0 = h1[n * 128 + l], a1 = h1[n * 128 + 64 + l];
    float p[10];
    #pragma unroll
    for (int j = 0; j < 10; ++j)
        p[j] = w[j * 128 + l] * a0 + w[j * 128 + 64 + l] * a1;
    #pragma unroll
    for (int j = 0; j < 10; ++j) {
        #pragma unroll
        for (int off = 32; off > 0; off >>= 1) p[j] += __shfl_xor(p[j], off);
    }
    if (l == 0) {
        #pragma unroll
        for (int j = 0; j < 10; ++j) xq[n * 10 + j] = p[j] + b[j];
    }
}

// ---------------------------------------------------------------------------
// Quantum circuit + Z-exp + head: ONE WAVE per batch element (reg-resident).
// ---------------------------------------------------------------------------
__global__ __launch_bounds__(64) void quantum_head_kernel(
    const float* __restrict__ xq, const float* __restrict__ rotm,
    const unsigned short* __restrict__ perm,
    const float* __restrict__ head_w, const float* __restrict__ head_b,
    float* __restrict__ outp)
{
    __shared__ float lds[2048];
    const int n = blockIdx.x;
    const int l = threadIdx.x;

    float ar[16], ai[16];
    #pragma unroll
    for (int r = 0; r < 16; ++r) { ar[r] = 0.f; ai[r] = 0.f; }
    if (l == 0) ar[0] = 1.f;

    #pragma unroll
    for (int w = 0; w < 10; ++w) {
        float th = 0.5f * PI_F * xq[n * 10 + w];
        float c = cosf(th), s = sinf(th);
        const int k = 9 - w;
        if (k >= 6) {
            const int b = k - 6;
            #pragma unroll
            for (int r = 0; r < 16; ++r) {
                if (!(r & (1 << b))) {
                    int r1 = r | (1 << b);
                    float a0 = ar[r], a1 = ar[r1];
                    ar[r]  = c * a0 - s * a1;
                    ar[r1] = s * a0 + c * a1;
                }
            }
        } else {
            float ss = ((l >> k) & 1) ? s : -s;
            #pragma unroll
            for (int r = 0; r < 16; ++r) {
                float p = __shfl_xor(ar[r], 1 << k);
                ar[r] = c * ar[r] + ss * p;
            }
        }
    }

    #pragma unroll 1
    for (int layer = 0; layer < 6; ++layer) {
        #pragma unroll
        for (int w = 0; w < 10; ++w) {
            const float* m = rotm + (layer * 10 + w) * 8;
            float m00r = m[0], m00i = m[1], m01r = m[2], m01i = m[3];
            float m10r = m[4], m10i = m[5], m11r = m[6], m11i = m[7];
            const int k = 9 - w;
            if (k >= 6) {
                const int b = k - 6;
                #pragma unroll
                for (int r = 0; r < 16; ++r) {
                    if (!(r & (1 << b))) {
                        int r1 = r | (1 << b);
                        float a0r = ar[r], a0i = ai[r];
                        float a1r = ar[r1], a1i = ai[r1];
                        ar[r]  = m00r * a0r - m00i * a0i + m01r * a1r - m01i * a1i;
                        ai[r]  = m00r * a0i + m00i * a0r + m01r * a1i + m01i * a1r;
                        ar[r1] = m10r * a0r - m10i * a0i + m11r * a1r - m11i * a1i;
                        ai[r1] = m10r * a0i + m10i * a0r + m11r * a1i + m11i * a1r;
                    }
                }
            } else {
                int bit = (l >> k) & 1;
                float mAr = bit ? m11r : m00r, mAi = bit ? m11i : m00i;
                float mBr = bit ? m10r : m01r, mBi = bit ? m10i : m01i;
                #pragma unroll
                for (int r = 0; r < 16; ++r) {
                    float pr = __shfl_xor(ar[r], 1 << k);
                    float pi = __shfl_xor(ai[r], 1 << k);
                    float mr = ar[r], mi = ai[r];
                    ar[r] = mAr * mr - mAi * mi + mBr * pr - mBi * pi;
                    ai[r] = mAr * mi + mAi * mr + mBr * pi + mBi * pr;
                }
            }
        }
        #pragma unroll
        for (int r = 0; r < 16; ++r) {
            lds[(r << 6) | l] = ar[r];
            lds[1024 + ((r << 6) | l)] = ai[r];
        }
        __syncthreads();
        const unsigned short* pt = perm + layer * 1024;
        #pragma unroll
        for (int r = 0; r < 16; ++r) {
            int ji = pt[(r << 6) | l];
            ar[r] = lds[ji];
            ai[r] = lds[1024 + ji];
        }
        __syncthreads();
    }

    float S = 0.f, T0 = 0.f, T1 = 0.f, T2 = 0.f, T3 = 0.f;
    #pragma unroll
    for (int r = 0; r < 16; ++r) {
        float pr = ar[r] * ar[r] + ai[r] * ai[r];
        S += pr;
        T0 += (r & 1) ? -pr : pr;
        T1 += (r & 2) ? -pr : pr;
        T2 += (r & 4) ? -pr : pr;
        T3 += (r & 8) ? -pr : pr;
    }
    float pk[10];
    pk[0] = T3; pk[1] = T2; pk[2] = T1; pk[3] = T0;
    #pragma unroll
    for (int w = 4; w < 10; ++w)
        pk[w] = ((l >> (9 - w)) & 1) ? -S : S;
    #pragma unroll
    for (int w = 0; w < 10; ++w) {
        #pragma unroll
        for (int off = 1; off < 64; off <<= 1)
            pk[w] += __shfl_xor(pk[w], off);
    }
    if (l < 10) {
        float o = head_b[l];
        #pragma unroll
        for (int kk = 0; kk < 10; ++kk) o += pk[kk] * head_w[l * 10 + kk];
        outp[n * 10 + l] = o;
    }
}

// ---------------------------------------------------------------------------
extern "C" void kernel_launch(void* const* d_in, const int* in_sizes, int n_in,
                              void* d_out, int out_size, void* d_ws, size_t ws_size,
                              hipStream_t stream)
{
    const float* x   = (const float*)d_in[0];
    const float* c1w = (const float*)d_in[1];  const float* c1b = (const float*)d_in[2];
    const float* g1  = (const float*)d_in[3];  const float* b1  = (const float*)d_in[4];
    const float* c2w = (const float*)d_in[5];  const float* c2b = (const float*)d_in[6];
    const float* g2  = (const float*)d_in[7];  const float* b2  = (const float*)d_in[8];
    const float* c3w = (const float*)d_in[9];  const float* c3b = (const float*)d_in[10];
    const float* g3  = (const float*)d_in[11]; const float* b3  = (const float*)d_in[12];
    const float* c4w = (const float*)d_in[13]; const float* c4b = (const float*)d_in[14];
    const float* g4  = (const float*)d_in[15]; const float* b4  = (const float*)d_in[16];
    const float* f1w = (const float*)d_in[17]; const float* f1b = (const float*)d_in[18];
    const float* f2w = (const float*)d_in[19]; const float* f2b = (const float*)d_in[20];
    const float* qw  = (const float*)d_in[21];
    const float* hw  = (const float*)d_in[22]; const float* hb  = (const float*)d_in[23];

    float* ws = (float*)d_ws;
    _Float16* H0 = (_Float16*)ws;              // 33,554,432 halves (64 MB)
    _Float16* H1 = H0 + 33554432;              // 33,554,432 halves (64 MB)
    float* part = ws + 33554432;               // 524,288
    float* ss1  = part + 524288;               // 64
    float* ss2  = ss1 + 64;                    // 64
    float* ss3  = ss2 + 64;                    // 128
    float* ss4  = ss3 + 128;                   // 128
    float* hp   = ss4 + 128;                   // 1,048,576
    float* h1   = hp + 1048576;                // 32,768
    float* xqv  = h1 + 32768;                  // 2,560
    float* rotm = xqv + 2560;                  // 480
    unsigned short* perm16 = (unsigned short*)(rotm + 480);   // 6,144 u16
    _Float16* ssh1 = (_Float16*)(perm16 + 6144);   // 64 halves
    _Float16* ssh3 = ssh1 + 64;                // 128
    _Float16* sab2 = ssh3 + 128;               // 96
    _Float16* sab4 = sab2 + 96;                // 192
    _Float16* wt2  = sab4 + 192;               // 9,216
    _Float16* wt3  = wt2 + 9216;               // 18,432
    _Float16* wt4  = wt3 + 18432;              // 36,864
    _Float16* w1m  = wt4 + 36864;              // 2,048
    _Float16* w1t  = w1m + 2048;               // 2,097,152
    _Float16* X4   = w1t + 2097152;            // 4,194,304 (8 MB)

    // overlays on H1 (sequential lifetimes)
    _Float16* minT2 = H1;                      // (256,32,32,32)
    _Float16* maxT2 = H1 + 8388608;
    _Float16* minT4 = H1;                      // (256,16,16,64)
    _Float16* maxT4 = H1 + 4194304;

    // one-time precomputes
    quantum_prep_kernel<<<1, 256, 0, stream>>>(qw, rotm, perm16);
    wt_transform_kernel<<<260, 256, 0, stream>>>(c1w, c2w, c3w, c4w, w1m, wt2, wt3, wt4);
    fc1w_transform_kernel<<<dim3(4, 128), 256, 0, stream>>>(f1w, w1t);
    x_to_nhwc4_kernel<<<2048, 256, 0, stream>>>(x, X4);

    // conv1 (MFMA): X4 -> H0 (256,64,64,32) + stats
    conv1_mfma_kernel<<<dim3(16, 1, 256), 256, 0, stream>>>(X4, w1m, c1b, H0, part);
    bn_finalize_kernel<<<32, 256, 0, stream>>>(part, 16, 1, 1.f / 1048576.f,
                                               g1, b1, ss1, ssh1, nullptr, 32);

    // conv2 (512 thr, fused 2x2 min/max pool): bn1+relu(H0) -> minT2/maxT2
    conv_mfma_kernel<512, 64, 32, 32, 1, false, true><<<dim3(8, 1, 256), 512, 0, stream>>>(
        H0, nullptr, ssh1, wt2, c2b, minT2, maxT2, part);
    bn_finalize_kernel<<<32, 256, 0, stream>>>(part, 8, 1, 1.f / 1048576.f,
                                               g2, b2, ss2, nullptr, sab2, 32);

    // conv3 (512 thr, minmax input): relu(bn2(pool1)) -> H0 (256,32,32,64)
    conv_mfma_kernel<512, 32, 32, 64, 1, true, false><<<dim3(2, 2, 256), 512, 0, stream>>>(
        minT2, maxT2, sab2, wt3, c3b, H0, nullptr, part);
    bn_finalize_kernel<<<64, 256, 0, stream>>>(part, 2, 2, 1.f / 262144.f,
                                               g3, b3, ss3, ssh3, nullptr, 64);

    // conv4 (512 thr, 2 ci-chunks, fused pool): bn3+relu(H0) -> minT4/maxT4
    conv_mfma_kernel<512, 32, 64, 64, 2, false, true><<<dim3(2, 2, 256), 512, 0, stream>>>(
        H0, nullptr, ssh3, wt4, c4b, minT4, maxT4, part);
    bn_finalize_kernel<<<64, 256, 0, stream>>>(part, 2, 2, 1.f / 262144.f,
                                               g4, b4, ss4, nullptr, sab4, 64);

    // fc1: MFMA GEMM with on-the-fly relu(bn4(pool2)) + reduce -> h1
    fc1_mfma_kernel<<<dim3(4, 32), 256, 0, stream>>>(minT4, maxT4, sab4, w1t, hp);
    fc1_reduce_kernel<<<128, 256, 0, stream>>>(hp, f1b, h1);

    // fc2 -> xq (256,10)
    fc2_kernel<<<256, 64, 0, stream>>>(h1, f2w, f2b, xqv);

    // quantum circuit + head -> out (256,10)
    quantum_head_kernel<<<256, 64, 0, stream>>>(xqv, rotm, perm16, hw, hb, (float*)d_out);
}

// Round 11
// 220.791 us; speedup vs baseline: 8.1898x; 1.0046x over previous
//
#include <hip/hip_runtime.h>
#include <math.h>

#define PI_F 3.14159265358979323846f

typedef __attribute__((ext_vector_type(8))) _Float16 half8;
typedef __attribute__((ext_vector_type(4))) _Float16 half4;
typedef __attribute__((ext_vector_type(4))) float f32x4;

// ---------------------------------------------------------------------------
// x (256,3,64,64) fp32 -> X4 (256,64,64,4) fp16, channel 3 zero-padded.
// ---------------------------------------------------------------------------
__global__ __launch_bounds__(256) void x_to_nhwc4_kernel(
    const float* __restrict__ x, _Float16* __restrict__ X4)
{
    int idx = blockIdx.x * 256 + threadIdx.x;      // 524,288
    int n = idx >> 11;
    int p = (idx & 2047) * 2;
    const float* xb = x + (size_t)n * 12288;
    float2 c0 = *(const float2*)&xb[p];
    float2 c1 = *(const float2*)&xb[4096 + p];
    float2 c2 = *(const float2*)&xb[8192 + p];
    half8 o;
    o[0] = (_Float16)c0.x; o[1] = (_Float16)c1.x; o[2] = (_Float16)c2.x; o[3] = (_Float16)0.f;
    o[4] = (_Float16)c0.y; o[5] = (_Float16)c1.y; o[6] = (_Float16)c2.y; o[7] = (_Float16)0.f;
    *(half8*)&X4[(size_t)idx * 8] = o;
}

// ---------------------------------------------------------------------------
// Weight transforms to channel-blocked fp16 layouts.
// ---------------------------------------------------------------------------
__global__ __launch_bounds__(256) void wt_transform_kernel(
    const float* __restrict__ w1, const float* __restrict__ w2,
    const float* __restrict__ w3, const float* __restrict__ w4,
    _Float16* __restrict__ t1, _Float16* __restrict__ t2,
    _Float16* __restrict__ t3, _Float16* __restrict__ t4)
{
    int idx = blockIdx.x * 256 + threadIdx.x;
    if (idx < 9216) {               // conv2: K=288, 1 group
        int j = idx & 7, co = (idx >> 3) & 31, k8 = idx >> 8;
        int k = k8 * 8 + j, tap = k >> 5, ci = k & 31;
        t2[idx] = (_Float16)w2[(size_t)(co * 32 + ci) * 9 + tap];
    } else if (idx < 27648) {       // conv3: K=288, 2 cout groups
        int e = idx - 9216;
        int j = e & 7, co = (e >> 3) & 31, r = e >> 8;
        int k8 = r % 36, gg = r / 36;
        int k = k8 * 8 + j, tap = k >> 5, ci = k & 31;
        t3[e] = (_Float16)w3[(size_t)((gg * 32 + co) * 32 + ci) * 9 + tap];
    } else if (idx < 64512) {       // conv4: 2 cout groups x 2 ci-chunks
        int e = idx - 27648;
        int j = e & 7, co = (e >> 3) & 31, r = e >> 8;   // r 0..143
        int k8 = r % 36, gc = r / 36;                    // gc = g*2+cc
        int g = gc >> 1, cc = gc & 1;
        int kl = k8 * 8 + j, tap = kl >> 5, ci = cc * 32 + (kl & 31);
        t4[e] = (_Float16)w4[(size_t)((g * 32 + co) * 64 + ci) * 9 + tap];
    } else if (idx < 66560) {       // conv1: K=64 padded
        int e = idx - 64512;
        int j = e & 7, co = (e >> 3) & 31, k8 = e >> 8;  // 0..7
        int k = k8 * 8 + j, tap = k >> 2, ci = k & 3;
        t1[e] = (_Float16)((tap < 9 && ci < 3) ? w1[(size_t)(co * 3 + ci) * 9 + tap] : 0.f);
    }
}

// ---------------------------------------------------------------------------
// fc1 weight transform: f1w [128][16384] fp32 NCHW-k -> w1t fp16 NHWC-k.
// ---------------------------------------------------------------------------
__global__ __launch_bounds__(256) void fc1w_transform_kernel(
    const float* __restrict__ w, _Float16* __restrict__ wt)
{
    __shared__ float lds[64][65];
    const int t = threadIdx.x;
    const int yx0 = blockIdx.x * 64;
    const int j = blockIdx.y;
    #pragma unroll
    for (int i = 0; i < 16; ++i) {
        int idx = t + 256 * i;
        int c = idx >> 6, yxl = idx & 63;
        lds[c][yxl] = w[(size_t)j * 16384 + c * 256 + yx0 + yxl];
    }
    __syncthreads();
    #pragma unroll
    for (int i = 0; i < 2; ++i) {
        int idx = t + 256 * i;
        int yxl = idx >> 3, c8 = idx & 7;
        half8 h;
        #pragma unroll
        for (int jj = 0; jj < 8; ++jj)
            h[jj] = (_Float16)lds[c8 * 8 + jj][yxl];
        *(half8*)&wt[(size_t)j * 16384 + (size_t)(yx0 + yxl) * 64 + c8 * 8] = h;
    }
}

// ---------------------------------------------------------------------------
// quantum_prep: 60 Rot matrices + 6x1024 u16 perm table (depends only on qw).
// ---------------------------------------------------------------------------
__global__ __launch_bounds__(256) void quantum_prep_kernel(
    const float* __restrict__ qw, float* __restrict__ rotm,
    unsigned short* __restrict__ perm)
{
    int t = threadIdx.x;
    if (t < 60) {
        float phi = qw[t * 3], th = qw[t * 3 + 1], om = qw[t * 3 + 2];
        float c = cosf(0.5f * th), s = sinf(0.5f * th);
        float apo = 0.5f * (phi + om), amo = 0.5f * (phi - om);
        float cpo = cosf(apo), spo = sinf(apo);
        float cmo = cosf(amo), smo = sinf(amo);
        rotm[t * 8 + 0] = cpo * c;  rotm[t * 8 + 1] = -spo * c;
        rotm[t * 8 + 2] = -cmo * s; rotm[t * 8 + 3] = -smo * s;
        rotm[t * 8 + 4] = cmo * s;  rotm[t * 8 + 5] = -smo * s;
        rotm[t * 8 + 6] = cpo * c;  rotm[t * 8 + 7] = spo * c;
    }
    for (int e = t; e < 6144; e += 256) {
        int layer = e >> 10, i = e & 1023;
        int r = layer % 9 + 1;
        int jdx = i;
        for (int w = 9; w >= 0; --w) {
            int tt = (w + r) % 10;
            int pc = 9 - w, pt_ = 9 - tt;
            jdx ^= ((jdx >> pc) & 1) << pt_;
        }
        perm[e] = (unsigned short)jdx;
    }
}

// ---------------------------------------------------------------------------
// conv1 via MFMA: X4 NHWC4 fp16 -> out (256,64,64,32) fp16 + stats.
// ---------------------------------------------------------------------------
__global__ __launch_bounds__(256) void conv1_mfma_kernel(
    const _Float16* __restrict__ X4, const _Float16* __restrict__ w1m,
    const float* __restrict__ bias, _Float16* __restrict__ out,
    float* __restrict__ partials)
{
    constexpr int TC = 66, TR = 6;
    constexpr int NPIX = (TR + 1) * TC;     // 462
    __shared__ __align__(16) _Float16 s_in[NPIX * 4];
    __shared__ __align__(16) _Float16 s_w[2048];
    __shared__ float s_red[64];

    const int t = threadIdx.x;
    const int row0 = blockIdx.x * 4;
    const int n = blockIdx.z;

    *(half8*)&s_w[t * 8] = *(const half8*)&w1m[t * 8];

    for (int p = t; p < NPIX; p += 256) {
        int col = p % TC, r = p / TC;
        int gy = row0 + r - 1, gx = col - 1;
        uint2 u = make_uint2(0u, 0u);
        if (r < TR && gy >= 0 && gy < 64 && gx >= 0 && gx < 64)
            u = *(const uint2*)&X4[(((size_t)n << 12) + (gy << 6) + gx) * 4];
        *(uint2*)&s_in[p * 4] = u;
    }
    if (t < 64) s_red[t] = 0.f;
    __syncthreads();

    const int w = t >> 6, l = t & 63;
    const int lm = l & 15, lg = l >> 4;
    int pA[4];
    #pragma unroll
    for (int f = 0; f < 4; ++f) {
        int m = w * 64 + f * 16 + lm;
        pA[f] = (m >> 6) * TC + (m & 63);
    }
    f32x4 zero4 = {0.f, 0.f, 0.f, 0.f};
    f32x4 acc[4][2];
    #pragma unroll
    for (int f = 0; f < 4; ++f) { acc[f][0] = zero4; acc[f][1] = zero4; }

    {
        const int t0 = lg * 2;
        const int off0 = (t0 / 3) * TC + (t0 % 3);
        const int off1 = ((t0 + 1) / 3) * TC + ((t0 + 1) % 3);
        half8 b0 = *(const half8*)&s_w[(lg * 32 + lm) * 8];
        half8 b1 = *(const half8*)&s_w[(lg * 32 + 16 + lm) * 8];
        #pragma unroll
        for (int f = 0; f < 4; ++f) {
            half4 alo = *(const half4*)&s_in[(pA[f] + off0) * 4];
            half4 ahi = *(const half4*)&s_in[(pA[f] + off1) * 4];
            half8 a;
            #pragma unroll
            for (int j = 0; j < 4; ++j) { a[j] = alo[j]; a[4 + j] = ahi[j]; }
            acc[f][0] = __builtin_amdgcn_mfma_f32_16x16x32_f16(a, b0, acc[f][0], 0, 0, 0);
            acc[f][1] = __builtin_amdgcn_mfma_f32_16x16x32_f16(a, b1, acc[f][1], 0, 0, 0);
        }
    }
    {
        half8 b0 = *(const half8*)&s_w[((4 + lg) * 32 + lm) * 8];
        half8 b1 = *(const half8*)&s_w[((4 + lg) * 32 + 16 + lm) * 8];
        #pragma unroll
        for (int f = 0; f < 4; ++f) {
            half8 a;
            #pragma unroll
            for (int j = 0; j < 8; ++j) a[j] = (_Float16)0.f;
            if (lg == 0) {
                half4 alo = *(const half4*)&s_in[(pA[f] + 134) * 4];
                half4 ahi = *(const half4*)&s_in[(pA[f] + 198) * 4];
                #pragma unroll
                for (int j = 0; j < 4; ++j) { a[j] = alo[j]; a[4 + j] = ahi[j]; }
            }
            acc[f][0] = __builtin_amdgcn_mfma_f32_16x16x32_f16(a, b0, acc[f][0], 0, 0, 0);
            acc[f][1] = __builtin_amdgcn_mfma_f32_16x16x32_f16(a, b1, acc[f][1], 0, 0, 0);
        }
    }

    float bv0 = bias[lm];
    float bv1 = bias[16 + lm];
    float s0 = 0.f, s20 = 0.f, s1 = 0.f, s21 = 0.f;
    #pragma unroll
    for (int f = 0; f < 4; ++f) {
        #pragma unroll
        for (int r = 0; r < 4; ++r) {
            int m = w * 64 + f * 16 + lg * 4 + r;
            int yy = row0 + (m >> 6), xo = m & 63;
            size_t base = (((size_t)n * 64 + yy) * 64 + xo) * 32;
            float v0 = acc[f][0][r] + bv0;
            float v1 = acc[f][1][r] + bv1;
            out[base + lm] = (_Float16)v0;
            out[base + 16 + lm] = (_Float16)v1;
            s0 += v0; s20 += v0 * v0;
            s1 += v1; s21 += v1 * v1;
        }
    }
    s0 += __shfl_xor(s0, 16);  s0 += __shfl_xor(s0, 32);
    s1 += __shfl_xor(s1, 16);  s1 += __shfl_xor(s1, 32);
    s20 += __shfl_xor(s20, 16); s20 += __shfl_xor(s20, 32);
    s21 += __shfl_xor(s21, 16); s21 += __shfl_xor(s21, 32);
    if (l < 16) {
        atomicAdd(&s_red[lm], s0);
        atomicAdd(&s_red[16 + lm], s1);
        atomicAdd(&s_red[32 + lm], s20);
        atomicAdd(&s_red[48 + lm], s21);
    }
    __syncthreads();
    if (t < 64)
        partials[((size_t)n * 16 + blockIdx.x) * 64 + t] = s_red[t];
}

// ---------------------------------------------------------------------------
// Implicit-GEMM 3x3 conv via MFMA. Per wave: MF*16 spatial x NB*16 cout
// (NB*16 == COUT, gridDim.y == 1). Weights read from global (pre-arranged,
// L1/L2-hot); LDS holds only the input tile (channel-blocked).
// MMIN: input is pooled pre-BN (min,max) pair; stage relu(max*sA+min*sB+sh).
// POOL: write 2x2-pooled pre-BN (min,max) pair, fully in-lane.
// Emits per-block [sum COUT | sumsq COUT] of full-res conv+bias output.
// ---------------------------------------------------------------------------
template<int BLOCK, int W, int CIN, int COUT, int NCH, int MF, int NB,
         bool MMIN, bool POOL>
__global__ __launch_bounds__(BLOCK, (BLOCK == 512 ? 4 : 3)) void conv_mfma_kernel(
    const _Float16* __restrict__ in0, const _Float16* __restrict__ in1,
    const _Float16* __restrict__ coef, const _Float16* __restrict__ wt,
    const float* __restrict__ bias,
    _Float16* __restrict__ out0, _Float16* __restrict__ out1,
    float* __restrict__ partials)
{
    constexpr int H = W;
    constexpr int NWAVE = BLOCK / 64;
    constexpr int SPW = MF * 16;            // spatial per wave
    constexpr int ROWS = NWAVE * SPW / W;
    constexpr int TR = ROWS + 2;
    constexpr int TC = W + 2;
    constexpr int NPIX = TR * TC;
    constexpr int CCI = 32;
    constexpr int KC = 9 * CCI;             // 288
    constexpr int COUTB = NB * 16;          // == COUT
    __shared__ __align__(16) _Float16 s_in[NPIX * CCI];
    __shared__ float s_red[2 * COUTB];

    const int t = threadIdx.x;
    const int row0 = blockIdx.x * ROWS;
    const int n = blockIdx.z;

    const int w = t >> 6, l = t & 63;
    const int lm = l & 15, lg = l >> 4;
    int pA[MF];
    #pragma unroll
    for (int f = 0; f < MF; ++f) {
        int m = w * SPW + f * 16 + lm;
        pA[f] = (m / W) * TC + (m % W);
    }
    f32x4 zero4 = {0.f, 0.f, 0.f, 0.f};
    f32x4 acc[MF][NB];
    #pragma unroll
    for (int f = 0; f < MF; ++f)
        #pragma unroll
        for (int nb = 0; nb < NB; ++nb) acc[f][nb] = zero4;
    if (t < 2 * COUTB) s_red[t] = 0.f;

    #pragma unroll
    for (int cc = 0; cc < NCH; ++cc) {
        __syncthreads();
        // ---- stage input chunk ----
        for (int idx = t; idx < NPIX * 4; idx += BLOCK) {
            int c8 = idx & 3;
            int p = idx >> 2;
            int col = p % TC, r = p / TC;
            int gy = row0 + r - 1, gx = col - 1;
            half8 v;
            #pragma unroll
            for (int j = 0; j < 8; ++j) v[j] = (_Float16)0.f;
            if (gy >= 0 && gy < H && gx >= 0 && gx < W) {
                size_t gidx = (((size_t)n * H + gy) * W + gx) * CIN + cc * CCI + c8 * 8;
                if (MMIN) {
                    half8 mn = *(const half8*)&in0[gidx];
                    half8 mx = *(const half8*)&in1[gidx];
                    half8 sa = *(const half8*)&coef[cc * CCI + c8 * 8];
                    half8 sb = *(const half8*)&coef[CIN + cc * CCI + c8 * 8];
                    half8 sh = *(const half8*)&coef[2 * CIN + cc * CCI + c8 * 8];
                    #pragma unroll
                    for (int j = 0; j < 8; ++j) {
                        _Float16 f = mx[j] * sa[j] + mn[j] * sb[j] + sh[j];
                        v[j] = f > (_Float16)0.f ? f : (_Float16)0.f;
                    }
                } else {
                    v = *(const half8*)&in0[gidx];
                    if (coef) {
                        half8 sc = *(const half8*)&coef[cc * CCI + c8 * 8];
                        half8 sh = *(const half8*)&coef[CIN + cc * CCI + c8 * 8];
                        #pragma unroll
                        for (int j = 0; j < 8; ++j) {
                            _Float16 f = v[j] * sc[j] + sh[j];
                            v[j] = f > (_Float16)0.f ? f : (_Float16)0.f;
                        }
                    }
                }
            }
            *(half8*)&s_in[(c8 * NPIX + p) * 8] = v;
        }
        __syncthreads();
        // ---- compute chunk: 9 K-steps, NB B-loads + MF A-reads -> MF*NB MFMA
        #pragma unroll
        for (int tap = 0; tap < 9; ++tap) {
            const int dy = tap / 3, dx = tap % 3;
            const int poff = dy * TC + dx;
            half8 b[NB];
            #pragma unroll
            for (int nb = 0; nb < NB; ++nb) {
                int cog = nb * 16 + lm;
                int gg = cog >> 5, col = cog & 31;
                const _Float16* wp = wt + (size_t)(gg * NCH + cc) * KC * 32;
                b[nb] = *(const half8*)&wp[((tap * 4 + lg) * 32 + col) * 8];
            }
            #pragma unroll
            for (int f = 0; f < MF; ++f) {
                half8 a = *(const half8*)&s_in[(lg * NPIX + pA[f] + poff) * 8];
                #pragma unroll
                for (int nb = 0; nb < NB; ++nb)
                    acc[f][nb] = __builtin_amdgcn_mfma_f32_16x16x32_f16(a, b[nb], acc[f][nb], 0, 0, 0);
            }
        }
    }

    // ---- stats over full-res conv+bias output (+ full-res store if !POOL) --
    float bv[NB], s[NB], s2[NB];
    #pragma unroll
    for (int nb = 0; nb < NB; ++nb) {
        bv[nb] = bias[nb * 16 + lm];
        s[nb] = 0.f; s2[nb] = 0.f;
    }
    #pragma unroll
    for (int f = 0; f < MF; ++f) {
        #pragma unroll
        for (int r = 0; r < 4; ++r) {
            int m = w * SPW + f * 16 + lg * 4 + r;
            int yy = row0 + m / W, xo = m % W;
            size_t base = (((size_t)n * H + yy) * W + xo) * COUT;
            #pragma unroll
            for (int nb = 0; nb < NB; ++nb) {
                float v = acc[f][nb][r] + bv[nb];
                if (!POOL) out0[base + nb * 16 + lm] = (_Float16)v;
                s[nb] += v; s2[nb] += v * v;
            }
        }
    }
    #pragma unroll
    for (int nb = 0; nb < NB; ++nb) {
        s[nb] += __shfl_xor(s[nb], 16);  s[nb] += __shfl_xor(s[nb], 32);
        s2[nb] += __shfl_xor(s2[nb], 16); s2[nb] += __shfl_xor(s2[nb], 32);
    }
    if (l < 16) {
        #pragma unroll
        for (int nb = 0; nb < NB; ++nb) {
            atomicAdd(&s_red[nb * 16 + lm], s[nb]);
            atomicAdd(&s_red[COUTB + nb * 16 + lm], s2[nb]);
        }
    }

    if (POOL) {
        // fully in-lane 2x2 pool: horizontal (2rp,2rp+1) in r, vertical f<->f+FH
        constexpr int FH = MF / 2;
        const int yp = (row0 >> 1) + w;
        #pragma unroll
        for (int nb = 0; nb < NB; ++nb) {
            #pragma unroll
            for (int f = 0; f < FH; ++f) {
                #pragma unroll
                for (int rp = 0; rp < 2; ++rp) {
                    float a0 = acc[f][nb][2 * rp] + bv[nb];
                    float a1 = acc[f][nb][2 * rp + 1] + bv[nb];
                    float a2 = acc[f + FH][nb][2 * rp] + bv[nb];
                    float a3 = acc[f + FH][nb][2 * rp + 1] + bv[nb];
                    float mn = fminf(fminf(a0, a1), fminf(a2, a3));
                    float mx = fmaxf(fmaxf(a0, a1), fmaxf(a2, a3));
                    int xp = f * 8 + lg * 2 + rp;
                    size_t ob = (((size_t)n * (W / 2) + yp) * (W / 2) + xp) * COUT
                                + nb * 16 + lm;
                    out0[ob] = (_Float16)mn;
                    out1[ob] = (_Float16)mx;
                }
            }
        }
    }

    __syncthreads();
    if (t < 2 * COUTB) {
        size_t bid = (size_t)n * gridDim.x + blockIdx.x;
        partials[bid * 2 * COUTB + t] = s_red[t];
    }
}

// ---------------------------------------------------------------------------
// Reduce per-block partials -> BN coefficients. Record = [sum C | sumsq C].
// ss (fp32 pair), ssh (fp16 pair), sab (fp16 triple sA,sB,sh for minmax).
// ---------------------------------------------------------------------------
__global__ __launch_bounds__(256) void bn_finalize_kernel(
    const float* __restrict__ partials, int nx, float inv_count,
    const float* __restrict__ gamma, const float* __restrict__ beta,
    float* __restrict__ ss, _Float16* __restrict__ ssh,
    _Float16* __restrict__ sab, int COUT)
{
    const int c = blockIdx.x;
    const int t = threadIdx.x;
    float sum = 0.f, sq = 0.f;
    int total = 256 * nx;
    for (int e = t; e < total; e += 256) {
        size_t off = (size_t)e * 2 * COUT;
        sum += partials[off + c];
        sq  += partials[off + COUT + c];
    }
    #pragma unroll
    for (int off = 32; off > 0; off >>= 1) {
        sum += __shfl_xor(sum, off);
        sq  += __shfl_xor(sq, off);
    }
    __shared__ float rs[4], rq[4];
    if ((t & 63) == 0) { rs[t >> 6] = sum; rq[t >> 6] = sq; }
    __syncthreads();
    if (t == 0) {
        sum = rs[0] + rs[1] + rs[2] + rs[3];
        sq  = rq[0] + rq[1] + rq[2] + rq[3];
        float mean = sum * inv_count;
        float var = sq * inv_count - mean * mean;
        float scale = gamma[c] * rsqrtf(var + 1e-5f);
        float shift = beta[c] - mean * scale;
        ss[c] = scale;
        ss[COUT + c] = shift;
        if (ssh) {
            ssh[c] = (_Float16)scale;
            ssh[COUT + c] = (_Float16)shift;
        }
        if (sab) {
            sab[c] = (_Float16)(scale > 0.f ? scale : 0.f);
            sab[COUT + c] = (_Float16)(scale > 0.f ? 0.f : scale);
            sab[2 * COUT + c] = (_Float16)shift;
        }
    }
}

// ---------------------------------------------------------------------------
// fc1 MFMA GEMM (K-split): A = relu(bn4(pooled minmax pair)) on the fly.
// ---------------------------------------------------------------------------
__global__ __launch_bounds__(256) void fc1_mfma_kernel(
    const _Float16* __restrict__ Amin, const _Float16* __restrict__ Amax,
    const _Float16* __restrict__ sab, const _Float16* __restrict__ Bw,
    float* __restrict__ hp)
{
    __shared__ __align__(16) _Float16 As[64][72];
    __shared__ __align__(16) _Float16 Bs[128][72];
    const int t = threadIdx.x;
    const int mt = blockIdx.x;
    const int kc = blockIdx.y;
    const int w = t >> 6, l = t & 63;
    const int lm = l & 15, lg = l >> 4;

    f32x4 zero4 = {0.f, 0.f, 0.f, 0.f};
    f32x4 acc[8];
    #pragma unroll
    for (int nb = 0; nb < 8; ++nb) acc[nb] = zero4;

    const size_t a_base = (size_t)(mt * 64) * 16384 + (size_t)kc * 512;
    const size_t b_base = (size_t)kc * 512;

    for (int p = 0; p < 8; ++p) {
        __syncthreads();
        #pragma unroll
        for (int i = 0; i < 2; ++i) {
            int idx = t + 256 * i;
            int r = idx >> 3, c8 = idx & 7;
            size_t off = a_base + (size_t)r * 16384 + p * 64 + c8 * 8;
            half8 mn = *(const half8*)&Amin[off];
            half8 mx = *(const half8*)&Amax[off];
            half8 sa = *(const half8*)&sab[c8 * 8];
            half8 sb = *(const half8*)&sab[64 + c8 * 8];
            half8 sh = *(const half8*)&sab[128 + c8 * 8];
            half8 v;
            #pragma unroll
            for (int j = 0; j < 8; ++j) {
                _Float16 f = mx[j] * sa[j] + mn[j] * sb[j] + sh[j];
                v[j] = f > (_Float16)0.f ? f : (_Float16)0.f;
            }
            *(half8*)&As[r][c8 * 8] = v;
        }
        #pragma unroll
        for (int i = 0; i < 4; ++i) {
            int idx = t + 256 * i;
            int r = idx >> 3, c8 = idx & 7;
            *(half8*)&Bs[r][c8 * 8] =
                *(const half8*)&Bw[b_base + (size_t)r * 16384 + p * 64 + c8 * 8];
        }
        __syncthreads();
        #pragma unroll
        for (int ks = 0; ks < 64; ks += 32) {
            half8 a = *(const half8*)&As[w * 16 + lm][ks + lg * 8];
            #pragma unroll
            for (int nb = 0; nb < 8; ++nb) {
                half8 b = *(const half8*)&Bs[nb * 16 + lm][ks + lg * 8];
                acc[nb] = __builtin_amdgcn_mfma_f32_16x16x32_f16(a, b, acc[nb], 0, 0, 0);
            }
        }
    }
    #pragma unroll
    for (int nb = 0; nb < 8; ++nb) {
        #pragma unroll
        for (int r = 0; r < 4; ++r) {
            int row = mt * 64 + w * 16 + lg * 4 + r;
            hp[((size_t)kc * 256 + row) * 128 + nb * 16 + lm] = acc[nb][r];
        }
    }
}

__global__ __launch_bounds__(256) void fc1_reduce_kernel(
    const float* __restrict__ hp, const float* __restrict__ bias, float* __restrict__ h1)
{
    int gid = blockIdx.x * 256 + threadIdx.x;   // 32768
    int n = gid >> 7, j = gid & 127;
    float s = bias[j];
    #pragma unroll
    for (int kc = 0; kc < 32; ++kc) s += hp[((size_t)kc * 256 + n) * 128 + j];
    h1[gid] = fmaxf(0.f, s);
}

// ---------------------------------------------------------------------------
// fc2: (256,128) x (10,128)^T + b -> xq (256,10). One wave per batch element.
// ---------------------------------------------------------------------------
__global__ __launch_bounds__(64) void fc2_kernel(
    const float* __restrict__ h1, const float* __restrict__ w,
    const float* __restrict__ b, float* __restrict__ xq)
{
    int n = blockIdx.x, l = threadIdx.x;
    float a0 = h1[n * 128 + l], a1 = h1[n * 128 + 64 + l];
    float p[10];
    #pragma unroll
    for (int j = 0; j < 10; ++j)
        p[j] = w[j * 128 + l] * a0 + w[j * 128 + 64 + l] * a1;
    #pragma unroll
    for (int j = 0; j < 10; ++j) {
        #pragma unroll
        for (int off = 32; off > 0; off >>= 1) p[j] += __shfl_xor(p[j], off);
    }
    if (l == 0) {
        #pragma unroll
        for (int j = 0; j < 10; ++j) xq[n * 10 + j] = p[j] + b[j];
    }
}

// ---------------------------------------------------------------------------
// Quantum circuit + Z-exp + head: ONE WAVE per batch element (reg-resident).
// ---------------------------------------------------------------------------
__global__ __launch_bounds__(64) void quantum_head_kernel(
    const float* __restrict__ xq, const float* __restrict__ rotm,
    const unsigned short* __restrict__ perm,
    const float* __restrict__ head_w, const float* __restrict__ head_b,
    float* __restrict__ outp)
{
    __shared__ float lds[2048];
    const int n = blockIdx.x;
    const int l = threadIdx.x;

    float ar[16], ai[16];
    #pragma unroll
    for (int r = 0; r < 16; ++r) { ar[r] = 0.f; ai[r] = 0.f; }
    if (l == 0) ar[0] = 1.f;

    #pragma unroll
    for (int w = 0; w < 10; ++w) {
        float th = 0.5f * PI_F * xq[n * 10 + w];
        float c = cosf(th), s = sinf(th);
        const int k = 9 - w;
        if (k >= 6) {
            const int b = k - 6;
            #pragma unroll
            for (int r = 0; r < 16; ++r) {
                if (!(r & (1 << b))) {
                    int r1 = r | (1 << b);
                    float a0 = ar[r], a1 = ar[r1];
                    ar[r]  = c * a0 - s * a1;
                    ar[r1] = s * a0 + c * a1;
                }
            }
        } else {
            float ss = ((l >> k) & 1) ? s : -s;
            #pragma unroll
            for (int r = 0; r < 16; ++r) {
                float p = __shfl_xor(ar[r], 1 << k);
                ar[r] = c * ar[r] + ss * p;
            }
        }
    }

    #pragma unroll 1
    for (int layer = 0; layer < 6; ++layer) {
        #pragma unroll
        for (int w = 0; w < 10; ++w) {
            const float* m = rotm + (layer * 10 + w) * 8;
            float m00r = m[0], m00i = m[1], m01r = m[2], m01i = m[3];
            float m10r = m[4], m10i = m[5], m11r = m[6], m11i = m[7];
            const int k = 9 - w;
            if (k >= 6) {
                const int b = k - 6;
                #pragma unroll
                for (int r = 0; r < 16; ++r) {
                    if (!(r & (1 << b))) {
                        int r1 = r | (1 << b);
                        float a0r = ar[r], a0i = ai[r];
                        float a1r = ar[r1], a1i = ai[r1];
                        ar[r]  = m00r * a0r - m00i * a0i + m01r * a1r - m01i * a1i;
                        ai[r]  = m00r * a0i + m00i * a0r + m01r * a1i + m01i * a1r;
                        ar[r1] = m10r * a0r - m10i * a0i + m11r * a1r - m11i * a1i;
                        ai[r1] = m10r * a0i + m10i * a0r + m11r * a1i + m11i * a1r;
                    }
                }
            } else {
                int bit = (l >> k) & 1;
                float mAr = bit ? m11r : m00r, mAi = bit ? m11i : m00i;
                float mBr = bit ? m10r : m01r, mBi = bit ? m10i : m01i;
                #pragma unroll
                for (int r = 0; r < 16; ++r) {
                    float pr = __shfl_xor(ar[r], 1 << k);
                    float pi = __shfl_xor(ai[r], 1 << k);
                    float mr = ar[r], mi = ai[r];
                    ar[r] = mAr * mr - mAi * mi + mBr * pr - mBi * pi;
                    ai[r] = mAr * mi + mAi * mr + mBr * pi + mBi * pr;
                }
            }
        }
        #pragma unroll
        for (int r = 0; r < 16; ++r) {
            lds[(r << 6) | l] = ar[r];
            lds[1024 + ((r << 6) | l)] = ai[r];
        }
        __syncthreads();
        const unsigned short* pt = perm + layer * 1024;
        #pragma unroll
        for (int r = 0; r < 16; ++r) {
            int ji = pt[(r << 6) | l];
            ar[r] = lds[ji];
            ai[r] = lds[1024 + ji];
        }
        __syncthreads();
    }

    float S = 0.f, T0 = 0.f, T1 = 0.f, T2 = 0.f, T3 = 0.f;
    #pragma unroll
    for (int r = 0; r < 16; ++r) {
        float pr = ar[r] * ar[r] + ai[r] * ai[r];
        S += pr;
        T0 += (r & 1) ? -pr : pr;
        T1 += (r & 2) ? -pr : pr;
        T2 += (r & 4) ? -pr : pr;
        T3 += (r & 8) ? -pr : pr;
    }
    float pk[10];
    pk[0] = T3; pk[1] = T2; pk[2] = T1; pk[3] = T0;
    #pragma unroll
    for (int w = 4; w < 10; ++w)
        pk[w] = ((l >> (9 - w)) & 1) ? -S : S;
    #pragma unroll
    for (int w = 0; w < 10; ++w) {
        #pragma unroll
        for (int off = 1; off < 64; off <<= 1)
            pk[w] += __shfl_xor(pk[w], off);
    }
    if (l < 10) {
        float o = head_b[l];
        #pragma unroll
        for (int kk = 0; kk < 10; ++kk) o += pk[kk] * head_w[l * 10 + kk];
        outp[n * 10 + l] = o;
    }
}

// ---------------------------------------------------------------------------
extern "C" void kernel_launch(void* const* d_in, const int* in_sizes, int n_in,
                              void* d_out, int out_size, void* d_ws, size_t ws_size,
                              hipStream_t stream)
{
    const float* x   = (const float*)d_in[0];
    const float* c1w = (const float*)d_in[1];  const float* c1b = (const float*)d_in[2];
    const float* g1  = (const float*)d_in[3];  const float* b1  = (const float*)d_in[4];
    const float* c2w = (const float*)d_in[5];  const float* c2b = (const float*)d_in[6];
    const float* g2  = (const float*)d_in[7];  const float* b2  = (const float*)d_in[8];
    const float* c3w = (const float*)d_in[9];  const float* c3b = (const float*)d_in[10];
    const float* g3  = (const float*)d_in[11]; const float* b3  = (const float*)d_in[12];
    const float* c4w = (const float*)d_in[13]; const float* c4b = (const float*)d_in[14];
    const float* g4  = (const float*)d_in[15]; const float* b4  = (const float*)d_in[16];
    const float* f1w = (const float*)d_in[17]; const float* f1b = (const float*)d_in[18];
    const float* f2w = (const float*)d_in[19]; const float* f2b = (const float*)d_in[20];
    const float* qw  = (const float*)d_in[21];
    const float* hw  = (const float*)d_in[22]; const float* hb  = (const float*)d_in[23];

    float* ws = (float*)d_ws;
    _Float16* H0 = (_Float16*)ws;              // 33,554,432 halves (64 MB)
    _Float16* H1 = H0 + 33554432;              // 33,554,432 halves (64 MB)
    float* part = ws + 33554432;               // 524,288
    float* ss1  = part + 524288;               // 64
    float* ss2  = ss1 + 64;                    // 64
    float* ss3  = ss2 + 64;                    // 128
    float* ss4  = ss3 + 128;                   // 128
    float* hp   = ss4 + 128;                   // 1,048,576
    float* h1   = hp + 1048576;                // 32,768
    float* xqv  = h1 + 32768;                  // 2,560
    float* rotm = xqv + 2560;                  // 480
    unsigned short* perm16 = (unsigned short*)(rotm + 480);   // 6,144 u16
    _Float16* ssh1 = (_Float16*)(perm16 + 6144);   // 64 halves
    _Float16* ssh3 = ssh1 + 64;                // 128
    _Float16* sab2 = ssh3 + 128;               // 96
    _Float16* sab4 = sab2 + 96;                // 192
    _Float16* wt2  = sab4 + 192;               // 9,216
    _Float16* wt3  = wt2 + 9216;               // 18,432
    _Float16* wt4  = wt3 + 18432;              // 36,864
    _Float16* w1m  = wt4 + 36864;              // 2,048
    _Float16* w1t  = w1m + 2048;               // 2,097,152
    _Float16* X4   = w1t + 2097152;            // 4,194,304 (8 MB)

    // overlays on H1 (sequential lifetimes)
    _Float16* minT2 = H1;                      // (256,32,32,32)
    _Float16* maxT2 = H1 + 8388608;
    _Float16* minT4 = H1;                      // (256,16,16,64)
    _Float16* maxT4 = H1 + 4194304;

    // one-time precomputes
    quantum_prep_kernel<<<1, 256, 0, stream>>>(qw, rotm, perm16);
    wt_transform_kernel<<<260, 256, 0, stream>>>(c1w, c2w, c3w, c4w, w1m, wt2, wt3, wt4);
    fc1w_transform_kernel<<<dim3(4, 128), 256, 0, stream>>>(f1w, w1t);
    x_to_nhwc4_kernel<<<2048, 256, 0, stream>>>(x, X4);

    // conv1 (MFMA): X4 -> H0 (256,64,64,32) + stats
    conv1_mfma_kernel<<<dim3(16, 1, 256), 256, 0, stream>>>(X4, w1m, c1b, H0, part);
    bn_finalize_kernel<<<32, 256, 0, stream>>>(part, 16, 1.f / 1048576.f,
                                               g1, b1, ss1, ssh1, nullptr, 32);

    // conv2 (256thr, 128 spat/wave, fused in-lane pool): bn1+relu(H0) -> minT2/maxT2
    conv_mfma_kernel<256, 64, 32, 32, 1, 8, 2, false, true>
        <<<dim3(8, 1, 256), 256, 0, stream>>>(
        H0, nullptr, ssh1, wt2, c2b, minT2, maxT2, part);
    bn_finalize_kernel<<<32, 256, 0, stream>>>(part, 8, 1.f / 1048576.f,
                                               g2, b2, ss2, nullptr, sab2, 32);

    // conv3 (512thr, 64 cout/wave, minmax input): relu(bn2(pool1)) -> H0
    conv_mfma_kernel<512, 32, 32, 64, 1, 4, 4, true, false>
        <<<dim3(2, 1, 256), 512, 0, stream>>>(
        minT2, maxT2, sab2, wt3, c3b, H0, nullptr, part);
    bn_finalize_kernel<<<64, 256, 0, stream>>>(part, 2, 1.f / 262144.f,
                                               g3, b3, ss3, ssh3, nullptr, 64);

    // conv4 (512thr, 64 cout/wave, 2 ci-chunks, fused pool): bn3+relu(H0) -> minT4/maxT4
    conv_mfma_kernel<512, 32, 64, 64, 2, 4, 4, false, true>
        <<<dim3(2, 1, 256), 512, 0, stream>>>(
        H0, nullptr, ssh3, wt4, c4b, minT4, maxT4, part);
    bn_finalize_kernel<<<64, 256, 0, stream>>>(part, 2, 1.f / 262144.f,
                                               g4, b4, ss4, nullptr, sab4, 64);

    // fc1: MFMA GEMM with on-the-fly relu(bn4(pool2)) + reduce -> h1
    fc1_mfma_kernel<<<dim3(4, 32), 256, 0, stream>>>(minT4, maxT4, sab4, w1t, hp);
    fc1_reduce_kernel<<<128, 256, 0, stream>>>(hp, f1b, h1);

    // fc2 -> xq (256,10)
    fc2_kernel<<<256, 64, 0, stream>>>(h1, f2w, f2b, xqv);

    // quantum circuit + head -> out (256,10)
    quantum_head_kernel<<<256, 64, 0, stream>>>(xqv, rotm, perm16, hw, hb, (float*)d_out);
}

// Round 12
// 203.016 us; speedup vs baseline: 8.9068x; 1.0876x over previous
//
#include <hip/hip_runtime.h>
#include <math.h>

#define PI_F 3.14159265358979323846f

typedef __attribute__((ext_vector_type(8))) _Float16 half8;
typedef __attribute__((ext_vector_type(4))) _Float16 half4;
typedef __attribute__((ext_vector_type(4))) float f32x4;

// ---------------------------------------------------------------------------
// x (256,3,64,64) fp32 -> X4 (256,64,64,4) fp16, channel 3 zero-padded.
// ---------------------------------------------------------------------------
__global__ __launch_bounds__(256) void x_to_nhwc4_kernel(
    const float* __restrict__ x, _Float16* __restrict__ X4)
{
    int idx = blockIdx.x * 256 + threadIdx.x;      // 524,288
    int n = idx >> 11;
    int p = (idx & 2047) * 2;
    const float* xb = x + (size_t)n * 12288;
    float2 c0 = *(const float2*)&xb[p];
    float2 c1 = *(const float2*)&xb[4096 + p];
    float2 c2 = *(const float2*)&xb[8192 + p];
    half8 o;
    o[0] = (_Float16)c0.x; o[1] = (_Float16)c1.x; o[2] = (_Float16)c2.x; o[3] = (_Float16)0.f;
    o[4] = (_Float16)c0.y; o[5] = (_Float16)c1.y; o[6] = (_Float16)c2.y; o[7] = (_Float16)0.f;
    *(half8*)&X4[(size_t)idx * 8] = o;
}

// ---------------------------------------------------------------------------
// Weight transforms to channel-blocked fp16 layouts.
// ---------------------------------------------------------------------------
__global__ __launch_bounds__(256) void wt_transform_kernel(
    const float* __restrict__ w1, const float* __restrict__ w2,
    const float* __restrict__ w3, const float* __restrict__ w4,
    _Float16* __restrict__ t1, _Float16* __restrict__ t2,
    _Float16* __restrict__ t3, _Float16* __restrict__ t4)
{
    int idx = blockIdx.x * 256 + threadIdx.x;
    if (idx < 9216) {               // conv2: K=288, 1 group
        int j = idx & 7, co = (idx >> 3) & 31, k8 = idx >> 8;
        int k = k8 * 8 + j, tap = k >> 5, ci = k & 31;
        t2[idx] = (_Float16)w2[(size_t)(co * 32 + ci) * 9 + tap];
    } else if (idx < 27648) {       // conv3: K=288, 2 cout groups
        int e = idx - 9216;
        int j = e & 7, co = (e >> 3) & 31, r = e >> 8;
        int k8 = r % 36, gg = r / 36;
        int k = k8 * 8 + j, tap = k >> 5, ci = k & 31;
        t3[e] = (_Float16)w3[(size_t)((gg * 32 + co) * 32 + ci) * 9 + tap];
    } else if (idx < 64512) {       // conv4: 2 cout groups x 2 ci-chunks
        int e = idx - 27648;
        int j = e & 7, co = (e >> 3) & 31, r = e >> 8;   // r 0..143
        int k8 = r % 36, gc = r / 36;                    // gc = g*2+cc
        int g = gc >> 1, cc = gc & 1;
        int kl = k8 * 8 + j, tap = kl >> 5, ci = cc * 32 + (kl & 31);
        t4[e] = (_Float16)w4[(size_t)((g * 32 + co) * 64 + ci) * 9 + tap];
    } else if (idx < 66560) {       // conv1: K=64 padded
        int e = idx - 64512;
        int j = e & 7, co = (e >> 3) & 31, k8 = e >> 8;  // 0..7
        int k = k8 * 8 + j, tap = k >> 2, ci = k & 3;
        t1[e] = (_Float16)((tap < 9 && ci < 3) ? w1[(size_t)(co * 3 + ci) * 9 + tap] : 0.f);
    }
}

// ---------------------------------------------------------------------------
// fc1 weight transform: f1w [128][16384] fp32 NCHW-k -> w1t fp16 NHWC-k.
// ---------------------------------------------------------------------------
__global__ __launch_bounds__(256) void fc1w_transform_kernel(
    const float* __restrict__ w, _Float16* __restrict__ wt)
{
    __shared__ float lds[64][65];
    const int t = threadIdx.x;
    const int yx0 = blockIdx.x * 64;
    const int j = blockIdx.y;
    #pragma unroll
    for (int i = 0; i < 16; ++i) {
        int idx = t + 256 * i;
        int c = idx >> 6, yxl = idx & 63;
        lds[c][yxl] = w[(size_t)j * 16384 + c * 256 + yx0 + yxl];
    }
    __syncthreads();
    #pragma unroll
    for (int i = 0; i < 2; ++i) {
        int idx = t + 256 * i;
        int yxl = idx >> 3, c8 = idx & 7;
        half8 h;
        #pragma unroll
        for (int jj = 0; jj < 8; ++jj)
            h[jj] = (_Float16)lds[c8 * 8 + jj][yxl];
        *(half8*)&wt[(size_t)j * 16384 + (size_t)(yx0 + yxl) * 64 + c8 * 8] = h;
    }
}

// ---------------------------------------------------------------------------
// quantum_prep: 60 Rot matrices + 6x1024 u16 perm table (depends only on qw).
// ---------------------------------------------------------------------------
__global__ __launch_bounds__(256) void quantum_prep_kernel(
    const float* __restrict__ qw, float* __restrict__ rotm,
    unsigned short* __restrict__ perm)
{
    int t = threadIdx.x;
    if (t < 60) {
        float phi = qw[t * 3], th = qw[t * 3 + 1], om = qw[t * 3 + 2];
        float c = cosf(0.5f * th), s = sinf(0.5f * th);
        float apo = 0.5f * (phi + om), amo = 0.5f * (phi - om);
        float cpo = cosf(apo), spo = sinf(apo);
        float cmo = cosf(amo), smo = sinf(amo);
        rotm[t * 8 + 0] = cpo * c;  rotm[t * 8 + 1] = -spo * c;
        rotm[t * 8 + 2] = -cmo * s; rotm[t * 8 + 3] = -smo * s;
        rotm[t * 8 + 4] = cmo * s;  rotm[t * 8 + 5] = -smo * s;
        rotm[t * 8 + 6] = cpo * c;  rotm[t * 8 + 7] = spo * c;
    }
    for (int e = t; e < 6144; e += 256) {
        int layer = e >> 10, i = e & 1023;
        int r = layer % 9 + 1;
        int jdx = i;
        for (int w = 9; w >= 0; --w) {
            int tt = (w + r) % 10;
            int pc = 9 - w, pt_ = 9 - tt;
            jdx ^= ((jdx >> pc) & 1) << pt_;
        }
        perm[e] = (unsigned short)jdx;
    }
}

// ---------------------------------------------------------------------------
// conv1 via MFMA: X4 NHWC4 fp16 -> out (256,64,64,32) fp16 + stats.
// ---------------------------------------------------------------------------
__global__ __launch_bounds__(256) void conv1_mfma_kernel(
    const _Float16* __restrict__ X4, const _Float16* __restrict__ w1m,
    const float* __restrict__ bias, _Float16* __restrict__ out,
    float* __restrict__ partials)
{
    constexpr int TC = 66, TR = 6;
    constexpr int NPIX = (TR + 1) * TC;     // 462
    __shared__ __align__(16) _Float16 s_in[NPIX * 4];
    __shared__ __align__(16) _Float16 s_w[2048];
    __shared__ float s_red[64];

    const int t = threadIdx.x;
    const int row0 = blockIdx.x * 4;
    const int n = blockIdx.z;

    *(half8*)&s_w[t * 8] = *(const half8*)&w1m[t * 8];

    for (int p = t; p < NPIX; p += 256) {
        int col = p % TC, r = p / TC;
        int gy = row0 + r - 1, gx = col - 1;
        uint2 u = make_uint2(0u, 0u);
        if (r < TR && gy >= 0 && gy < 64 && gx >= 0 && gx < 64)
            u = *(const uint2*)&X4[(((size_t)n << 12) + (gy << 6) + gx) * 4];
        *(uint2*)&s_in[p * 4] = u;
    }
    if (t < 64) s_red[t] = 0.f;
    __syncthreads();

    const int w = t >> 6, l = t & 63;
    const int lm = l & 15, lg = l >> 4;
    int pA[4];
    #pragma unroll
    for (int f = 0; f < 4; ++f) {
        int m = w * 64 + f * 16 + lm;
        pA[f] = (m >> 6) * TC + (m & 63);
    }
    f32x4 zero4 = {0.f, 0.f, 0.f, 0.f};
    f32x4 acc[4][2];
    #pragma unroll
    for (int f = 0; f < 4; ++f) { acc[f][0] = zero4; acc[f][1] = zero4; }

    {
        const int t0 = lg * 2;
        const int off0 = (t0 / 3) * TC + (t0 % 3);
        const int off1 = ((t0 + 1) / 3) * TC + ((t0 + 1) % 3);
        half8 b0 = *(const half8*)&s_w[(lg * 32 + lm) * 8];
        half8 b1 = *(const half8*)&s_w[(lg * 32 + 16 + lm) * 8];
        #pragma unroll
        for (int f = 0; f < 4; ++f) {
            half4 alo = *(const half4*)&s_in[(pA[f] + off0) * 4];
            half4 ahi = *(const half4*)&s_in[(pA[f] + off1) * 4];
            half8 a;
            #pragma unroll
            for (int j = 0; j < 4; ++j) { a[j] = alo[j]; a[4 + j] = ahi[j]; }
            acc[f][0] = __builtin_amdgcn_mfma_f32_16x16x32_f16(a, b0, acc[f][0], 0, 0, 0);
            acc[f][1] = __builtin_amdgcn_mfma_f32_16x16x32_f16(a, b1, acc[f][1], 0, 0, 0);
        }
    }
    {
        half8 b0 = *(const half8*)&s_w[((4 + lg) * 32 + lm) * 8];
        half8 b1 = *(const half8*)&s_w[((4 + lg) * 32 + 16 + lm) * 8];
        #pragma unroll
        for (int f = 0; f < 4; ++f) {
            half8 a;
            #pragma unroll
            for (int j = 0; j < 8; ++j) a[j] = (_Float16)0.f;
            if (lg == 0) {
                half4 alo = *(const half4*)&s_in[(pA[f] + 134) * 4];
                half4 ahi = *(const half4*)&s_in[(pA[f] + 198) * 4];
                #pragma unroll
                for (int j = 0; j < 4; ++j) { a[j] = alo[j]; a[4 + j] = ahi[j]; }
            }
            acc[f][0] = __builtin_amdgcn_mfma_f32_16x16x32_f16(a, b0, acc[f][0], 0, 0, 0);
            acc[f][1] = __builtin_amdgcn_mfma_f32_16x16x32_f16(a, b1, acc[f][1], 0, 0, 0);
        }
    }

    float bv0 = bias[lm];
    float bv1 = bias[16 + lm];
    float s0 = 0.f, s20 = 0.f, s1 = 0.f, s21 = 0.f;
    #pragma unroll
    for (int f = 0; f < 4; ++f) {
        #pragma unroll
        for (int r = 0; r < 4; ++r) {
            int m = w * 64 + f * 16 + lg * 4 + r;
            int yy = row0 + (m >> 6), xo = m & 63;
            size_t base = (((size_t)n * 64 + yy) * 64 + xo) * 32;
            float v0 = acc[f][0][r] + bv0;
            float v1 = acc[f][1][r] + bv1;
            out[base + lm] = (_Float16)v0;
            out[base + 16 + lm] = (_Float16)v1;
            s0 += v0; s20 += v0 * v0;
            s1 += v1; s21 += v1 * v1;
        }
    }
    s0 += __shfl_xor(s0, 16);  s0 += __shfl_xor(s0, 32);
    s1 += __shfl_xor(s1, 16);  s1 += __shfl_xor(s1, 32);
    s20 += __shfl_xor(s20, 16); s20 += __shfl_xor(s20, 32);
    s21 += __shfl_xor(s21, 16); s21 += __shfl_xor(s21, 32);
    if (l < 16) {
        atomicAdd(&s_red[lm], s0);
        atomicAdd(&s_red[16 + lm], s1);
        atomicAdd(&s_red[32 + lm], s20);
        atomicAdd(&s_red[48 + lm], s21);
    }
    __syncthreads();
    if (t < 64)
        partials[((size_t)n * 16 + blockIdx.x) * 64 + t] = s_red[t];
}

// ---------------------------------------------------------------------------
// Implicit-GEMM 3x3 conv via MFMA. Per wave: MF*16 spatial x NB*16 cout
// (NB*16 == COUT, gridDim.y == 1). SINGLE-PASS staging: all CIN channels of
// the tile staged at once (each cache line read exactly once). Weights read
// from global (pre-arranged, L2-hot). K-loop = 9 taps x CIN/32 ci-halves.
// MMIN: input is pooled pre-BN (min,max) pair; stage relu(max*sA+min*sB+sh).
// POOL: 2x2 in-lane pool -> LDS pack (reuses s_in) -> coalesced half8 stores.
// Emits per-block [sum COUT | sumsq COUT] of full-res conv+bias output.
// ---------------------------------------------------------------------------
template<int BLOCK, int W, int CIN, int COUT, int MF, int NB,
         bool MMIN, bool POOL>
__global__ __launch_bounds__(BLOCK, (BLOCK == 512 ? 4 : 3)) void conv_mfma_kernel(
    const _Float16* __restrict__ in0, const _Float16* __restrict__ in1,
    const _Float16* __restrict__ coef, const _Float16* __restrict__ wt,
    const float* __restrict__ bias,
    _Float16* __restrict__ out0, _Float16* __restrict__ out1,
    float* __restrict__ partials)
{
    constexpr int H = W;
    constexpr int NWAVE = BLOCK / 64;
    constexpr int SPW = MF * 16;            // spatial per wave (2 rows)
    constexpr int ROWS = NWAVE * SPW / W;
    constexpr int TR = ROWS + 2;
    constexpr int TC = W + 2;
    constexpr int NPIX = TR * TC;
    constexpr int NCH = CIN / 32;           // ci-halves per K-step group
    constexpr int C8N = CIN / 8;
    constexpr int KC = 288;                 // 9*32, weight-chunk row count
    constexpr int COUTB = NB * 16;          // == COUT
    __shared__ __align__(16) _Float16 s_in[NPIX * CIN];
    __shared__ float s_red[2 * COUTB];

    const int t = threadIdx.x;
    const int row0 = blockIdx.x * ROWS;
    const int n = blockIdx.z;

    const int w = t >> 6, l = t & 63;
    const int lm = l & 15, lg = l >> 4;
    int pA[MF];
    #pragma unroll
    for (int f = 0; f < MF; ++f) {
        int m = w * SPW + f * 16 + lm;
        pA[f] = (m / W) * TC + (m % W);
    }
    f32x4 zero4 = {0.f, 0.f, 0.f, 0.f};
    f32x4 acc[MF][NB];
    #pragma unroll
    for (int f = 0; f < MF; ++f)
        #pragma unroll
        for (int nb = 0; nb < NB; ++nb) acc[f][nb] = zero4;
    if (t < 2 * COUTB) s_red[t] = 0.f;

    // ---- single-pass staging of the full tile ----
    for (int idx = t; idx < NPIX * C8N; idx += BLOCK) {
        int c8 = idx % C8N;
        int p = idx / C8N;
        int col = p % TC, r = p / TC;
        int gy = row0 + r - 1, gx = col - 1;
        half8 v;
        #pragma unroll
        for (int j = 0; j < 8; ++j) v[j] = (_Float16)0.f;
        if (gy >= 0 && gy < H && gx >= 0 && gx < W) {
            size_t gidx = (((size_t)n * H + gy) * W + gx) * CIN + c8 * 8;
            if (MMIN) {
                half8 mn = *(const half8*)&in0[gidx];
                half8 mx = *(const half8*)&in1[gidx];
                half8 sa = *(const half8*)&coef[c8 * 8];
                half8 sb = *(const half8*)&coef[CIN + c8 * 8];
                half8 sh = *(const half8*)&coef[2 * CIN + c8 * 8];
                #pragma unroll
                for (int j = 0; j < 8; ++j) {
                    _Float16 f = mx[j] * sa[j] + mn[j] * sb[j] + sh[j];
                    v[j] = f > (_Float16)0.f ? f : (_Float16)0.f;
                }
            } else {
                v = *(const half8*)&in0[gidx];
                if (coef) {
                    half8 sc = *(const half8*)&coef[c8 * 8];
                    half8 sh = *(const half8*)&coef[CIN + c8 * 8];
                    #pragma unroll
                    for (int j = 0; j < 8; ++j) {
                        _Float16 f = v[j] * sc[j] + sh[j];
                        v[j] = f > (_Float16)0.f ? f : (_Float16)0.f;
                    }
                }
            }
        }
        *(half8*)&s_in[(c8 * NPIX + p) * 8] = v;
    }
    __syncthreads();

    // ---- compute: 9 taps x NCH ci-halves; per step NB B-loads + MF A-reads
    #pragma unroll
    for (int tap = 0; tap < 9; ++tap) {
        const int dy = tap / 3, dx = tap % 3;
        const int poff = dy * TC + dx;
        #pragma unroll
        for (int cc = 0; cc < NCH; ++cc) {
            half8 b[NB];
            #pragma unroll
            for (int nb = 0; nb < NB; ++nb) {
                int cog = nb * 16 + lm;
                int gg = cog >> 5, col = cog & 31;
                const _Float16* wp = wt + (size_t)(gg * NCH + cc) * KC * 32;
                b[nb] = *(const half8*)&wp[((tap * 4 + lg) * 32 + col) * 8];
            }
            #pragma unroll
            for (int f = 0; f < MF; ++f) {
                half8 a = *(const half8*)&s_in[((cc * 4 + lg) * NPIX + pA[f] + poff) * 8];
                #pragma unroll
                for (int nb = 0; nb < NB; ++nb)
                    acc[f][nb] = __builtin_amdgcn_mfma_f32_16x16x32_f16(a, b[nb], acc[f][nb], 0, 0, 0);
            }
        }
    }

    // ---- stats over full-res conv+bias output (+ full-res store if !POOL) --
    float bv[NB], s[NB], s2[NB];
    #pragma unroll
    for (int nb = 0; nb < NB; ++nb) {
        bv[nb] = bias[nb * 16 + lm];
        s[nb] = 0.f; s2[nb] = 0.f;
    }
    #pragma unroll
    for (int f = 0; f < MF; ++f) {
        #pragma unroll
        for (int r = 0; r < 4; ++r) {
            int m = w * SPW + f * 16 + lg * 4 + r;
            int yy = row0 + m / W, xo = m % W;
            size_t base = (((size_t)n * H + yy) * W + xo) * COUT;
            #pragma unroll
            for (int nb = 0; nb < NB; ++nb) {
                float v = acc[f][nb][r] + bv[nb];
                if (!POOL) out0[base + nb * 16 + lm] = (_Float16)v;
                s[nb] += v; s2[nb] += v * v;
            }
        }
    }
    #pragma unroll
    for (int nb = 0; nb < NB; ++nb) {
        s[nb] += __shfl_xor(s[nb], 16);  s[nb] += __shfl_xor(s[nb], 32);
        s2[nb] += __shfl_xor(s2[nb], 16); s2[nb] += __shfl_xor(s2[nb], 32);
    }
    if (l < 16) {
        #pragma unroll
        for (int nb = 0; nb < NB; ++nb) {
            atomicAdd(&s_red[nb * 16 + lm], s[nb]);
            atomicAdd(&s_red[COUTB + nb * 16 + lm], s2[nb]);
        }
    }

    if (POOL) {
        // in-lane 2x2 pool -> LDS pack (reuse s_in) -> coalesced half8 stores
        constexpr int FH = MF / 2;
        constexpr int PPIX = (ROWS / 2) * (W / 2);
        static_assert(2 * PPIX * COUT <= NPIX * CIN, "pool pack fits in s_in");
        __syncthreads();                   // all MFMA reads of s_in done
        _Float16* pk = s_in;
        #pragma unroll
        for (int nb = 0; nb < NB; ++nb) {
            #pragma unroll
            for (int f = 0; f < FH; ++f) {
                #pragma unroll
                for (int rp = 0; rp < 2; ++rp) {
                    float a0 = acc[f][nb][2 * rp] + bv[nb];
                    float a1 = acc[f][nb][2 * rp + 1] + bv[nb];
                    float a2 = acc[f + FH][nb][2 * rp] + bv[nb];
                    float a3 = acc[f + FH][nb][2 * rp + 1] + bv[nb];
                    float mn = fminf(fminf(a0, a1), fminf(a2, a3));
                    float mx = fmaxf(fmaxf(a0, a1), fmaxf(a2, a3));
                    int xp = f * 8 + lg * 2 + rp;
                    int o = (w * (W / 2) + xp) * COUT + nb * 16 + lm;
                    pk[o] = (_Float16)mn;
                    pk[PPIX * COUT + o] = (_Float16)mx;
                }
            }
        }
        __syncthreads();
        size_t gb = (((size_t)n * (H / 2) + (row0 >> 1)) * (W / 2)) * COUT;
        for (int idx = t; idx < PPIX * COUT / 8; idx += BLOCK) {
            *(half8*)&out0[gb + (size_t)idx * 8] = *(const half8*)&pk[idx * 8];
            *(half8*)&out1[gb + (size_t)idx * 8] = *(const half8*)&pk[(PPIX * COUT + idx * 8)];
        }
    }

    __syncthreads();
    if (t < 2 * COUTB) {
        size_t bid = (size_t)n * gridDim.x + blockIdx.x;
        partials[bid * 2 * COUTB + t] = s_red[t];
    }
}

// ---------------------------------------------------------------------------
// Reduce per-block partials -> BN coefficients. Record = [sum C | sumsq C].
// ---------------------------------------------------------------------------
__global__ __launch_bounds__(256) void bn_finalize_kernel(
    const float* __restrict__ partials, int nx, float inv_count,
    const float* __restrict__ gamma, const float* __restrict__ beta,
    float* __restrict__ ss, _Float16* __restrict__ ssh,
    _Float16* __restrict__ sab, int COUT)
{
    const int c = blockIdx.x;
    const int t = threadIdx.x;
    float sum = 0.f, sq = 0.f;
    int total = 256 * nx;
    for (int e = t; e < total; e += 256) {
        size_t off = (size_t)e * 2 * COUT;
        sum += partials[off + c];
        sq  += partials[off + COUT + c];
    }
    #pragma unroll
    for (int off = 32; off > 0; off >>= 1) {
        sum += __shfl_xor(sum, off);
        sq  += __shfl_xor(sq, off);
    }
    __shared__ float rs[4], rq[4];
    if ((t & 63) == 0) { rs[t >> 6] = sum; rq[t >> 6] = sq; }
    __syncthreads();
    if (t == 0) {
        sum = rs[0] + rs[1] + rs[2] + rs[3];
        sq  = rq[0] + rq[1] + rq[2] + rq[3];
        float mean = sum * inv_count;
        float var = sq * inv_count - mean * mean;
        float scale = gamma[c] * rsqrtf(var + 1e-5f);
        float shift = beta[c] - mean * scale;
        ss[c] = scale;
        ss[COUT + c] = shift;
        if (ssh) {
            ssh[c] = (_Float16)scale;
            ssh[COUT + c] = (_Float16)shift;
        }
        if (sab) {
            sab[c] = (_Float16)(scale > 0.f ? scale : 0.f);
            sab[COUT + c] = (_Float16)(scale > 0.f ? 0.f : scale);
            sab[2 * COUT + c] = (_Float16)shift;
        }
    }
}

// ---------------------------------------------------------------------------
// fc1 MFMA GEMM (K-split): A = relu(bn4(pooled minmax pair)) on the fly.
// ---------------------------------------------------------------------------
__global__ __launch_bounds__(256) void fc1_mfma_kernel(
    const _Float16* __restrict__ Amin, const _Float16* __restrict__ Amax,
    const _Float16* __restrict__ sab, const _Float16* __restrict__ Bw,
    float* __restrict__ hp)
{
    __shared__ __align__(16) _Float16 As[64][72];
    __shared__ __align__(16) _Float16 Bs[128][72];
    const int t = threadIdx.x;
    const int mt = blockIdx.x;
    const int kc = blockIdx.y;
    const int w = t >> 6, l = t & 63;
    const int lm = l & 15, lg = l >> 4;

    f32x4 zero4 = {0.f, 0.f, 0.f, 0.f};
    f32x4 acc[8];
    #pragma unroll
    for (int nb = 0; nb < 8; ++nb) acc[nb] = zero4;

    const size_t a_base = (size_t)(mt * 64) * 16384 + (size_t)kc * 512;
    const size_t b_base = (size_t)kc * 512;

    for (int p = 0; p < 8; ++p) {
        __syncthreads();
        #pragma unroll
        for (int i = 0; i < 2; ++i) {
            int idx = t + 256 * i;
            int r = idx >> 3, c8 = idx & 7;
            size_t off = a_base + (size_t)r * 16384 + p * 64 + c8 * 8;
            half8 mn = *(const half8*)&Amin[off];
            half8 mx = *(const half8*)&Amax[off];
            half8 sa = *(const half8*)&sab[c8 * 8];
            half8 sb = *(const half8*)&sab[64 + c8 * 8];
            half8 sh = *(const half8*)&sab[128 + c8 * 8];
            half8 v;
            #pragma unroll
            for (int j = 0; j < 8; ++j) {
                _Float16 f = mx[j] * sa[j] + mn[j] * sb[j] + sh[j];
                v[j] = f > (_Float16)0.f ? f : (_Float16)0.f;
            }
            *(half8*)&As[r][c8 * 8] = v;
        }
        #pragma unroll
        for (int i = 0; i < 4; ++i) {
            int idx = t + 256 * i;
            int r = idx >> 3, c8 = idx & 7;
            *(half8*)&Bs[r][c8 * 8] =
                *(const half8*)&Bw[b_base + (size_t)r * 16384 + p * 64 + c8 * 8];
        }
        __syncthreads();
        #pragma unroll
        for (int ks = 0; ks < 64; ks += 32) {
            half8 a = *(const half8*)&As[w * 16 + lm][ks + lg * 8];
            #pragma unroll
            for (int nb = 0; nb < 8; ++nb) {
                half8 b = *(const half8*)&Bs[nb * 16 + lm][ks + lg * 8];
                acc[nb] = __builtin_amdgcn_mfma_f32_16x16x32_f16(a, b, acc[nb], 0, 0, 0);
            }
        }
    }
    #pragma unroll
    for (int nb = 0; nb < 8; ++nb) {
        #pragma unroll
        for (int r = 0; r < 4; ++r) {
            int row = mt * 64 + w * 16 + lg * 4 + r;
            hp[((size_t)kc * 256 + row) * 128 + nb * 16 + lm] = acc[nb][r];
        }
    }
}

__global__ __launch_bounds__(256) void fc1_reduce_kernel(
    const float* __restrict__ hp, const float* __restrict__ bias, float* __restrict__ h1)
{
    int gid = blockIdx.x * 256 + threadIdx.x;   // 32768
    int n = gid >> 7, j = gid & 127;
    float s = bias[j];
    #pragma unroll
    for (int kc = 0; kc < 32; ++kc) s += hp[((size_t)kc * 256 + n) * 128 + j];
    h1[gid] = fmaxf(0.f, s);
}

// ---------------------------------------------------------------------------
// fc2: (256,128) x (10,128)^T + b -> xq (256,10). One wave per batch element.
// ---------------------------------------------------------------------------
__global__ __launch_bounds__(64) void fc2_kernel(
    const float* __restrict__ h1, const float* __restrict__ w,
    const float* __restrict__ b, float* __restrict__ xq)
{
    int n = blockIdx.x, l = threadIdx.x;
    float a0 = h1[n * 128 + l], a1 = h1[n * 128 + 64 + l];
    float p[10];
    #pragma unroll
    for (int j = 0; j < 10; ++j)
        p[j] = w[j * 128 + l] * a0 + w[j * 128 + 64 + l] * a1;
    #pragma unroll
    for (int j = 0; j < 10; ++j) {
        #pragma unroll
        for (int off = 32; off > 0; off >>= 1) p[j] += __shfl_xor(p[j], off);
    }
    if (l == 0) {
        #pragma unroll
        for (int j = 0; j < 10; ++j) xq[n * 10 + j] = p[j] + b[j];
    }
}

// ---------------------------------------------------------------------------
// Quantum circuit + Z-exp + head: ONE WAVE per batch element (reg-resident).
// ---------------------------------------------------------------------------
__global__ __launch_bounds__(64) void quantum_head_kernel(
    const float* __restrict__ xq, const float* __restrict__ rotm,
    const unsigned short* __restrict__ perm,
    const float* __restrict__ head_w, const float* __restrict__ head_b,
    float* __restrict__ outp)
{
    __shared__ float lds[2048];
    const int n = blockIdx.x;
    const int l = threadIdx.x;

    float ar[16], ai[16];
    #pragma unroll
    for (int r = 0; r < 16; ++r) { ar[r] = 0.f; ai[r] = 0.f; }
    if (l == 0) ar[0] = 1.f;

    #pragma unroll
    for (int w = 0; w < 10; ++w) {
        float th = 0.5f * PI_F * xq[n * 10 + w];
        float c = cosf(th), s = sinf(th);
        const int k = 9 - w;
        if (k >= 6) {
            const int b = k - 6;
            #pragma unroll
            for (int r = 0; r < 16; ++r) {
                if (!(r & (1 << b))) {
                    int r1 = r | (1 << b);
                    float a0 = ar[r], a1 = ar[r1];
                    ar[r]  = c * a0 - s * a1;
                    ar[r1] = s * a0 + c * a1;
                }
            }
        } else {
            float ss = ((l >> k) & 1) ? s : -s;
            #pragma unroll
            for (int r = 0; r < 16; ++r) {
                float p = __shfl_xor(ar[r], 1 << k);
                ar[r] = c * ar[r] + ss * p;
            }
        }
    }

    #pragma unroll 1
    for (int layer = 0; layer < 6; ++layer) {
        #pragma unroll
        for (int w = 0; w < 10; ++w) {
            const float* m = rotm + (layer * 10 + w) * 8;
            float m00r = m[0], m00i = m[1], m01r = m[2], m01i = m[3];
            float m10r = m[4], m10i = m[5], m11r = m[6], m11i = m[7];
            const int k = 9 - w;
            if (k >= 6) {
                const int b = k - 6;
                #pragma unroll
                for (int r = 0; r < 16; ++r) {
                    if (!(r & (1 << b))) {
                        int r1 = r | (1 << b);
                        float a0r = ar[r], a0i = ai[r];
                        float a1r = ar[r1], a1i = ai[r1];
                        ar[r]  = m00r * a0r - m00i * a0i + m01r * a1r - m01i * a1i;
                        ai[r]  = m00r * a0i + m00i * a0r + m01r * a1i + m01i * a1r;
                        ar[r1] = m10r * a0r - m10i * a0i + m11r * a1r - m11i * a1i;
                        ai[r1] = m10r * a0i + m10i * a0r + m11r * a1i + m11i * a1r;
                    }
                }
            } else {
                int bit = (l >> k) & 1;
                float mAr = bit ? m11r : m00r, mAi = bit ? m11i : m00i;
                float mBr = bit ? m10r : m01r, mBi = bit ? m10i : m01i;
                #pragma unroll
                for (int r = 0; r < 16; ++r) {
                    float pr = __shfl_xor(ar[r], 1 << k);
                    float pi = __shfl_xor(ai[r], 1 << k);
                    float mr = ar[r], mi = ai[r];
                    ar[r] = mAr * mr - mAi * mi + mBr * pr - mBi * pi;
                    ai[r] = mAr * mi + mAi * mr + mBr * pi + mBi * pr;
                }
            }
        }
        #pragma unroll
        for (int r = 0; r < 16; ++r) {
            lds[(r << 6) | l] = ar[r];
            lds[1024 + ((r << 6) | l)] = ai[r];
        }
        __syncthreads();
        const unsigned short* pt = perm + layer * 1024;
        #pragma unroll
        for (int r = 0; r < 16; ++r) {
            int ji = pt[(r << 6) | l];
            ar[r] = lds[ji];
            ai[r] = lds[1024 + ji];
        }
        __syncthreads();
    }

    float S = 0.f, T0 = 0.f, T1 = 0.f, T2 = 0.f, T3 = 0.f;
    #pragma unroll
    for (int r = 0; r < 16; ++r) {
        float pr = ar[r] * ar[r] + ai[r] * ai[r];
        S += pr;
        T0 += (r & 1) ? -pr : pr;
        T1 += (r & 2) ? -pr : pr;
        T2 += (r & 4) ? -pr : pr;
        T3 += (r & 8) ? -pr : pr;
    }
    float pk[10];
    pk[0] = T3; pk[1] = T2; pk[2] = T1; pk[3] = T0;
    #pragma unroll
    for (int w = 4; w < 10; ++w)
        pk[w] = ((l >> (9 - w)) & 1) ? -S : S;
    #pragma unroll
    for (int w = 0; w < 10; ++w) {
        #pragma unroll
        for (int off = 1; off < 64; off <<= 1)
            pk[w] += __shfl_xor(pk[w], off);
    }
    if (l < 10) {
        float o = head_b[l];
        #pragma unroll
        for (int kk = 0; kk < 10; ++kk) o += pk[kk] * head_w[l * 10 + kk];
        outp[n * 10 + l] = o;
    }
}

// ---------------------------------------------------------------------------
extern "C" void kernel_launch(void* const* d_in, const int* in_sizes, int n_in,
                              void* d_out, int out_size, void* d_ws, size_t ws_size,
                              hipStream_t stream)
{
    const float* x   = (const float*)d_in[0];
    const float* c1w = (const float*)d_in[1];  const float* c1b = (const float*)d_in[2];
    const float* g1  = (const float*)d_in[3];  const float* b1  = (const float*)d_in[4];
    const float* c2w = (const float*)d_in[5];  const float* c2b = (const float*)d_in[6];
    const float* g2  = (const float*)d_in[7];  const float* b2  = (const float*)d_in[8];
    const float* c3w = (const float*)d_in[9];  const float* c3b = (const float*)d_in[10];
    const float* g3  = (const float*)d_in[11]; const float* b3  = (const float*)d_in[12];
    const float* c4w = (const float*)d_in[13]; const float* c4b = (const float*)d_in[14];
    const float* g4  = (const float*)d_in[15]; const float* b4  = (const float*)d_in[16];
    const float* f1w = (const float*)d_in[17]; const float* f1b = (const float*)d_in[18];
    const float* f2w = (const float*)d_in[19]; const float* f2b = (const float*)d_in[20];
    const float* qw  = (const float*)d_in[21];
    const float* hw  = (const float*)d_in[22]; const float* hb  = (const float*)d_in[23];

    float* ws = (float*)d_ws;
    _Float16* H0 = (_Float16*)ws;              // 33,554,432 halves (64 MB)
    _Float16* H1 = H0 + 33554432;              // 33,554,432 halves (64 MB)
    float* part = ws + 33554432;               // 524,288
    float* ss1  = part + 524288;               // 64
    float* ss2  = ss1 + 64;                    // 64
    float* ss3  = ss2 + 64;                    // 128
    float* ss4  = ss3 + 128;                   // 128
    float* hp   = ss4 + 128;                   // 1,048,576
    float* h1   = hp + 1048576;                // 32,768
    float* xqv  = h1 + 32768;                  // 2,560
    float* rotm = xqv + 2560;                  // 480
    unsigned short* perm16 = (unsigned short*)(rotm + 480);   // 6,144 u16
    _Float16* ssh1 = (_Float16*)(perm16 + 6144);   // 64 halves
    _Float16* ssh3 = ssh1 + 64;                // 128
    _Float16* sab2 = ssh3 + 128;               // 96
    _Float16* sab4 = sab2 + 96;                // 192
    _Float16* wt2  = sab4 + 192;               // 9,216
    _Float16* wt3  = wt2 + 9216;               // 18,432
    _Float16* wt4  = wt3 + 18432;              // 36,864
    _Float16* w1m  = wt4 + 36864;              // 2,048
    _Float16* w1t  = w1m + 2048;               // 2,097,152
    _Float16* X4   = w1t + 2097152;            // 4,194,304 (8 MB)

    // overlays on H1 (sequential lifetimes)
    _Float16* minT2 = H1;                      // (256,32,32,32)
    _Float16* maxT2 = H1 + 8388608;
    _Float16* minT4 = H1;                      // (256,16,16,64)
    _Float16* maxT4 = H1 + 4194304;

    // one-time precomputes
    quantum_prep_kernel<<<1, 256, 0, stream>>>(qw, rotm, perm16);
    wt_transform_kernel<<<260, 256, 0, stream>>>(c1w, c2w, c3w, c4w, w1m, wt2, wt3, wt4);
    fc1w_transform_kernel<<<dim3(4, 128), 256, 0, stream>>>(f1w, w1t);
    x_to_nhwc4_kernel<<<2048, 256, 0, stream>>>(x, X4);

    // conv1 (MFMA): X4 -> H0 (256,64,64,32) + stats
    conv1_mfma_kernel<<<dim3(16, 1, 256), 256, 0, stream>>>(X4, w1m, c1b, H0, part);
    bn_finalize_kernel<<<32, 256, 0, stream>>>(part, 16, 1.f / 1048576.f,
                                               g1, b1, ss1, ssh1, nullptr, 32);

    // conv2 (256thr, 128 spat/wave, packed pooled stores): bn1+relu(H0) -> minT2/maxT2
    conv_mfma_kernel<256, 64, 32, 32, 8, 2, false, true>
        <<<dim3(8, 1, 256), 256, 0, stream>>>(
        H0, nullptr, ssh1, wt2, c2b, minT2, maxT2, part);
    bn_finalize_kernel<<<32, 256, 0, stream>>>(part, 8, 1.f / 1048576.f,
                                               g2, b2, ss2, nullptr, sab2, 32);

    // conv3 (512thr, 64 cout/wave, minmax input): relu(bn2(pool1)) -> H0
    conv_mfma_kernel<512, 32, 32, 64, 4, 4, true, false>
        <<<dim3(2, 1, 256), 512, 0, stream>>>(
        minT2, maxT2, sab2, wt3, c3b, H0, nullptr, part);
    bn_finalize_kernel<<<64, 256, 0, stream>>>(part, 2, 1.f / 262144.f,
                                               g3, b3, ss3, ssh3, nullptr, 64);

    // conv4 (512thr, single-pass CIN=64 staging, packed pooled stores)
    conv_mfma_kernel<512, 32, 64, 64, 4, 4, false, true>
        <<<dim3(2, 1, 256), 512, 0, stream>>>(
        H0, nullptr, ssh3, wt4, c4b, minT4, maxT4, part);
    bn_finalize_kernel<<<64, 256, 0, stream>>>(part, 2, 1.f / 262144.f,
                                               g4, b4, ss4, nullptr, sab4, 64);

    // fc1: MFMA GEMM with on-the-fly relu(bn4(pool2)) + reduce -> h1
    fc1_mfma_kernel<<<dim3(4, 32), 256, 0, stream>>>(minT4, maxT4, sab4, w1t, hp);
    fc1_reduce_kernel<<<128, 256, 0, stream>>>(hp, f1b, h1);

    // fc2 -> xq (256,10)
    fc2_kernel<<<256, 64, 0, stream>>>(h1, f2w, f2b, xqv);

    // quantum circuit + head -> out (256,10)
    quantum_head_kernel<<<256, 64, 0, stream>>>(xqv, rotm, perm16, hw, hb, (float*)d_out);
}